// Round 4
// baseline (729.842 us; speedup 1.0000x reference)
//
#include <hip/hip_runtime.h>

#define NN 50000
#define FD 128
#define NE 800000
#define NG 512
#define NC 16
#define NL 3
#define NTOT 100000
#define NBLK 391            // ceil(100000/256) and ceil(50000/128)
#define NBUCK 196           // ceil(100000/512) slot-buckets
#define CAP 10240           // per-bucket capacity (avg 8163, sigma ~90)
#define BINTILE 2048
#define NBINBLK 782         // ceil(1600000/2048)
#define BNEPS 1e-5f
#define LOGITS_N (NL*NG*NC)

typedef unsigned short u16;
typedef unsigned char u8;
typedef __attribute__((ext_vector_type(8))) short short8;
typedef __attribute__((ext_vector_type(4))) float f32x4;

// ---- workspace layout (bytes) ----
#define OFF_GCNT     0ul          // 2*512 int
#define OFF_BCUR     4096ul       // 196 int
#define OFF_ACC      5120ul       // 2 banks x 512 f32 (S[256],Q[256] each)
#define MEMSET_BYTES 9216ul       // covers GCNT + BCUR + ACC banks
#define OFF_USTART   9728ul       // 513 int
#define OFF_ISTART   12288ul      // 513 int
#define OFF_INVCNT   14848ul      // 512 f32
#define OFF_ROWRANGE 16896ul      // 100000 int2
#define OFF_WB       817152ul     // layer-0 2*128*256 bf16
#define OFF_CSR      1210368ul    // 196*10240 int (binned, then CSR in place)
#define OFF_N0I      9238528ul    // pair0 item (50000*128 bf16)
#define OFF_N0U      22038528ul   // pair0 user
// old N1 region now hosts P / WBs / bvec (pair1 lives in the x0 region)
#define OFF_P        34838528ul   // [2][512][128] f32 = 524288 B
#define OFF_WBS      35362816ul   // 2*128*256 bf16 scaled weights
#define OFF_BVEC     35493888ul   // b1[2][128] | b2[2][128] f32
#define OFF_XU0      60438528ul   // pair1 user / initial cast
#define OFF_XI0      73238528ul   // pair1 item / initial cast

static __device__ __forceinline__ float bf2f(u16 v) {
  return __uint_as_float(((unsigned)v) << 16);
}
static __device__ __forceinline__ u16 f2bf(float f) {
  unsigned u = __float_as_uint(f);
  return (u16)((u + 0x7FFFu + ((u >> 16) & 1u)) >> 16);
}
template<int RELU>
static __device__ __forceinline__ void accT8(float* a, int4 v) {
  unsigned w[4] = {(unsigned)v.x, (unsigned)v.y, (unsigned)v.z, (unsigned)v.w};
  #pragma unroll
  for (int i = 0; i < 4; i++) {
    float lo = __uint_as_float(w[i] << 16);
    float hi = __uint_as_float(w[i] & 0xffff0000u);
    if (RELU) { lo = lo > 0.f ? lo : 0.f; hi = hi > 0.f ? hi : 0.f; }
    a[2*i]   += lo;
    a[2*i+1] += hi;
  }
}
static __device__ __forceinline__ int relu2(int w) {
  int lo = (w & 0x00008000) ? 0 : (w & 0x0000FFFF);
  int hi = (w < 0)          ? 0 : (int)(w & 0xFFFF0000u);
  return lo | hi;
}

// merged preprocessing: castX (12500 blk) | castW (256 blk) | hist (391 blk)
__global__ __launch_bounds__(256) void k_pre(const float* __restrict__ xu,
                                             const float* __restrict__ xi,
                                             u16* __restrict__ xbu,
                                             u16* __restrict__ xbi,
                                             const float* __restrict__ WrelA,
                                             const float* __restrict__ WrootA,
                                             const float* __restrict__ WrelB,
                                             const float* __restrict__ WrootB,
                                             u16* __restrict__ WB,
                                             const int* __restrict__ bu,
                                             const int* __restrict__ bi,
                                             int* __restrict__ gcnt) {
  int b = blockIdx.x;
  if (b < 12500) {
    int half = b >= 6250;
    const float* src = half ? xi : xu;
    u16* dst = half ? xbi : xbu;
    int i = ((half ? b - 6250 : b)*256 + threadIdx.x) * 4;
    float4 v = *(const float4*)(src + i);
    ushort4 o = { f2bf(v.x), f2bf(v.y), f2bf(v.z), f2bf(v.w) };
    *(ushort4*)(dst + i) = o;
  } else if (b < 12756) {
    int idx = (b - 12500)*256 + threadIdx.x;   // layer-0 weights only
    int lr = idx >> 15;
    int rem = idx & 32767;
    int h = rem >> 8;
    int k = rem & 255;
    int rel = lr & 1;
    const float* Wr = rel ? WrelB : WrelA;
    const float* Wo = rel ? WrootB : WrootA;
    float v = (k < FD) ? Wr[h*FD + k] : Wo[h*FD + (k-FD)];
    WB[idx] = f2bf(v);
  } else {
    int i = (b - 12756)*256 + threadIdx.x;
    if (i >= NTOT) return;
    int type = i >= NN;
    int g = type ? bi[i-NN] : bu[i];
    atomicAdd(&gcnt[type*NG + g], 1);
  }
}

// scan per-type graph counts -> contiguous row ranges (batch ids are sorted)
__global__ __launch_bounds__(512) void k_scan_g(const int* __restrict__ gcnt,
                                                int* __restrict__ ustart,
                                                int* __restrict__ istart,
                                                float* __restrict__ invcnt) {
  __shared__ int pu[512], pi[512];
  int t = threadIdx.x;
  int cu = gcnt[t], ci = gcnt[NG + t];
  pu[t] = cu; pi[t] = ci;
  __syncthreads();
  for (int off = 1; off < 512; off <<= 1) {
    int vu = (t >= off) ? pu[t-off] : 0;
    int vi = (t >= off) ? pi[t-off] : 0;
    __syncthreads();
    pu[t] += vu; pi[t] += vi;
    __syncthreads();
  }
  ustart[t] = pu[t] - cu;
  istart[t] = pi[t] - ci;
  if (t == 511) { ustart[NG] = pu[511]; istart[NG] = pi[511]; }
  int c = cu + ci;
  invcnt[t] = 1.0f / (float)(c > 0 ? c : 1);
}

// bucket edges by dst-slot>>9 into fixed-capacity regions. Entry packed to 4B:
// (lslot:9 | src:17). Coalesced run writes via LDS reorder. 2048-edge tiles.
__global__ __launch_bounds__(256) void k_bin(const int* __restrict__ eu2i,
                                             const int* __restrict__ ei2u,
                                             int* __restrict__ bcursor,
                                             int* __restrict__ binned) {
  __shared__ int hist[256];
  __shared__ int scan[256];
  __shared__ int gbase[256];
  __shared__ int rbuf[BINTILE];
  __shared__ u8 rbk[BINTILE];
  int tid = threadIdx.x;
  int base = blockIdx.x * BINTILE;
  hist[tid] = 0;
  __syncthreads();
  int packr[8], bkr[8], rankr[8];
  #pragma unroll
  for (int c = 0; c < 8; c++) {
    int idx = base + c*256 + tid;
    if (idx < 2*NE) {
      int rel = idx >= NE;
      int e = rel ? idx - NE : idx;
      const int* edge = rel ? ei2u : eu2i;
      int s = edge[e];
      int d = edge[NE + e];
      int slot = d + (rel ? NN : 0);
      int bk = slot >> 9;
      bkr[c] = bk;
      packr[c] = ((slot & 511) << 17) | s;
      rankr[c] = atomicAdd(&hist[bk], 1);
    } else bkr[c] = -1;
  }
  __syncthreads();
  scan[tid] = hist[tid];
  __syncthreads();
  for (int o = 1; o < 256; o <<= 1) {
    int v = (tid >= o) ? scan[tid - o] : 0;
    __syncthreads();
    scan[tid] += v;
    __syncthreads();
  }
  if (tid < NBUCK && hist[tid] > 0)
    gbase[tid] = atomicAdd(&bcursor[tid], hist[tid]);
  __syncthreads();
  #pragma unroll
  for (int c = 0; c < 8; c++) {
    if (bkr[c] >= 0) {
      int bk = bkr[c];
      int lpos = scan[bk] - hist[bk] + rankr[c];
      rbuf[lpos] = packr[c];
      rbk[lpos] = (u8)bk;
    }
  }
  __syncthreads();
  int nv = min(BINTILE, 2*NE - base);
  for (int j = tid; j < nv; j += 256) {
    int bk = rbk[j];
    int outpos = bk*CAP + gbase[bk] + (j - (scan[bk] - hist[bk]));
    binned[outpos] = rbuf[j];
  }
}

// one block per bucket: local hist+scan -> rowrange, LDS-staged scatter,
// CSR written IN PLACE over the binned region (block-private).
__global__ __launch_bounds__(256) void k_csrbuild(const int* __restrict__ bcursor,
                                                  int* __restrict__ csrbin,
                                                  int2* __restrict__ rowrange) {
  __shared__ int lcnt[512];
  __shared__ int scan2[256];
  __shared__ int lcsr[CAP];
  int b = blockIdx.x;
  int tid = threadIdx.x;
  int slot0 = b << 9;
  int nslots = min(512, NTOT - slot0);
  int n = bcursor[b];
  int gb = b * CAP;
  lcnt[tid] = 0; lcnt[tid + 256] = 0;
  __syncthreads();
  for (int i = tid; i < n; i += 256) {
    int e = csrbin[gb + i];
    atomicAdd(&lcnt[e >> 17], 1);
  }
  __syncthreads();
  int v0 = lcnt[2*tid], v1 = lcnt[2*tid + 1];
  int ps = v0 + v1;
  scan2[tid] = ps;
  __syncthreads();
  for (int o = 1; o < 256; o <<= 1) {
    int v = (tid >= o) ? scan2[tid - o] : 0;
    __syncthreads();
    scan2[tid] += v;
    __syncthreads();
  }
  int e0 = scan2[tid] - ps;       // exclusive prefix for slot 2*tid
  int e1 = e0 + v0;
  if (2*tid < nslots)     rowrange[slot0 + 2*tid]     = make_int2(gb + e0, gb + e0 + v0);
  if (2*tid + 1 < nslots) rowrange[slot0 + 2*tid + 1] = make_int2(gb + e1, gb + e1 + v1);
  __syncthreads();
  lcnt[2*tid] = e0; lcnt[2*tid + 1] = e1;   // cursors
  __syncthreads();
  for (int i = tid; i < n; i += 256) {
    int e = csrbin[gb + i];
    int pos = atomicAdd(&lcnt[e >> 17], 1);
    lcsr[pos] = e & 0x1FFFF;
  }
  __syncthreads();
  for (int i = tid; i < n; i += 256) csrbin[gb + i] = lcsr[i];
}

// merged BN finalize + fold + feats (replaces k_bnfinal/k_bnfold/k_pool tail):
// every block recomputes sc/sh from accSQ bank (cheap, bit-identical).
// mode 0: blocks [0,64) WBs scale, [64,66) bvec, [66,322) feats
// mode 1 (last layer): all 256 blocks feats.
// feats block fb==0 also zeroes the OTHER accSQ bank for the next gemm.
// feats blocks zero their P entries after reading (ready for next layer).
__global__ __launch_bounds__(256) void k_bnfold2(const float* __restrict__ WrelA,
                                                 const float* __restrict__ WrootA,
                                                 const float* __restrict__ WrelB,
                                                 const float* __restrict__ WrootB,
                                                 int l,
                                                 const float* __restrict__ accSQ,
                                                 float* __restrict__ accSQz,
                                                 const float* __restrict__ gu,
                                                 const float* __restrict__ bu_,
                                                 const float* __restrict__ gi_,
                                                 const float* __restrict__ bi_,
                                                 u16* __restrict__ WBs,
                                                 float* __restrict__ bvec,
                                                 float* __restrict__ P,
                                                 const int* __restrict__ ustart,
                                                 const int* __restrict__ istart,
                                                 const float* __restrict__ invcnt,
                                                 float* __restrict__ feats,
                                                 int mode) {
  __shared__ float sc_l[256], sh_l[256];
  int tid = threadIdx.x;
  {
    int type = tid >> 7;
    int c = tid & 127;
    float s = accSQ[tid];
    float q = accSQ[256 + tid];
    float inv = 1.0f / (float)NN;
    float mean = s * inv;
    float var = q * inv - mean*mean;
    float rstd = rsqrtf(var + BNEPS);
    float g = type ? gi_[c] : gu[c];
    float bb = type ? bi_[c] : bu_[c];
    float sc = rstd * g;
    sc_l[tid] = sc;
    sh_l[tid] = bb - mean * sc;
  }
  __syncthreads();
  int b = blockIdx.x;
  int nfold = mode ? 0 : 66;
  if (b < nfold) {
    if (b < 64) {
      int e = b*256 + tid;          // 16384 entries x 4 consecutive k
      int rel = e >> 13;
      int rem = e & 8191;
      int h = rem >> 6;
      int k0 = (rem & 63) * 4;
      const float* Wr = rel ? WrelB : WrelA;
      const float* Wo = rel ? WrootB : WrootA;
      const float* scs = sc_l + (rel ? 128 : 0);
      const float* scd = sc_l + (rel ? 0 : 128);
      u16 t[4];
      #pragma unroll
      for (int j = 0; j < 4; j++) {
        int k = k0 + j;
        float v = (k < FD) ? Wr[((size_t)l*FD + h)*FD + k] * scs[k]
                           : Wo[((size_t)l*FD + h)*FD + (k - FD)] * scd[k - FD];
        t[j] = f2bf(v);
      }
      ushort4 o = { t[0], t[1], t[2], t[3] };
      *(ushort4*)(WBs + rel*32768 + h*256 + k0) = o;
    } else {
      int vid = (b - 64)*256 + tid; // 0..511
      int kind = vid >> 8;          // 0 = b1 (Wrel, sh_src), 1 = b2 (Wroot, sh_dst)
      int rel = (vid >> 7) & 1;
      int h = vid & 127;
      const float* W = kind ? (rel ? WrootB : WrootA) : (rel ? WrelB : WrelA);
      const float* sh = sh_l + ((kind ^ rel) ? 128 : 0);
      const float* wrow = W + ((size_t)l*FD + h)*FD;
      float s = 0.f;
      #pragma unroll
      for (int k = 0; k < FD; k += 4) {
        float4 wv = *(const float4*)(wrow + k);
        float4 sv = { sh[k], sh[k+1], sh[k+2], sh[k+3] };
        s += wv.x*sv.x + wv.y*sv.y + wv.z*sv.z + wv.w*sv.w;
      }
      bvec[kind*256 + rel*128 + h] = s;
    }
  } else {
    int fb = b - nfold;             // 0..255
    if (fb == 0) { accSQz[tid] = 0.f; accSQz[256 + tid] = 0.f; }
    int g = fb*2 + (tid >> 7);
    int ch = tid & 127;
    size_t iu = (size_t)g*FD + ch;
    size_t ii = (size_t)NG*FD + iu;
    float pu = P[iu];
    float pi = P[ii];
    float cu = (float)(ustart[g+1] - ustart[g]);
    float ci = (float)(istart[g+1] - istart[g]);
    feats[iu] = invcnt[g] * (sc_l[ch]*pu + cu*sh_l[ch]
                           + sc_l[128+ch]*pi + ci*sh_l[128+ch]);
    P[iu] = 0.f; P[ii] = 0.f;
  }
}

// one wave per dst row; 16B/lane loads (16 lanes = one 256B row), quarter-waves
// take different edges; 2 chains x 8-edge iters with index prefetch.
// RELU=1 (layers >0): sources are raw pre-BN activations; relu in-register,
// BN affine folded downstream into GEMM weights/bias.
template<int RELU>
__global__ __launch_bounds__(256) void k_gather(const u16* __restrict__ curU,
                                                const u16* __restrict__ curI,
                                                const int2* __restrict__ rowrange,
                                                const int* __restrict__ csr,
                                                u16* __restrict__ aggI,
                                                u16* __restrict__ aggU) {
  int b = blockIdx.x;
  int half = b >= 12500;
  int blk = half ? b - 12500 : b;
  const u16* src = half ? curI : curU;
  u16* out = half ? aggU : aggI;
  int slotbase = half ? NN : 0;
  int wid = __builtin_amdgcn_readfirstlane(threadIdx.x >> 6);
  int row = blk*4 + wid;
  int lane = threadIdx.x & 63;
  int q = lane >> 4;
  int c16 = (lane & 15) * 8;      // 8 bf16 = 16B per lane
  const u16* sp = src + c16;
  int2 pr = rowrange[slotbase + row];
  int p = pr.x, pe = pr.y;
  float a0[8], a1[8];
  #pragma unroll
  for (int j = 0; j < 8; j++) { a0[j] = 0.f; a1[j] = 0.f; }
  if (p + 8 <= pe) {
    int i0 = csr[p + q], i1 = csr[p + 4 + q];
    while (p + 16 <= pe) {
      int n0 = csr[p + 8 + q], n1 = csr[p + 12 + q];
      int4 v0 = *(const int4*)(sp + (size_t)i0*FD);
      int4 v1 = *(const int4*)(sp + (size_t)i1*FD);
      accT8<RELU>(a0, v0); accT8<RELU>(a1, v1);
      i0 = n0; i1 = n1; p += 8;
    }
    int4 v0 = *(const int4*)(sp + (size_t)i0*FD);
    int4 v1 = *(const int4*)(sp + (size_t)i1*FD);
    accT8<RELU>(a0, v0); accT8<RELU>(a1, v1);
    p += 8;
  }
  int rem = pe - p;               // 0..7
  if (q < rem) {
    int s = csr[p + q];
    accT8<RELU>(a0, *(const int4*)(sp + (size_t)s*FD));
  }
  if (q + 4 < rem) {
    int s = csr[p + 4 + q];
    accT8<RELU>(a1, *(const int4*)(sp + (size_t)s*FD));
  }
  #pragma unroll
  for (int j = 0; j < 8; j++) a0[j] += a1[j];
  #pragma unroll
  for (int j = 0; j < 8; j++) {
    a0[j] += __shfl_xor(a0[j], 16);
    a0[j] += __shfl_xor(a0[j], 32);
  }
  if (q == 0) {
    int4 o;
    o.x = (unsigned)f2bf(a0[0]) | ((unsigned)f2bf(a0[1]) << 16);
    o.y = (unsigned)f2bf(a0[2]) | ((unsigned)f2bf(a0[3]) << 16);
    o.z = (unsigned)f2bf(a0[4]) | ((unsigned)f2bf(a0[5]) << 16);
    o.w = (unsigned)f2bf(a0[6]) | ((unsigned)f2bf(a0[7]) << 16);
    *(int4*)(out + (size_t)row*FD + c16) = o;
  }
}

// MFMA bf16 GEMM + fused BN-stat + per-graph pool accumulation.
// new[n,h] = [agg|cur][n,0:256] @ WB[h,0:256]^T + bias'[n,h]
// Epilogue: relu-stats (shuffle+atomics), per-graph relu-sum into P via
// LDS tile Pl[6][128] (rows graph-sorted -> tile spans <=~3 graphs;
// overflow -> direct global atomic), LDS-transposed coalesced C writeback.
__global__ __launch_bounds__(256) void k_gemm(u16* __restrict__ newU,
                                              u16* __restrict__ newI,
                                              const u16* __restrict__ curU,
                                              const u16* __restrict__ curI,
                                              const u16* __restrict__ WBl,
                                              const float* __restrict__ bI2U,
                                              const float* __restrict__ bU2I,
                                              float* __restrict__ accSQ,
                                              const float* __restrict__ bvec,
                                              const int2* __restrict__ rowrange,
                                              const int* __restrict__ bu,
                                              const int* __restrict__ bi,
                                              float* __restrict__ P,
                                              int fold) {
  __shared__ u16 smem[128*72*2];            // As | Bs; tail reused: Cs + Pl
  __shared__ float Sred[2][4][128];
  u16* As = smem;
  u16* Bs = smem + 128*72;
  u16* Cs = smem;                           // 128*132 = 16896 u16
  float* Pl = (float*)&smem[16896];         // 6*128 f32 = 3072 B (tail)
  int ty = blockIdx.y;
  u16* A1 = ty ? newI : newU;
  const u16* A2 = ty ? curI : curU;
  const u16* WBp = ty ? WBl : (WBl + 32768);
  const float* bias = ty ? bU2I : bI2U;
  const float* b1p = bvec + (ty ? 0 : 128);
  const float* b2p = bvec + 256 + (ty ? 0 : 128);
  const int* batch = ty ? bi : bu;
  float* Pg = P + (size_t)ty*NG*FD;
  int slot0 = ty ? 0 : NN;        // dst slots: items [0,NN), users [NN,2NN)
  int tid = threadIdx.x;
  int n0 = blockIdx.x * 128;
  int w = __builtin_amdgcn_readfirstlane(tid >> 6);
  int lane = tid & 63;
  int l15 = lane & 15;
  int quad = lane >> 4;
  f32x4 acc[2][8];
  #pragma unroll
  for (int tr = 0; tr < 2; tr++)
    #pragma unroll
    for (int tc = 0; tc < 8; tc++)
      acc[tr][tc] = (f32x4){0.f,0.f,0.f,0.f};

  for (int ch = 0; ch < 4; ch++) {
    const u16* Ap = (ch < 2) ? ((const u16*)A1 + ch*64) : (A2 + (ch-2)*64);
    int dorelu = fold && (ch >= 2);
    #pragma unroll
    for (int i = 0; i < 4; i++) {
      int e = i*256 + tid;
      int r = e >> 3, seg = e & 7;
      int4 v = {0,0,0,0};
      int gr = n0 + r;
      if (gr < NN) v = *(const int4*)(Ap + (size_t)gr*FD + seg*8);
      if (dorelu) { v.x = relu2(v.x); v.y = relu2(v.y); v.z = relu2(v.z); v.w = relu2(v.w); }
      *(int4*)&As[r*72 + seg*8] = v;
    }
    #pragma unroll
    for (int i = 0; i < 4; i++) {
      int e = i*256 + tid;
      int r = e >> 3, seg = e & 7;
      int4 v = *(const int4*)(WBp + r*256 + ch*64 + seg*8);
      *(int4*)&Bs[r*72 + seg*8] = v;
    }
    __syncthreads();
    #pragma unroll
    for (int ks = 0; ks < 2; ks++) {
      int kb = ks*32 + quad*8;
      short8 af0 = *(const short8*)&As[(w*32 + l15)*72 + kb];
      short8 af1 = *(const short8*)&As[(w*32 + 16 + l15)*72 + kb];
      short8 bf[8];
      #pragma unroll
      for (int tc = 0; tc < 8; tc++)
        bf[tc] = *(const short8*)&Bs[(tc*16 + l15)*72 + kb];
      #pragma unroll
      for (int tc = 0; tc < 8; tc++) {
        acc[0][tc] = __builtin_amdgcn_mfma_f32_16x16x32_bf16(af0, bf[tc], acc[0][tc], 0, 0, 0);
        acc[1][tc] = __builtin_amdgcn_mfma_f32_16x16x32_bf16(af1, bf[tc], acc[1][tc], 0, 0, 0);
      }
    }
    __syncthreads();
  }
  // zero the per-graph pool tile (aliased into Bs tail -- Bs is dead now)
  #pragma unroll
  for (int i = 0; i < 3; i++) Pl[i*256 + tid] = 0.f;
  __syncthreads();

  int g0 = batch[n0];
  float sv[8], qv[8], bj[8], b1j[8];
  #pragma unroll
  for (int tc = 0; tc < 8; tc++) {
    int col = tc*16 + l15;
    float base = bias[col];
    if (fold) { base += b2p[col]; b1j[tc] = b1p[col]; } else b1j[tc] = 0.f;
    bj[tc] = base;
    sv[tc] = 0.f; qv[tc] = 0.f;
  }
  float dg[2][4] = {{0.f,0.f,0.f,0.f},{0.f,0.f,0.f,0.f}};
  int gix[2][4];
  #pragma unroll
  for (int tr = 0; tr < 2; tr++)
    #pragma unroll
    for (int gq = 0; gq < 4; gq++) {
      int r = n0 + w*32 + tr*16 + quad*4 + gq;
      gix[tr][gq] = -1;
      if (r < NN) {
        gix[tr][gq] = batch[r] - g0;
        if (fold) {
          int2 rr = rowrange[slot0 + r];
          dg[tr][gq] = (float)(rr.y - rr.x);
        }
      }
    }
  #pragma unroll
  for (int tr = 0; tr < 2; tr++) {
    int rl0 = w*32 + tr*16 + quad*4;
    #pragma unroll
    for (int tc = 0; tc < 8; tc++) {
      int col = tc*16 + l15;
      #pragma unroll
      for (int g = 0; g < 4; g++) {
        float v = acc[tr][tc][g] + bj[tc] + dg[tr][g]*b1j[tc];
        Cs[(rl0 + g)*132 + col] = f2bf(v);
        int gx = gix[tr][g];
        if (gx >= 0) {
          float y = v > 0.f ? v : 0.f;
          sv[tc] += y; qv[tc] += y*y;
          if (gx < 6) atomicAdd(&Pl[gx*128 + col], y);
          else        atomicAdd(&Pg[(size_t)(g0+gx)*FD + col], y);
        }
      }
    }
  }
  #pragma unroll
  for (int tc = 0; tc < 8; tc++) {
    sv[tc] += __shfl_xor(sv[tc], 16); qv[tc] += __shfl_xor(qv[tc], 16);
    sv[tc] += __shfl_xor(sv[tc], 32); qv[tc] += __shfl_xor(qv[tc], 32);
  }
  if (quad == 0) {
    #pragma unroll
    for (int tc = 0; tc < 8; tc++) {
      Sred[0][w][tc*16 + l15] = sv[tc];
      Sred[1][w][tc*16 + l15] = qv[tc];
    }
  }
  __syncthreads();          // covers Cs + Pl + Sred writes
  if (tid < 128) {
    float s = Sred[0][0][tid] + Sred[0][1][tid] + Sred[0][2][tid] + Sred[0][3][tid];
    float q = Sred[1][0][tid] + Sred[1][1][tid] + Sred[1][2][tid] + Sred[1][3][tid];
    atomicAdd(&accSQ[ty*128 + tid], s);
    atomicAdd(&accSQ[256 + ty*128 + tid], q);
    #pragma unroll
    for (int gi = 0; gi < 6; gi++) {
      float pv = Pl[gi*128 + tid];
      if (pv != 0.f && g0 + gi < NG)
        atomicAdd(&Pg[(size_t)(g0+gi)*FD + tid], pv);
    }
  }
  // coalesced write-back: per pass j, block covers rows j*16..j*16+15 (4 KB)
  int prow = tid >> 4;            // 0..15
  int pc = (tid & 15) * 8;        // u16 col base (16B per lane)
  #pragma unroll
  for (int j = 0; j < 8; j++) {
    int row = j*16 + prow;
    int gr = n0 + row;
    int4 vv = *(const int4*)&Cs[row*132 + pc];
    if (gr < NN) *(int4*)(A1 + (size_t)gr*FD + pc) = vv;
  }
}

__global__ __launch_bounds__(256) void k_heads(const float* __restrict__ feats,
                                               const float* __restrict__ fcW,
                                               const float* __restrict__ fcb,
                                               float* __restrict__ logits) {
  int idx = blockIdx.x*256 + threadIdx.x;
  if (idx >= LOGITS_N) return;
  int l = idx >> 13;
  int rem = idx & 8191;
  int g = rem >> 4;
  int c = rem & 15;
  const float* f = feats + ((size_t)l*NG + g)*FD;
  const float* w = fcW + ((size_t)l*NC + c)*FD;
  float s = 0.f;
  #pragma unroll
  for (int k = 0; k < FD; k += 4) {
    float4 fv = *(const float4*)(f + k);
    float4 wv = *(const float4*)(w + k);
    s += fv.x*wv.x + fv.y*wv.y + fv.z*wv.z + fv.w*wv.w;
  }
  logits[idx] = s + fcb[l*NC + c];
}

extern "C" void kernel_launch(void* const* d_in, const int* in_sizes, int n_in,
                              void* d_out, int out_size, void* d_ws, size_t ws_size,
                              hipStream_t stream) {
  const float* x_user   = (const float*)d_in[0];
  const float* x_item   = (const float*)d_in[1];
  const int*   eu2i     = (const int*)d_in[2];
  const int*   ei2u     = (const int*)d_in[3];
  const int*   bu       = (const int*)d_in[4];
  const int*   bi       = (const int*)d_in[5];
  const float* Wrel_u2i = (const float*)d_in[6];
  const float* Wroot_u2i= (const float*)d_in[7];
  const float* b_u2i    = (const float*)d_in[8];
  const float* Wrel_i2u = (const float*)d_in[9];
  const float* Wroot_i2u= (const float*)d_in[10];
  const float* b_i2u    = (const float*)d_in[11];
  const float* bn_g_user= (const float*)d_in[12];
  const float* bn_b_user= (const float*)d_in[13];
  const float* bn_g_item= (const float*)d_in[14];
  const float* bn_b_item= (const float*)d_in[15];
  const float* fcW      = (const float*)d_in[16];
  const float* fcb      = (const float*)d_in[17];

  char* ws = (char*)d_ws;
  int*   gcnt   = (int*)(ws + OFF_GCNT);
  int*   bcursor= (int*)(ws + OFF_BCUR);
  float* accSQ  = (float*)(ws + OFF_ACC);     // 2 banks x 512 f32
  int*   ustart = (int*)(ws + OFF_USTART);
  int*   istart = (int*)(ws + OFF_ISTART);
  float* invcnt = (float*)(ws + OFF_INVCNT);
  int2*  rowrange = (int2*)(ws + OFF_ROWRANGE);
  u16*   WB     = (u16*)(ws + OFF_WB);
  int*   csrbin = (int*)(ws + OFF_CSR);
  u16*   p0I    = (u16*)(ws + OFF_N0I);       // pair0 item
  u16*   p0U    = (u16*)(ws + OFF_N0U);       // pair0 user
  float* P      = (float*)(ws + OFF_P);
  u16*   WBs    = (u16*)(ws + OFF_WBS);
  float* bvec   = (float*)(ws + OFF_BVEC);
  u16*   p1U    = (u16*)(ws + OFF_XU0);       // pair1 user (= initial cast)
  u16*   p1I    = (u16*)(ws + OFF_XI0);       // pair1 item (= initial cast)
  float* fout   = (float*)d_out;
  float* featsAll = fout + LOGITS_N;

  float* bank0 = accSQ;
  float* bank1 = accSQ + 512;

  hipMemsetAsync(ws, 0, MEMSET_BYTES, stream);
  hipMemsetAsync(ws + OFF_P, 0, 2ul*NG*FD*4ul, stream);
  k_pre<<<13147, 256, 0, stream>>>(x_user, x_item, p1U, p1I,
                                   Wrel_u2i, Wroot_u2i, Wrel_i2u, Wroot_i2u, WB,
                                   bu, bi, gcnt);
  k_bin<<<NBINBLK, 256, 0, stream>>>(eu2i, ei2u, bcursor, csrbin);
  k_scan_g<<<1, 512, 0, stream>>>(gcnt, ustart, istart, invcnt);
  k_csrbuild<<<NBUCK, 256, 0, stream>>>(bcursor, csrbin, rowrange);

  // ---- layer 0: sources are raw inputs (no relu, no BN fold), pair1 = x0 ----
  k_gather<0><<<25000, 256, 0, stream>>>(p1U, p1I, rowrange, csrbin, p0I, p0U);
  k_gemm<<<dim3(NBLK,2), 256, 0, stream>>>(p0U, p0I, p1U, p1I, WB,
                                           b_i2u, b_u2i, bank0,
                                           bvec, rowrange, bu, bi, P, 0);
  k_bnfold2<<<322, 256, 0, stream>>>(Wrel_u2i, Wroot_u2i, Wrel_i2u, Wroot_i2u,
                                     1, bank0, bank1,
                                     bn_g_user, bn_b_user, bn_g_item, bn_b_item,
                                     WBs, bvec, P, ustart, istart, invcnt,
                                     featsAll, 0);

  // ---- layer 1: relu in gather/staging, BN folded; writes pair1 (x0 dead) ----
  k_gather<1><<<25000, 256, 0, stream>>>(p0U, p0I, rowrange, csrbin, p1I, p1U);
  k_gemm<<<dim3(NBLK,2), 256, 0, stream>>>(p1U, p1I, p0U, p0I, WBs,
                                           b_i2u + FD, b_u2i + FD, bank1,
                                           bvec, rowrange, bu, bi, P, 1);
  k_bnfold2<<<322, 256, 0, stream>>>(Wrel_u2i, Wroot_u2i, Wrel_i2u, Wroot_i2u,
                                     2, bank1, bank0,
                                     bn_g_user, bn_b_user, bn_g_item, bn_b_item,
                                     WBs, bvec, P, ustart, istart, invcnt,
                                     featsAll + NG*FD, 0);

  // ---- layer 2 ----
  k_gather<1><<<25000, 256, 0, stream>>>(p1U, p1I, rowrange, csrbin, p0I, p0U);
  k_gemm<<<dim3(NBLK,2), 256, 0, stream>>>(p0U, p0I, p1U, p1I, WBs,
                                           b_i2u + 2*FD, b_u2i + 2*FD, bank0,
                                           bvec, rowrange, bu, bi, P, 1);
  k_bnfold2<<<256, 256, 0, stream>>>(Wrel_u2i, Wroot_u2i, Wrel_i2u, Wroot_i2u,
                                     2, bank0, bank1,
                                     bn_g_user, bn_b_user, bn_g_item, bn_b_item,
                                     WBs, bvec, P, ustart, istart, invcnt,
                                     featsAll + 2*NG*FD, 1);

  k_heads<<<96, 256, 0, stream>>>(featsAll, fcW, fcb, fout);
}

// Round 6
// 522.319 us; speedup vs baseline: 1.3973x; 1.3973x over previous
//
#include <hip/hip_runtime.h>

#define NN 50000
#define FD 128
#define NE 800000
#define NG 512
#define NC 16
#define NL 3
#define NTOT 100000
#define NBLK 391            // ceil(100000/256) and ceil(50000/128)
#define NBUCK 196           // ceil(100000/512) slot-buckets
#define CAP 10240           // per-bucket capacity (avg 8163, sigma ~90)
#define BINTILE 2048
#define NBINBLK 782         // ceil(1600000/2048)
#define BNEPS 1e-5f
#define LOGITS_N (NL*NG*NC)

typedef unsigned short u16;
typedef unsigned char u8;
typedef __attribute__((ext_vector_type(8))) short short8;
typedef __attribute__((ext_vector_type(4))) float f32x4;

// ---- workspace layout (bytes) ----
#define OFF_GCNT     0ul          // 2*512 int
#define OFF_BCUR     4096ul       // 196 int
#define OFF_ACC      5120ul       // 2 banks x 512 f32 (S[256],Q[256] each)
#define MEMSET_BYTES 9216ul       // covers GCNT + BCUR + ACC banks
#define OFF_USTART   9728ul       // 513 int
#define OFF_ISTART   12288ul      // 513 int
#define OFF_INVCNT   14848ul      // 512 f32
#define OFF_ROWRANGE 16896ul      // 100000 int2
#define OFF_WB       817152ul     // layer-0 2*128*256 bf16
#define OFF_CSR      1210368ul    // 196*10240 int (binned, then CSR in place)
#define OFF_N0I      9238528ul    // pair0 item (50000*128 bf16)
#define OFF_N0U      22038528ul   // pair0 user
// old N1 region hosts P / WBs / bvec (pair1 lives in the x0 region)
#define OFF_P        34838528ul   // [2][512][128] f32 = 524288 B
#define OFF_WBS      35362816ul   // 2*128*256 bf16 scaled weights
#define OFF_BVEC     35493888ul   // b1[2][128] | b2[2][128] f32
#define OFF_XU0      60438528ul   // pair1 user / initial cast
#define OFF_XI0      73238528ul   // pair1 item / initial cast

static __device__ __forceinline__ float bf2f(u16 v) {
  return __uint_as_float(((unsigned)v) << 16);
}
static __device__ __forceinline__ u16 f2bf(float f) {
  unsigned u = __float_as_uint(f);
  return (u16)((u + 0x7FFFu + ((u >> 16) & 1u)) >> 16);
}
template<int RELU>
static __device__ __forceinline__ void accT8(float* a, int4 v) {
  unsigned w[4] = {(unsigned)v.x, (unsigned)v.y, (unsigned)v.z, (unsigned)v.w};
  #pragma unroll
  for (int i = 0; i < 4; i++) {
    float lo = __uint_as_float(w[i] << 16);
    float hi = __uint_as_float(w[i] & 0xffff0000u);
    if (RELU) { lo = lo > 0.f ? lo : 0.f; hi = hi > 0.f ? hi : 0.f; }
    a[2*i]   += lo;
    a[2*i+1] += hi;
  }
}
static __device__ __forceinline__ int relu2(int w) {
  int lo = (w & 0x00008000) ? 0 : (w & 0x0000FFFF);
  int hi = (w < 0)          ? 0 : (int)(w & 0xFFFF0000u);
  return lo | hi;
}

// merged preprocessing: castX (12500 blk) | castW (256 blk) | hist (391 blk)
__global__ __launch_bounds__(256) void k_pre(const float* __restrict__ xu,
                                             const float* __restrict__ xi,
                                             u16* __restrict__ xbu,
                                             u16* __restrict__ xbi,
                                             const float* __restrict__ WrelA,
                                             const float* __restrict__ WrootA,
                                             const float* __restrict__ WrelB,
                                             const float* __restrict__ WrootB,
                                             u16* __restrict__ WB,
                                             const int* __restrict__ bu,
                                             const int* __restrict__ bi,
                                             int* __restrict__ gcnt) {
  int b = blockIdx.x;
  if (b < 12500) {
    int half = b >= 6250;
    const float* src = half ? xi : xu;
    u16* dst = half ? xbi : xbu;
    int i = ((half ? b - 6250 : b)*256 + threadIdx.x) * 4;
    float4 v = *(const float4*)(src + i);
    ushort4 o = { f2bf(v.x), f2bf(v.y), f2bf(v.z), f2bf(v.w) };
    *(ushort4*)(dst + i) = o;
  } else if (b < 12756) {
    int idx = (b - 12500)*256 + threadIdx.x;   // layer-0 weights only
    int lr = idx >> 15;
    int rem = idx & 32767;
    int h = rem >> 8;
    int k = rem & 255;
    int rel = lr & 1;
    const float* Wr = rel ? WrelB : WrelA;
    const float* Wo = rel ? WrootB : WrootA;
    float v = (k < FD) ? Wr[h*FD + k] : Wo[h*FD + (k-FD)];
    WB[idx] = f2bf(v);
  } else {
    int i = (b - 12756)*256 + threadIdx.x;
    if (i >= NTOT) return;
    int type = i >= NN;
    int g = type ? bi[i-NN] : bu[i];
    atomicAdd(&gcnt[type*NG + g], 1);
  }
}

// scan per-type graph counts -> contiguous row ranges (batch ids are sorted)
__global__ __launch_bounds__(512) void k_scan_g(const int* __restrict__ gcnt,
                                                int* __restrict__ ustart,
                                                int* __restrict__ istart,
                                                float* __restrict__ invcnt) {
  __shared__ int pu[512], pi[512];
  int t = threadIdx.x;
  int cu = gcnt[t], ci = gcnt[NG + t];
  pu[t] = cu; pi[t] = ci;
  __syncthreads();
  for (int off = 1; off < 512; off <<= 1) {
    int vu = (t >= off) ? pu[t-off] : 0;
    int vi = (t >= off) ? pi[t-off] : 0;
    __syncthreads();
    pu[t] += vu; pi[t] += vi;
    __syncthreads();
  }
  ustart[t] = pu[t] - cu;
  istart[t] = pi[t] - ci;
  if (t == 511) { ustart[NG] = pu[511]; istart[NG] = pi[511]; }
  int c = cu + ci;
  invcnt[t] = 1.0f / (float)(c > 0 ? c : 1);
}

// bucket edges by dst-slot>>9 into fixed-capacity regions. Entry packed to 4B:
// (lslot:9 | src:17). Coalesced run writes via LDS reorder. 2048-edge tiles.
__global__ __launch_bounds__(256) void k_bin(const int* __restrict__ eu2i,
                                             const int* __restrict__ ei2u,
                                             int* __restrict__ bcursor,
                                             int* __restrict__ binned) {
  __shared__ int hist[256];
  __shared__ int scan[256];
  __shared__ int gbase[256];
  __shared__ int rbuf[BINTILE];
  __shared__ u8 rbk[BINTILE];
  int tid = threadIdx.x;
  int base = blockIdx.x * BINTILE;
  hist[tid] = 0;
  __syncthreads();
  int packr[8], bkr[8], rankr[8];
  #pragma unroll
  for (int c = 0; c < 8; c++) {
    int idx = base + c*256 + tid;
    if (idx < 2*NE) {
      int rel = idx >= NE;
      int e = rel ? idx - NE : idx;
      const int* edge = rel ? ei2u : eu2i;
      int s = edge[e];
      int d = edge[NE + e];
      int slot = d + (rel ? NN : 0);
      int bk = slot >> 9;
      bkr[c] = bk;
      packr[c] = ((slot & 511) << 17) | s;
      rankr[c] = atomicAdd(&hist[bk], 1);
    } else bkr[c] = -1;
  }
  __syncthreads();
  scan[tid] = hist[tid];
  __syncthreads();
  for (int o = 1; o < 256; o <<= 1) {
    int v = (tid >= o) ? scan[tid - o] : 0;
    __syncthreads();
    scan[tid] += v;
    __syncthreads();
  }
  if (tid < NBUCK && hist[tid] > 0)
    gbase[tid] = atomicAdd(&bcursor[tid], hist[tid]);
  __syncthreads();
  #pragma unroll
  for (int c = 0; c < 8; c++) {
    if (bkr[c] >= 0) {
      int bk = bkr[c];
      int lpos = scan[bk] - hist[bk] + rankr[c];
      rbuf[lpos] = packr[c];
      rbk[lpos] = (u8)bk;
    }
  }
  __syncthreads();
  int nv = min(BINTILE, 2*NE - base);
  for (int j = tid; j < nv; j += 256) {
    int bk = rbk[j];
    int outpos = bk*CAP + gbase[bk] + (j - (scan[bk] - hist[bk]));
    binned[outpos] = rbuf[j];
  }
}

// one block per bucket: local hist+scan -> rowrange, LDS-staged scatter,
// CSR written IN PLACE over the binned region (block-private).
__global__ __launch_bounds__(256) void k_csrbuild(const int* __restrict__ bcursor,
                                                  int* __restrict__ csrbin,
                                                  int2* __restrict__ rowrange) {
  __shared__ int lcnt[512];
  __shared__ int scan2[256];
  __shared__ int lcsr[CAP];
  int b = blockIdx.x;
  int tid = threadIdx.x;
  int slot0 = b << 9;
  int nslots = min(512, NTOT - slot0);
  int n = bcursor[b];
  int gb = b * CAP;
  lcnt[tid] = 0; lcnt[tid + 256] = 0;
  __syncthreads();
  for (int i = tid; i < n; i += 256) {
    int e = csrbin[gb + i];
    atomicAdd(&lcnt[e >> 17], 1);
  }
  __syncthreads();
  int v0 = lcnt[2*tid], v1 = lcnt[2*tid + 1];
  int ps = v0 + v1;
  scan2[tid] = ps;
  __syncthreads();
  for (int o = 1; o < 256; o <<= 1) {
    int v = (tid >= o) ? scan2[tid - o] : 0;
    __syncthreads();
    scan2[tid] += v;
    __syncthreads();
  }
  int e0 = scan2[tid] - ps;       // exclusive prefix for slot 2*tid
  int e1 = e0 + v0;
  if (2*tid < nslots)     rowrange[slot0 + 2*tid]     = make_int2(gb + e0, gb + e0 + v0);
  if (2*tid + 1 < nslots) rowrange[slot0 + 2*tid + 1] = make_int2(gb + e1, gb + e1 + v1);
  __syncthreads();
  lcnt[2*tid] = e0; lcnt[2*tid + 1] = e1;   // cursors
  __syncthreads();
  for (int i = tid; i < n; i += 256) {
    int e = csrbin[gb + i];
    int pos = atomicAdd(&lcnt[e >> 17], 1);
    lcsr[pos] = e & 0x1FFFF;
  }
  __syncthreads();
  for (int i = tid; i < n; i += 256) csrbin[gb + i] = lcsr[i];
}

// merged BN finalize + fold + feats:
// every block recomputes sc/sh from accSQ bank (cheap, bit-identical).
// mode 0: blocks [0,64) WBs scale, [64,66) bvec, [66,322) feats
// mode 1 (last layer): all 256 blocks feats.
// feats block fb==0 also zeroes the OTHER accSQ bank for the next gemm.
// feats blocks zero their P entries after reading (ready for next layer).
__global__ __launch_bounds__(256) void k_bnfold2(const float* __restrict__ WrelA,
                                                 const float* __restrict__ WrootA,
                                                 const float* __restrict__ WrelB,
                                                 const float* __restrict__ WrootB,
                                                 int l,
                                                 const float* __restrict__ accSQ,
                                                 float* __restrict__ accSQz,
                                                 const float* __restrict__ gu,
                                                 const float* __restrict__ bu_,
                                                 const float* __restrict__ gi_,
                                                 const float* __restrict__ bi_,
                                                 u16* __restrict__ WBs,
                                                 float* __restrict__ bvec,
                                                 float* __restrict__ P,
                                                 const int* __restrict__ ustart,
                                                 const int* __restrict__ istart,
                                                 const float* __restrict__ invcnt,
                                                 float* __restrict__ feats,
                                                 int mode) {
  __shared__ float sc_l[256], sh_l[256];
  int tid = threadIdx.x;
  {
    int type = tid >> 7;
    int c = tid & 127;
    float s = accSQ[tid];
    float q = accSQ[256 + tid];
    float inv = 1.0f / (float)NN;
    float mean = s * inv;
    float var = q * inv - mean*mean;
    float rstd = rsqrtf(var + BNEPS);
    float g = type ? gi_[c] : gu[c];
    float bb = type ? bi_[c] : bu_[c];
    float sc = rstd * g;
    sc_l[tid] = sc;
    sh_l[tid] = bb - mean * sc;
  }
  __syncthreads();
  int b = blockIdx.x;
  int nfold = mode ? 0 : 66;
  if (b < nfold) {
    if (b < 64) {
      int e = b*256 + tid;          // 16384 entries x 4 consecutive k
      int rel = e >> 13;
      int rem = e & 8191;
      int h = rem >> 6;
      int k0 = (rem & 63) * 4;
      const float* Wr = rel ? WrelB : WrelA;
      const float* Wo = rel ? WrootB : WrootA;
      const float* scs = sc_l + (rel ? 128 : 0);
      const float* scd = sc_l + (rel ? 0 : 128);
      u16 t[4];
      #pragma unroll
      for (int j = 0; j < 4; j++) {
        int k = k0 + j;
        float v = (k < FD) ? Wr[((size_t)l*FD + h)*FD + k] * scs[k]
                           : Wo[((size_t)l*FD + h)*FD + (k - FD)] * scd[k - FD];
        t[j] = f2bf(v);
      }
      ushort4 o = { t[0], t[1], t[2], t[3] };
      *(ushort4*)(WBs + rel*32768 + h*256 + k0) = o;
    } else {
      int vid = (b - 64)*256 + tid; // 0..511
      int kind = vid >> 8;          // 0 = b1 (Wrel, sh_src), 1 = b2 (Wroot, sh_dst)
      int rel = (vid >> 7) & 1;
      int h = vid & 127;
      const float* W = kind ? (rel ? WrootB : WrootA) : (rel ? WrelB : WrelA);
      const float* sh = sh_l + ((kind ^ rel) ? 128 : 0);
      const float* wrow = W + ((size_t)l*FD + h)*FD;
      float s = 0.f;
      #pragma unroll
      for (int k = 0; k < FD; k += 4) {
        float4 wv = *(const float4*)(wrow + k);
        float4 sv = { sh[k], sh[k+1], sh[k+2], sh[k+3] };
        s += wv.x*sv.x + wv.y*sv.y + wv.z*sv.z + wv.w*sv.w;
      }
      bvec[kind*256 + rel*128 + h] = s;
    }
  } else {
    int fb = b - nfold;             // 0..255
    if (fb == 0) { accSQz[tid] = 0.f; accSQz[256 + tid] = 0.f; }
    int g = fb*2 + (tid >> 7);
    int ch = tid & 127;
    size_t iu = (size_t)g*FD + ch;
    size_t ii = (size_t)NG*FD + iu;
    float pu = P[iu];
    float pi = P[ii];
    float cu = (float)(ustart[g+1] - ustart[g]);
    float ci = (float)(istart[g+1] - istart[g]);
    feats[iu] = invcnt[g] * (sc_l[ch]*pu + cu*sh_l[ch]
                           + sc_l[128+ch]*pi + ci*sh_l[128+ch]);
    P[iu] = 0.f; P[ii] = 0.f;
  }
}

// one wave per dst row; 16B/lane loads (16 lanes = one 256B row), quarter-waves
// take different edges; 2 chains x 8-edge iters with index prefetch.
// RELU=1 (layers >0): sources are raw pre-BN activations; relu in-register,
// BN affine folded downstream into GEMM weights/bias.
template<int RELU>
__global__ __launch_bounds__(256) void k_gather(const u16* __restrict__ curU,
                                                const u16* __restrict__ curI,
                                                const int2* __restrict__ rowrange,
                                                const int* __restrict__ csr,
                                                u16* __restrict__ aggI,
                                                u16* __restrict__ aggU) {
  int b = blockIdx.x;
  int half = b >= 12500;
  int blk = half ? b - 12500 : b;
  const u16* src = half ? curI : curU;
  u16* out = half ? aggU : aggI;
  int slotbase = half ? NN : 0;
  int wid = __builtin_amdgcn_readfirstlane(threadIdx.x >> 6);
  int row = blk*4 + wid;
  int lane = threadIdx.x & 63;
  int q = lane >> 4;
  int c16 = (lane & 15) * 8;      // 8 bf16 = 16B per lane
  const u16* sp = src + c16;
  int2 pr = rowrange[slotbase + row];
  int p = pr.x, pe = pr.y;
  float a0[8], a1[8];
  #pragma unroll
  for (int j = 0; j < 8; j++) { a0[j] = 0.f; a1[j] = 0.f; }
  if (p + 8 <= pe) {
    int i0 = csr[p + q], i1 = csr[p + 4 + q];
    while (p + 16 <= pe) {
      int n0 = csr[p + 8 + q], n1 = csr[p + 12 + q];
      int4 v0 = *(const int4*)(sp + (size_t)i0*FD);
      int4 v1 = *(const int4*)(sp + (size_t)i1*FD);
      accT8<RELU>(a0, v0); accT8<RELU>(a1, v1);
      i0 = n0; i1 = n1; p += 8;
    }
    int4 v0 = *(const int4*)(sp + (size_t)i0*FD);
    int4 v1 = *(const int4*)(sp + (size_t)i1*FD);
    accT8<RELU>(a0, v0); accT8<RELU>(a1, v1);
    p += 8;
  }
  int rem = pe - p;               // 0..7
  if (q < rem) {
    int s = csr[p + q];
    accT8<RELU>(a0, *(const int4*)(sp + (size_t)s*FD));
  }
  if (q + 4 < rem) {
    int s = csr[p + 4 + q];
    accT8<RELU>(a1, *(const int4*)(sp + (size_t)s*FD));
  }
  #pragma unroll
  for (int j = 0; j < 8; j++) a0[j] += a1[j];
  #pragma unroll
  for (int j = 0; j < 8; j++) {
    a0[j] += __shfl_xor(a0[j], 16);
    a0[j] += __shfl_xor(a0[j], 32);
  }
  if (q == 0) {
    int4 o;
    o.x = (unsigned)f2bf(a0[0]) | ((unsigned)f2bf(a0[1]) << 16);
    o.y = (unsigned)f2bf(a0[2]) | ((unsigned)f2bf(a0[3]) << 16);
    o.z = (unsigned)f2bf(a0[4]) | ((unsigned)f2bf(a0[5]) << 16);
    o.w = (unsigned)f2bf(a0[6]) | ((unsigned)f2bf(a0[7]) << 16);
    *(int4*)(out + (size_t)row*FD + c16) = o;
  }
}

// MFMA bf16 GEMM + fused BN-stat + per-graph pool.
// new[n,h] = [agg|cur][n,0:256] @ WB[h,0:256]^T + bias'[n,h]
// Epilogue: relu-stats from registers (shuffle+atomics), coalesced C
// writeback via LDS tile Cs[128][132], and per-graph pooling read BACK from
// Cs with REGISTER accumulation per graph-segment (segments from ustart/
// istart since rows are graph-sorted) -> ONE global atomic per
// (graph,col,half). No per-element atomics (round-4 lesson: 12.8M LDS
// atomics serialized the kernel, 120us).
__global__ __launch_bounds__(256) void k_gemm(u16* __restrict__ newU,
                                              u16* __restrict__ newI,
                                              const u16* __restrict__ curU,
                                              const u16* __restrict__ curI,
                                              const u16* __restrict__ WBl,
                                              const float* __restrict__ bI2U,
                                              const float* __restrict__ bU2I,
                                              float* __restrict__ accSQ,
                                              const float* __restrict__ bvec,
                                              const int2* __restrict__ rowrange,
                                              const int* __restrict__ bu,
                                              const int* __restrict__ bi,
                                              const int* __restrict__ ustart,
                                              const int* __restrict__ istart,
                                              float* __restrict__ P,
                                              int fold) {
  __shared__ u16 smem[128*72*2];            // As | Bs; reused as Cs[128][132]
  __shared__ float Sred[2][4][128];
  u16* As = smem;
  u16* Bs = smem + 128*72;
  u16* Cs = smem;                           // 128*132 = 16896 u16 <= 18432
  int ty = blockIdx.y;
  u16* A1 = ty ? newI : newU;
  const u16* A2 = ty ? curI : curU;
  const u16* WBp = ty ? WBl : (WBl + 32768);
  const float* bias = ty ? bU2I : bI2U;
  const float* b1p = bvec + (ty ? 0 : 128);
  const float* b2p = bvec + 256 + (ty ? 0 : 128);
  const int* batch = ty ? bi : bu;
  const int* st = ty ? istart : ustart;
  float* Pg = P + (size_t)ty*NG*FD;
  int slot0 = ty ? 0 : NN;        // dst slots: items [0,NN), users [NN,2NN)
  int tid = threadIdx.x;
  int n0 = blockIdx.x * 128;
  int w = __builtin_amdgcn_readfirstlane(tid >> 6);
  int lane = tid & 63;
  int l15 = lane & 15;
  int quad = lane >> 4;
  f32x4 acc[2][8];
  #pragma unroll
  for (int tr = 0; tr < 2; tr++)
    #pragma unroll
    for (int tc = 0; tc < 8; tc++)
      acc[tr][tc] = (f32x4){0.f,0.f,0.f,0.f};

  for (int ch = 0; ch < 4; ch++) {
    const u16* Ap = (ch < 2) ? ((const u16*)A1 + ch*64) : (A2 + (ch-2)*64);
    int dorelu = fold && (ch >= 2);
    #pragma unroll
    for (int i = 0; i < 4; i++) {
      int e = i*256 + tid;
      int r = e >> 3, seg = e & 7;
      int4 v = {0,0,0,0};
      int gr = n0 + r;
      if (gr < NN) v = *(const int4*)(Ap + (size_t)gr*FD + seg*8);
      if (dorelu) { v.x = relu2(v.x); v.y = relu2(v.y); v.z = relu2(v.z); v.w = relu2(v.w); }
      *(int4*)&As[r*72 + seg*8] = v;
    }
    #pragma unroll
    for (int i = 0; i < 4; i++) {
      int e = i*256 + tid;
      int r = e >> 3, seg = e & 7;
      int4 v = *(const int4*)(WBp + r*256 + ch*64 + seg*8);
      *(int4*)&Bs[r*72 + seg*8] = v;
    }
    __syncthreads();
    #pragma unroll
    for (int ks = 0; ks < 2; ks++) {
      int kb = ks*32 + quad*8;
      short8 af0 = *(const short8*)&As[(w*32 + l15)*72 + kb];
      short8 af1 = *(const short8*)&As[(w*32 + 16 + l15)*72 + kb];
      short8 bf[8];
      #pragma unroll
      for (int tc = 0; tc < 8; tc++)
        bf[tc] = *(const short8*)&Bs[(tc*16 + l15)*72 + kb];
      #pragma unroll
      for (int tc = 0; tc < 8; tc++) {
        acc[0][tc] = __builtin_amdgcn_mfma_f32_16x16x32_bf16(af0, bf[tc], acc[0][tc], 0, 0, 0);
        acc[1][tc] = __builtin_amdgcn_mfma_f32_16x16x32_bf16(af1, bf[tc], acc[1][tc], 0, 0, 0);
      }
    }
    __syncthreads();
  }
  float sv[8], qv[8], bj[8], b1j[8];
  #pragma unroll
  for (int tc = 0; tc < 8; tc++) {
    int col = tc*16 + l15;
    float base = bias[col];
    if (fold) { base += b2p[col]; b1j[tc] = b1p[col]; } else b1j[tc] = 0.f;
    bj[tc] = base;
    sv[tc] = 0.f; qv[tc] = 0.f;
  }
  float dg[2][4] = {{0.f,0.f,0.f,0.f},{0.f,0.f,0.f,0.f}};
  if (fold) {
    #pragma unroll
    for (int tr = 0; tr < 2; tr++)
      #pragma unroll
      for (int gq = 0; gq < 4; gq++) {
        int r = n0 + w*32 + tr*16 + quad*4 + gq;
        if (r < NN) {
          int2 rr = rowrange[slot0 + r];
          dg[tr][gq] = (float)(rr.y - rr.x);
        }
      }
  }
  #pragma unroll
  for (int tr = 0; tr < 2; tr++) {
    int rl0 = w*32 + tr*16 + quad*4;
    int rbase = n0 + rl0;
    #pragma unroll
    for (int tc = 0; tc < 8; tc++) {
      int col = tc*16 + l15;
      #pragma unroll
      for (int g = 0; g < 4; g++) {
        int r = rbase + g;
        float v = acc[tr][tc][g] + bj[tc] + dg[tr][g]*b1j[tc];
        Cs[(rl0 + g)*132 + col] = f2bf(v);
        if (r < NN) {
          float y = v > 0.f ? v : 0.f;
          sv[tc] += y; qv[tc] += y*y;
        }
      }
    }
  }
  #pragma unroll
  for (int tc = 0; tc < 8; tc++) {
    sv[tc] += __shfl_xor(sv[tc], 16); qv[tc] += __shfl_xor(qv[tc], 16);
    sv[tc] += __shfl_xor(sv[tc], 32); qv[tc] += __shfl_xor(qv[tc], 32);
  }
  if (quad == 0) {
    #pragma unroll
    for (int tc = 0; tc < 8; tc++) {
      Sred[0][w][tc*16 + l15] = sv[tc];
      Sred[1][w][tc*16 + l15] = qv[tc];
    }
  }
  __syncthreads();          // covers Cs writes + Sred writes
  if (tid < 128) {
    float s = Sred[0][0][tid] + Sred[0][1][tid] + Sred[0][2][tid] + Sred[0][3][tid];
    float q = Sred[1][0][tid] + Sred[1][1][tid] + Sred[1][2][tid] + Sred[1][3][tid];
    atomicAdd(&accSQ[ty*128 + tid], s);
    atomicAdd(&accSQ[256 + ty*128 + tid], q);
  }
  // per-graph pooling from Cs: thread = (col, half-of-rows). Graph segments
  // are contiguous (rows graph-sorted); boundaries straight from st[].
  {
    int col = tid & 127;
    int half = tid >> 7;
    int rlo = half * 64, rhi = rlo + 64;     // local row range
    int gg0 = batch[n0];
    int lastr = n0 + 127; if (lastr > NN - 1) lastr = NN - 1;
    int gg1 = batch[lastr];
    for (int g = gg0; g <= gg1; ++g) {
      int lo = st[g]   - n0; lo = lo < rlo ? rlo : lo;
      int hi = st[g+1] - n0; hi = hi > rhi ? rhi : hi;
      float s = 0.f;
      for (int r = lo; r < hi; ++r) {
        float v = bf2f(Cs[r*132 + col]);
        s += v > 0.f ? v : 0.f;
      }
      if (hi > lo) atomicAdd(&Pg[(size_t)g*FD + col], s);
    }
  }
  // coalesced write-back: per pass j, block covers rows j*16..j*16+15 (4 KB)
  int prow = tid >> 4;            // 0..15
  int pc = (tid & 15) * 8;        // u16 col base (16B per lane)
  #pragma unroll
  for (int j = 0; j < 8; j++) {
    int row = j*16 + prow;
    int gr = n0 + row;
    int4 vv = *(const int4*)&Cs[row*132 + pc];
    if (gr < NN) *(int4*)(A1 + (size_t)gr*FD + pc) = vv;
  }
}

__global__ __launch_bounds__(256) void k_heads(const float* __restrict__ feats,
                                               const float* __restrict__ fcW,
                                               const float* __restrict__ fcb,
                                               float* __restrict__ logits) {
  int idx = blockIdx.x*256 + threadIdx.x;
  if (idx >= LOGITS_N) return;
  int l = idx >> 13;
  int rem = idx & 8191;
  int g = rem >> 4;
  int c = rem & 15;
  const float* f = feats + ((size_t)l*NG + g)*FD;
  const float* w = fcW + ((size_t)l*NC + c)*FD;
  float s = 0.f;
  #pragma unroll
  for (int k = 0; k < FD; k += 4) {
    float4 fv = *(const float4*)(f + k);
    float4 wv = *(const float4*)(w + k);
    s += fv.x*wv.x + fv.y*wv.y + fv.z*wv.z + fv.w*wv.w;
  }
  logits[idx] = s + fcb[l*NC + c];
}

extern "C" void kernel_launch(void* const* d_in, const int* in_sizes, int n_in,
                              void* d_out, int out_size, void* d_ws, size_t ws_size,
                              hipStream_t stream) {
  const float* x_user   = (const float*)d_in[0];
  const float* x_item   = (const float*)d_in[1];
  const int*   eu2i     = (const int*)d_in[2];
  const int*   ei2u     = (const int*)d_in[3];
  const int*   bu       = (const int*)d_in[4];
  const int*   bi       = (const int*)d_in[5];
  const float* Wrel_u2i = (const float*)d_in[6];
  const float* Wroot_u2i= (const float*)d_in[7];
  const float* b_u2i    = (const float*)d_in[8];
  const float* Wrel_i2u = (const float*)d_in[9];
  const float* Wroot_i2u= (const float*)d_in[10];
  const float* b_i2u    = (const float*)d_in[11];
  const float* bn_g_user= (const float*)d_in[12];
  const float* bn_b_user= (const float*)d_in[13];
  const float* bn_g_item= (const float*)d_in[14];
  const float* bn_b_item= (const float*)d_in[15];
  const float* fcW      = (const float*)d_in[16];
  const float* fcb      = (const float*)d_in[17];

  char* ws = (char*)d_ws;
  int*   gcnt   = (int*)(ws + OFF_GCNT);
  int*   bcursor= (int*)(ws + OFF_BCUR);
  float* accSQ  = (float*)(ws + OFF_ACC);     // 2 banks x 512 f32
  int*   ustart = (int*)(ws + OFF_USTART);
  int*   istart = (int*)(ws + OFF_ISTART);
  float* invcnt = (float*)(ws + OFF_INVCNT);
  int2*  rowrange = (int2*)(ws + OFF_ROWRANGE);
  u16*   WB     = (u16*)(ws + OFF_WB);
  int*   csrbin = (int*)(ws + OFF_CSR);
  u16*   p0I    = (u16*)(ws + OFF_N0I);       // pair0 item
  u16*   p0U    = (u16*)(ws + OFF_N0U);       // pair0 user
  float* P      = (float*)(ws + OFF_P);
  u16*   WBs    = (u16*)(ws + OFF_WBS);
  float* bvec   = (float*)(ws + OFF_BVEC);
  u16*   p1U    = (u16*)(ws + OFF_XU0);       // pair1 user (= initial cast)
  u16*   p1I    = (u16*)(ws + OFF_XI0);       // pair1 item (= initial cast)
  float* fout   = (float*)d_out;
  float* featsAll = fout + LOGITS_N;

  float* bank0 = accSQ;
  float* bank1 = accSQ + 512;

  hipMemsetAsync(ws, 0, MEMSET_BYTES, stream);
  hipMemsetAsync(ws + OFF_P, 0, 2ul*NG*FD*4ul, stream);
  k_pre<<<13147, 256, 0, stream>>>(x_user, x_item, p1U, p1I,
                                   Wrel_u2i, Wroot_u2i, Wrel_i2u, Wroot_i2u, WB,
                                   bu, bi, gcnt);
  k_bin<<<NBINBLK, 256, 0, stream>>>(eu2i, ei2u, bcursor, csrbin);
  k_scan_g<<<1, 512, 0, stream>>>(gcnt, ustart, istart, invcnt);
  k_csrbuild<<<NBUCK, 256, 0, stream>>>(bcursor, csrbin, rowrange);

  // ---- layer 0: sources are raw inputs (no relu, no BN fold), pair1 = x0 ----
  k_gather<0><<<25000, 256, 0, stream>>>(p1U, p1I, rowrange, csrbin, p0I, p0U);
  k_gemm<<<dim3(NBLK,2), 256, 0, stream>>>(p0U, p0I, p1U, p1I, WB,
                                           b_i2u, b_u2i, bank0,
                                           bvec, rowrange, bu, bi,
                                           ustart, istart, P, 0);
  k_bnfold2<<<322, 256, 0, stream>>>(Wrel_u2i, Wroot_u2i, Wrel_i2u, Wroot_i2u,
                                     1, bank0, bank1,
                                     bn_g_user, bn_b_user, bn_g_item, bn_b_item,
                                     WBs, bvec, P, ustart, istart, invcnt,
                                     featsAll, 0);

  // ---- layer 1: relu in gather/staging, BN folded; writes pair1 (x0 dead) ----
  k_gather<1><<<25000, 256, 0, stream>>>(p0U, p0I, rowrange, csrbin, p1I, p1U);
  k_gemm<<<dim3(NBLK,2), 256, 0, stream>>>(p1U, p1I, p0U, p0I, WBs,
                                           b_i2u + FD, b_u2i + FD, bank1,
                                           bvec, rowrange, bu, bi,
                                           ustart, istart, P, 1);
  k_bnfold2<<<322, 256, 0, stream>>>(Wrel_u2i, Wroot_u2i, Wrel_i2u, Wroot_i2u,
                                     2, bank1, bank0,
                                     bn_g_user, bn_b_user, bn_g_item, bn_b_item,
                                     WBs, bvec, P, ustart, istart, invcnt,
                                     featsAll + NG*FD, 0);

  // ---- layer 2 ----
  k_gather<1><<<25000, 256, 0, stream>>>(p1U, p1I, rowrange, csrbin, p0I, p0U);
  k_gemm<<<dim3(NBLK,2), 256, 0, stream>>>(p0U, p0I, p1U, p1I, WBs,
                                           b_i2u + 2*FD, b_u2i + 2*FD, bank0,
                                           bvec, rowrange, bu, bi,
                                           ustart, istart, P, 1);
  k_bnfold2<<<256, 256, 0, stream>>>(Wrel_u2i, Wroot_u2i, Wrel_i2u, Wroot_i2u,
                                     2, bank0, bank1,
                                     bn_g_user, bn_b_user, bn_g_item, bn_b_item,
                                     WBs, bvec, P, ustart, istart, invcnt,
                                     featsAll + 2*NG*FD, 1);

  k_heads<<<96, 256, 0, stream>>>(featsAll, fcW, fcb, fout);
}

// Round 8
// 481.741 us; speedup vs baseline: 1.5150x; 1.0842x over previous
//
#include <hip/hip_runtime.h>

#define NN 50000
#define FD 128
#define NE 800000
#define NG 512
#define NC 16
#define NL 3
#define NTOT 100000
#define NBLK 391            // ceil(100000/256) and ceil(50000/128)
#define NBUCK 196           // ceil(100000/512) slot-buckets
#define CAP 10240           // per-bucket capacity (avg 8163, sigma ~90)
#define BINTILE 2048
#define NBINBLK 782         // ceil(1600000/2048)
#define BNEPS 1e-5f
#define LOGITS_N (NL*NG*NC)
#define Q4 800000           // 50000*128/4 float4s per half-array

typedef unsigned short u16;
typedef unsigned char u8;
typedef __attribute__((ext_vector_type(8))) short short8;
typedef __attribute__((ext_vector_type(4))) float f32x4;

// ---- workspace layout (bytes) ----
#define OFF_GCNT     0ul          // 2*512 int
#define OFF_BCUR     4096ul       // 196 int
#define OFF_ACC      5120ul       // 2 banks x 512 f32 (S[256],Q[256] each)
#define MEMSET_BYTES 9216ul       // covers GCNT + BCUR + ACC banks
#define OFF_USTART   9728ul       // 513 int
#define OFF_ISTART   12288ul      // 513 int
#define OFF_INVCNT   14848ul      // 512 f32
#define OFF_ROWRANGE 16896ul      // 100000 int2
#define OFF_WB       817152ul     // layer-0 2*128*256 bf16
#define OFF_CSR      1210368ul    // 196*10240 int (binned, then CSR in place)
#define OFF_N0I      9238528ul    // pair0 item (50000*128 bf16)
#define OFF_N0U      22038528ul   // pair0 user
// old N1 region hosts P / WBs / bvec (pair1 lives in the x0 region)
#define OFF_P        34838528ul   // [2][512][128] f32 = 524288 B
#define OFF_WBS      35362816ul   // 2*128*256 bf16 scaled weights
#define OFF_BVEC     35493888ul   // b1[2][128] | b2[2][128] f32
#define OFF_XU0      60438528ul   // pair1 user / initial cast
#define OFF_XI0      73238528ul   // pair1 item / initial cast

static __device__ __forceinline__ float bf2f(u16 v) {
  return __uint_as_float(((unsigned)v) << 16);
}
static __device__ __forceinline__ u16 f2bf(float f) {
  unsigned u = __float_as_uint(f);
  return (u16)((u + 0x7FFFu + ((u >> 16) & 1u)) >> 16);
}
template<int RELU>
static __device__ __forceinline__ void accT8(float* a, int4 v) {
  unsigned w[4] = {(unsigned)v.x, (unsigned)v.y, (unsigned)v.z, (unsigned)v.w};
  #pragma unroll
  for (int i = 0; i < 4; i++) {
    float lo = __uint_as_float(w[i] << 16);
    float hi = __uint_as_float(w[i] & 0xffff0000u);
    if (RELU) { lo = lo > 0.f ? lo : 0.f; hi = hi > 0.f ? hi : 0.f; }
    a[2*i]   += lo;
    a[2*i+1] += hi;
  }
}
static __device__ __forceinline__ int relu2(int w) {
  int lo = (w & 0x00008000) ? 0 : (w & 0x0000FFFF);
  int hi = (w < 0)          ? 0 : (int)(w & 0xFFFF0000u);
  return lo | hi;
}
static __device__ __forceinline__ ushort4 cvt4(float4 v) {
  ushort4 o = { f2bf(v.x), f2bf(v.y), f2bf(v.z), f2bf(v.w) };
  return o;
}

// batch histogram, FIRST kernel (absorbs the post-reset DVFS/cold window with
// cheap work). Batch ids sorted -> ballot run-length detection: ~3 atomics
// per wave instead of 64 same-address atomics per wave.
__global__ __launch_bounds__(256) void k_hist(const int* __restrict__ bu,
                                              const int* __restrict__ bi,
                                              int* __restrict__ gcnt) {
  int i = blockIdx.x*256 + threadIdx.x;
  int lane = threadIdx.x & 63;
  bool valid = i < NTOT;
  int slot = -1;
  if (valid) {
    int type = i >= NN;
    int g = type ? bi[i-NN] : bu[i];
    slot = type*NG + g;
  }
  int prevslot = __shfl_up(slot, 1);
  bool head = valid && (lane == 0 || prevslot != slot);
  unsigned long long hb = __ballot(head);
  int nvalid = __popcll(__ballot(valid));   // valid lanes form a prefix
  if (head) {
    unsigned long long higher = (lane < 63) ? (hb >> (lane+1)) : 0ull;
    int next = higher ? (lane + __ffsll(higher)) : 64;
    int end = next < nvalid ? next : nvalid;
    atomicAdd(&gcnt[slot], end - lane);
  }
}

// cast, launched AFTER csrbuild (warm-clock position, R6 lesson: first-kernel
// slot ran the 77MB stream at 833 GB/s). castX: 4 independent float4 loads
// per thread (MLP). castW: layer-0 weights -> WB.
__global__ __launch_bounds__(256) void k_cast(const float* __restrict__ xu,
                                              const float* __restrict__ xi,
                                              u16* __restrict__ xbu,
                                              u16* __restrict__ xbi,
                                              const float* __restrict__ WrelA,
                                              const float* __restrict__ WrootA,
                                              const float* __restrict__ WrelB,
                                              const float* __restrict__ WrootB,
                                              u16* __restrict__ WB) {
  int b = blockIdx.x;
  if (b < 3125) {
    int t = b*256 + threadIdx.x;           // < 800000
    const float4* su = (const float4*)xu;
    const float4* si = (const float4*)xi;
    float4 v0 = su[t];
    float4 v1 = su[t + Q4];
    float4 v2 = si[t];
    float4 v3 = si[t + Q4];
    ushort4* du = (ushort4*)xbu;
    ushort4* di = (ushort4*)xbi;
    du[t]      = cvt4(v0);
    du[t + Q4] = cvt4(v1);
    di[t]      = cvt4(v2);
    di[t + Q4] = cvt4(v3);
  } else {
    int idx = (b - 3125)*256 + threadIdx.x;   // 65536 layer-0 weight entries
    int lr = idx >> 15;
    int rem = idx & 32767;
    int h = rem >> 8;
    int k = rem & 255;
    int rel = lr & 1;
    const float* Wr = rel ? WrelB : WrelA;
    const float* Wo = rel ? WrootB : WrootA;
    float v = (k < FD) ? Wr[h*FD + k] : Wo[h*FD + (k-FD)];
    WB[idx] = f2bf(v);
  }
}

// scan per-type graph counts -> contiguous row ranges (batch ids are sorted)
__global__ __launch_bounds__(512) void k_scan_g(const int* __restrict__ gcnt,
                                                int* __restrict__ ustart,
                                                int* __restrict__ istart,
                                                float* __restrict__ invcnt) {
  __shared__ int pu[512], pi[512];
  int t = threadIdx.x;
  int cu = gcnt[t], ci = gcnt[NG + t];
  pu[t] = cu; pi[t] = ci;
  __syncthreads();
  for (int off = 1; off < 512; off <<= 1) {
    int vu = (t >= off) ? pu[t-off] : 0;
    int vi = (t >= off) ? pi[t-off] : 0;
    __syncthreads();
    pu[t] += vu; pi[t] += vi;
    __syncthreads();
  }
  ustart[t] = pu[t] - cu;
  istart[t] = pi[t] - ci;
  if (t == 511) { ustart[NG] = pu[511]; istart[NG] = pi[511]; }
  int c = cu + ci;
  invcnt[t] = 1.0f / (float)(c > 0 ? c : 1);
}

// bucket edges by dst-slot>>9 into fixed-capacity regions. Entry packed to 4B:
// (lslot:9 | src:17). Coalesced run writes via LDS reorder. 2048-edge tiles.
__global__ __launch_bounds__(256) void k_bin(const int* __restrict__ eu2i,
                                             const int* __restrict__ ei2u,
                                             int* __restrict__ bcursor,
                                             int* __restrict__ binned) {
  __shared__ int hist[256];
  __shared__ int scan[256];
  __shared__ int gbase[256];
  __shared__ int rbuf[BINTILE];
  __shared__ u8 rbk[BINTILE];
  int tid = threadIdx.x;
  int base = blockIdx.x * BINTILE;
  hist[tid] = 0;
  __syncthreads();
  int packr[8], bkr[8], rankr[8];
  #pragma unroll
  for (int c = 0; c < 8; c++) {
    int idx = base + c*256 + tid;
    if (idx < 2*NE) {
      int rel = idx >= NE;
      int e = rel ? idx - NE : idx;
      const int* edge = rel ? ei2u : eu2i;
      int s = edge[e];
      int d = edge[NE + e];
      int slot = d + (rel ? NN : 0);
      int bk = slot >> 9;
      bkr[c] = bk;
      packr[c] = ((slot & 511) << 17) | s;
      rankr[c] = atomicAdd(&hist[bk], 1);
    } else bkr[c] = -1;
  }
  __syncthreads();
  scan[tid] = hist[tid];
  __syncthreads();
  for (int o = 1; o < 256; o <<= 1) {
    int v = (tid >= o) ? scan[tid - o] : 0;
    __syncthreads();
    scan[tid] += v;
    __syncthreads();
  }
  if (tid < NBUCK && hist[tid] > 0)
    gbase[tid] = atomicAdd(&bcursor[tid], hist[tid]);
  __syncthreads();
  #pragma unroll
  for (int c = 0; c < 8; c++) {
    if (bkr[c] >= 0) {
      int bk = bkr[c];
      int lpos = scan[bk] - hist[bk] + rankr[c];
      rbuf[lpos] = packr[c];
      rbk[lpos] = (u8)bk;
    }
  }
  __syncthreads();
  int nv = min(BINTILE, 2*NE - base);
  for (int j = tid; j < nv; j += 256) {
    int bk = rbk[j];
    int outpos = bk*CAP + gbase[bk] + (j - (scan[bk] - hist[bk]));
    binned[outpos] = rbuf[j];
  }
}

// one block per bucket: local hist+scan -> rowrange, LDS-staged scatter,
// CSR written IN PLACE over the binned region (block-private).
__global__ __launch_bounds__(256) void k_csrbuild(const int* __restrict__ bcursor,
                                                  int* __restrict__ csrbin,
                                                  int2* __restrict__ rowrange) {
  __shared__ int lcnt[512];
  __shared__ int scan2[256];
  __shared__ int lcsr[CAP];
  int b = blockIdx.x;
  int tid = threadIdx.x;
  int slot0 = b << 9;
  int nslots = min(512, NTOT - slot0);
  int n = bcursor[b];
  int gb = b * CAP;
  lcnt[tid] = 0; lcnt[tid + 256] = 0;
  __syncthreads();
  for (int i = tid; i < n; i += 256) {
    int e = csrbin[gb + i];
    atomicAdd(&lcnt[e >> 17], 1);
  }
  __syncthreads();
  int v0 = lcnt[2*tid], v1 = lcnt[2*tid + 1];
  int ps = v0 + v1;
  scan2[tid] = ps;
  __syncthreads();
  for (int o = 1; o < 256; o <<= 1) {
    int v = (tid >= o) ? scan2[tid - o] : 0;
    __syncthreads();
    scan2[tid] += v;
    __syncthreads();
  }
  int e0 = scan2[tid] - ps;       // exclusive prefix for slot 2*tid
  int e1 = e0 + v0;
  if (2*tid < nslots)     rowrange[slot0 + 2*tid]     = make_int2(gb + e0, gb + e0 + v0);
  if (2*tid + 1 < nslots) rowrange[slot0 + 2*tid + 1] = make_int2(gb + e1, gb + e1 + v1);
  __syncthreads();
  lcnt[2*tid] = e0; lcnt[2*tid + 1] = e1;   // cursors
  __syncthreads();
  for (int i = tid; i < n; i += 256) {
    int e = csrbin[gb + i];
    int pos = atomicAdd(&lcnt[e >> 17], 1);
    lcsr[pos] = e & 0x1FFFF;
  }
  __syncthreads();
  for (int i = tid; i < n; i += 256) csrbin[gb + i] = lcsr[i];
}

// merged BN finalize + fold + feats:
// every block recomputes sc/sh from accSQ bank (cheap, bit-identical).
// mode 0: blocks [0,64) WBs scale, [64,66) bvec, [66,322) feats
// mode 1 (last layer): all 256 blocks feats.
// feats block fb==0 also zeroes the OTHER accSQ bank for the next gemm.
// feats blocks zero their P entries after reading (ready for next layer).
__global__ __launch_bounds__(256) void k_bnfold2(const float* __restrict__ WrelA,
                                                 const float* __restrict__ WrootA,
                                                 const float* __restrict__ WrelB,
                                                 const float* __restrict__ WrootB,
                                                 int l,
                                                 const float* __restrict__ accSQ,
                                                 float* __restrict__ accSQz,
                                                 const float* __restrict__ gu,
                                                 const float* __restrict__ bu_,
                                                 const float* __restrict__ gi_,
                                                 const float* __restrict__ bi_,
                                                 u16* __restrict__ WBs,
                                                 float* __restrict__ bvec,
                                                 float* __restrict__ P,
                                                 const int* __restrict__ ustart,
                                                 const int* __restrict__ istart,
                                                 const float* __restrict__ invcnt,
                                                 float* __restrict__ feats,
                                                 int mode) {
  __shared__ float sc_l[256], sh_l[256];
  int tid = threadIdx.x;
  {
    int type = tid >> 7;
    int c = tid & 127;
    float s = accSQ[tid];
    float q = accSQ[256 + tid];
    float inv = 1.0f / (float)NN;
    float mean = s * inv;
    float var = q * inv - mean*mean;
    float rstd = rsqrtf(var + BNEPS);
    float g = type ? gi_[c] : gu[c];
    float bb = type ? bi_[c] : bu_[c];
    float sc = rstd * g;
    sc_l[tid] = sc;
    sh_l[tid] = bb - mean * sc;
  }
  __syncthreads();
  int b = blockIdx.x;
  int nfold = mode ? 0 : 66;
  if (b < nfold) {
    if (b < 64) {
      int e = b*256 + tid;          // 16384 entries x 4 consecutive k
      int rel = e >> 13;
      int rem = e & 8191;
      int h = rem >> 6;
      int k0 = (rem & 63) * 4;
      const float* Wr = rel ? WrelB : WrelA;
      const float* Wo = rel ? WrootB : WrootA;
      const float* scs = sc_l + (rel ? 128 : 0);
      const float* scd = sc_l + (rel ? 0 : 128);
      u16 t[4];
      #pragma unroll
      for (int j = 0; j < 4; j++) {
        int k = k0 + j;
        float v = (k < FD) ? Wr[((size_t)l*FD + h)*FD + k] * scs[k]
                           : Wo[((size_t)l*FD + h)*FD + (k - FD)] * scd[k - FD];
        t[j] = f2bf(v);
      }
      ushort4 o = { t[0], t[1], t[2], t[3] };
      *(ushort4*)(WBs + rel*32768 + h*256 + k0) = o;
    } else {
      int vid = (b - 64)*256 + tid; // 0..511
      int kind = vid >> 8;          // 0 = b1 (Wrel, sh_src), 1 = b2 (Wroot, sh_dst)
      int rel = (vid >> 7) & 1;
      int h = vid & 127;
      const float* W = kind ? (rel ? WrootB : WrootA) : (rel ? WrelB : WrelA);
      const float* sh = sh_l + ((kind ^ rel) ? 128 : 0);
      const float* wrow = W + ((size_t)l*FD + h)*FD;
      float s = 0.f;
      #pragma unroll
      for (int k = 0; k < FD; k += 4) {
        float4 wv = *(const float4*)(wrow + k);
        float4 sv = { sh[k], sh[k+1], sh[k+2], sh[k+3] };
        s += wv.x*sv.x + wv.y*sv.y + wv.z*sv.z + wv.w*sv.w;
      }
      bvec[kind*256 + rel*128 + h] = s;
    }
  } else {
    int fb = b - nfold;             // 0..255
    if (fb == 0) { accSQz[tid] = 0.f; accSQz[256 + tid] = 0.f; }
    int g = fb*2 + (tid >> 7);
    int ch = tid & 127;
    size_t iu = (size_t)g*FD + ch;
    size_t ii = (size_t)NG*FD + iu;
    float pu = P[iu];
    float pi = P[ii];
    float cu = (float)(ustart[g+1] - ustart[g]);
    float ci = (float)(istart[g+1] - istart[g]);
    feats[iu] = invcnt[g] * (sc_l[ch]*pu + cu*sh_l[ch]
                           + sc_l[128+ch]*pi + ci*sh_l[128+ch]);
    P[iu] = 0.f; P[ii] = 0.f;
  }
}

// one wave per dst row; 16B/lane loads (16 lanes = one 256B row), quarter-waves
// take different edges; 2 chains x 8-edge iters with index prefetch.
// RELU=1 (layers >0): sources are raw pre-BN activations; relu in-register,
// BN affine folded downstream into GEMM weights/bias.
template<int RELU>
__global__ __launch_bounds__(256) void k_gather(const u16* __restrict__ curU,
                                                const u16* __restrict__ curI,
                                                const int2* __restrict__ rowrange,
                                                const int* __restrict__ csr,
                                                u16* __restrict__ aggI,
                                                u16* __restrict__ aggU) {
  int b = blockIdx.x;
  int half = b >= 12500;
  int blk = half ? b - 12500 : b;
  const u16* src = half ? curI : curU;
  u16* out = half ? aggU : aggI;
  int slotbase = half ? NN : 0;
  int wid = __builtin_amdgcn_readfirstlane(threadIdx.x >> 6);
  int row = blk*4 + wid;
  int lane = threadIdx.x & 63;
  int q = lane >> 4;
  int c16 = (lane & 15) * 8;      // 8 bf16 = 16B per lane
  const u16* sp = src + c16;
  int2 pr = rowrange[slotbase + row];
  int p = pr.x, pe = pr.y;
  float a0[8], a1[8];
  #pragma unroll
  for (int j = 0; j < 8; j++) { a0[j] = 0.f; a1[j] = 0.f; }
  if (p + 8 <= pe) {
    int i0 = csr[p + q], i1 = csr[p + 4 + q];
    while (p + 16 <= pe) {
      int n0 = csr[p + 8 + q], n1 = csr[p + 12 + q];
      int4 v0 = *(const int4*)(sp + (size_t)i0*FD);
      int4 v1 = *(const int4*)(sp + (size_t)i1*FD);
      accT8<RELU>(a0, v0); accT8<RELU>(a1, v1);
      i0 = n0; i1 = n1; p += 8;
    }
    int4 v0 = *(const int4*)(sp + (size_t)i0*FD);
    int4 v1 = *(const int4*)(sp + (size_t)i1*FD);
    accT8<RELU>(a0, v0); accT8<RELU>(a1, v1);
    p += 8;
  }
  int rem = pe - p;               // 0..7
  if (q < rem) {
    int s = csr[p + q];
    accT8<RELU>(a0, *(const int4*)(sp + (size_t)s*FD));
  }
  if (q + 4 < rem) {
    int s = csr[p + 4 + q];
    accT8<RELU>(a1, *(const int4*)(sp + (size_t)s*FD));
  }
  #pragma unroll
  for (int j = 0; j < 8; j++) a0[j] += a1[j];
  #pragma unroll
  for (int j = 0; j < 8; j++) {
    a0[j] += __shfl_xor(a0[j], 16);
    a0[j] += __shfl_xor(a0[j], 32);
  }
  if (q == 0) {
    int4 o;
    o.x = (unsigned)f2bf(a0[0]) | ((unsigned)f2bf(a0[1]) << 16);
    o.y = (unsigned)f2bf(a0[2]) | ((unsigned)f2bf(a0[3]) << 16);
    o.z = (unsigned)f2bf(a0[4]) | ((unsigned)f2bf(a0[5]) << 16);
    o.w = (unsigned)f2bf(a0[6]) | ((unsigned)f2bf(a0[7]) << 16);
    *(int4*)(out + (size_t)row*FD + c16) = o;
  }
}

// MFMA bf16 GEMM + fused BN-stat + per-graph pool.
// new[n,h] = [agg|cur][n,0:256] @ WB[h,0:256]^T + bias'[n,h]
// Epilogue: relu-stats from registers (shuffle+atomics), coalesced C
// writeback via LDS tile Cs[128][132], and per-graph pooling read BACK from
// Cs with REGISTER accumulation per graph-segment (segments from ustart/
// istart since rows are graph-sorted) -> ONE global atomic per
// (graph,col,half). No per-element atomics (round-4 lesson: 12.8M LDS
// atomics serialized the kernel, 120us).
__global__ __launch_bounds__(256) void k_gemm(u16* __restrict__ newU,
                                              u16* __restrict__ newI,
                                              const u16* __restrict__ curU,
                                              const u16* __restrict__ curI,
                                              const u16* __restrict__ WBl,
                                              const float* __restrict__ bI2U,
                                              const float* __restrict__ bU2I,
                                              float* __restrict__ accSQ,
                                              const float* __restrict__ bvec,
                                              const int2* __restrict__ rowrange,
                                              const int* __restrict__ bu,
                                              const int* __restrict__ bi,
                                              const int* __restrict__ ustart,
                                              const int* __restrict__ istart,
                                              float* __restrict__ P,
                                              int fold) {
  __shared__ u16 smem[128*72*2];            // As | Bs; reused as Cs[128][132]
  __shared__ float Sred[2][4][128];
  u16* As = smem;
  u16* Bs = smem + 128*72;
  u16* Cs = smem;                           // 128*132 = 16896 u16 <= 18432
  int ty = blockIdx.y;
  u16* A1 = ty ? newI : newU;
  const u16* A2 = ty ? curI : curU;
  const u16* WBp = ty ? WBl : (WBl + 32768);
  const float* bias = ty ? bU2I : bI2U;
  const float* b1p = bvec + (ty ? 0 : 128);
  const float* b2p = bvec + 256 + (ty ? 0 : 128);
  const int* batch = ty ? bi : bu;
  const int* st = ty ? istart : ustart;
  float* Pg = P + (size_t)ty*NG*FD;
  int slot0 = ty ? 0 : NN;        // dst slots: items [0,NN), users [NN,2NN)
  int tid = threadIdx.x;
  int n0 = blockIdx.x * 128;
  int w = __builtin_amdgcn_readfirstlane(tid >> 6);
  int lane = tid & 63;
  int l15 = lane & 15;
  int quad = lane >> 4;
  f32x4 acc[2][8];
  #pragma unroll
  for (int tr = 0; tr < 2; tr++)
    #pragma unroll
    for (int tc = 0; tc < 8; tc++)
      acc[tr][tc] = (f32x4){0.f,0.f,0.f,0.f};

  for (int ch = 0; ch < 4; ch++) {
    const u16* Ap = (ch < 2) ? ((const u16*)A1 + ch*64) : (A2 + (ch-2)*64);
    int dorelu = fold && (ch >= 2);
    #pragma unroll
    for (int i = 0; i < 4; i++) {
      int e = i*256 + tid;
      int r = e >> 3, seg = e & 7;
      int4 v = {0,0,0,0};
      int gr = n0 + r;
      if (gr < NN) v = *(const int4*)(Ap + (size_t)gr*FD + seg*8);
      if (dorelu) { v.x = relu2(v.x); v.y = relu2(v.y); v.z = relu2(v.z); v.w = relu2(v.w); }
      *(int4*)&As[r*72 + seg*8] = v;
    }
    #pragma unroll
    for (int i = 0; i < 4; i++) {
      int e = i*256 + tid;
      int r = e >> 3, seg = e & 7;
      int4 v = *(const int4*)(WBp + r*256 + ch*64 + seg*8);
      *(int4*)&Bs[r*72 + seg*8] = v;
    }
    __syncthreads();
    #pragma unroll
    for (int ks = 0; ks < 2; ks++) {
      int kb = ks*32 + quad*8;
      short8 af0 = *(const short8*)&As[(w*32 + l15)*72 + kb];
      short8 af1 = *(const short8*)&As[(w*32 + 16 + l15)*72 + kb];
      short8 bf[8];
      #pragma unroll
      for (int tc = 0; tc < 8; tc++)
        bf[tc] = *(const short8*)&Bs[(tc*16 + l15)*72 + kb];
      #pragma unroll
      for (int tc = 0; tc < 8; tc++) {
        acc[0][tc] = __builtin_amdgcn_mfma_f32_16x16x32_bf16(af0, bf[tc], acc[0][tc], 0, 0, 0);
        acc[1][tc] = __builtin_amdgcn_mfma_f32_16x16x32_bf16(af1, bf[tc], acc[1][tc], 0, 0, 0);
      }
    }
    __syncthreads();
  }
  float sv[8], qv[8], bj[8], b1j[8];
  #pragma unroll
  for (int tc = 0; tc < 8; tc++) {
    int col = tc*16 + l15;
    float base = bias[col];
    if (fold) { base += b2p[col]; b1j[tc] = b1p[col]; } else b1j[tc] = 0.f;
    bj[tc] = base;
    sv[tc] = 0.f; qv[tc] = 0.f;
  }
  float dg[2][4] = {{0.f,0.f,0.f,0.f},{0.f,0.f,0.f,0.f}};
  if (fold) {
    #pragma unroll
    for (int tr = 0; tr < 2; tr++)
      #pragma unroll
      for (int gq = 0; gq < 4; gq++) {
        int r = n0 + w*32 + tr*16 + quad*4 + gq;
        if (r < NN) {
          int2 rr = rowrange[slot0 + r];
          dg[tr][gq] = (float)(rr.y - rr.x);
        }
      }
  }
  #pragma unroll
  for (int tr = 0; tr < 2; tr++) {
    int rl0 = w*32 + tr*16 + quad*4;
    int rbase = n0 + rl0;
    #pragma unroll
    for (int tc = 0; tc < 8; tc++) {
      int col = tc*16 + l15;
      #pragma unroll
      for (int g = 0; g < 4; g++) {
        int r = rbase + g;
        float v = acc[tr][tc][g] + bj[tc] + dg[tr][g]*b1j[tc];
        Cs[(rl0 + g)*132 + col] = f2bf(v);
        if (r < NN) {
          float y = v > 0.f ? v : 0.f;
          sv[tc] += y; qv[tc] += y*y;
        }
      }
    }
  }
  #pragma unroll
  for (int tc = 0; tc < 8; tc++) {
    sv[tc] += __shfl_xor(sv[tc], 16); qv[tc] += __shfl_xor(qv[tc], 16);
    sv[tc] += __shfl_xor(sv[tc], 32); qv[tc] += __shfl_xor(qv[tc], 32);
  }
  if (quad == 0) {
    #pragma unroll
    for (int tc = 0; tc < 8; tc++) {
      Sred[0][w][tc*16 + l15] = sv[tc];
      Sred[1][w][tc*16 + l15] = qv[tc];
    }
  }
  __syncthreads();          // covers Cs writes + Sred writes
  if (tid < 128) {
    float s = Sred[0][0][tid] + Sred[0][1][tid] + Sred[0][2][tid] + Sred[0][3][tid];
    float q = Sred[1][0][tid] + Sred[1][1][tid] + Sred[1][2][tid] + Sred[1][3][tid];
    atomicAdd(&accSQ[ty*128 + tid], s);
    atomicAdd(&accSQ[256 + ty*128 + tid], q);
  }
  // per-graph pooling from Cs: thread = (col, half-of-rows). Graph segments
  // are contiguous (rows graph-sorted); boundaries straight from st[].
  {
    int col = tid & 127;
    int half = tid >> 7;
    int rlo = half * 64, rhi = rlo + 64;     // local row range
    int gg0 = batch[n0];
    int lastr = n0 + 127; if (lastr > NN - 1) lastr = NN - 1;
    int gg1 = batch[lastr];
    for (int g = gg0; g <= gg1; ++g) {
      int lo = st[g]   - n0; lo = lo < rlo ? rlo : lo;
      int hi = st[g+1] - n0; hi = hi > rhi ? rhi : hi;
      float s = 0.f;
      for (int r = lo; r < hi; ++r) {
        float v = bf2f(Cs[r*132 + col]);
        s += v > 0.f ? v : 0.f;
      }
      if (hi > lo) atomicAdd(&Pg[(size_t)g*FD + col], s);
    }
  }
  // coalesced write-back: per pass j, block covers rows j*16..j*16+15 (4 KB)
  int prow = tid >> 4;            // 0..15
  int pc = (tid & 15) * 8;        // u16 col base (16B per lane)
  #pragma unroll
  for (int j = 0; j < 8; j++) {
    int row = j*16 + prow;
    int gr = n0 + row;
    int4 vv = *(const int4*)&Cs[row*132 + pc];
    if (gr < NN) *(int4*)(A1 + (size_t)gr*FD + pc) = vv;
  }
}

__global__ __launch_bounds__(256) void k_heads(const float* __restrict__ feats,
                                               const float* __restrict__ fcW,
                                               const float* __restrict__ fcb,
                                               float* __restrict__ logits) {
  int idx = blockIdx.x*256 + threadIdx.x;
  if (idx >= LOGITS_N) return;
  int l = idx >> 13;
  int rem = idx & 8191;
  int g = rem >> 4;
  int c = rem & 15;
  const float* f = feats + ((size_t)l*NG + g)*FD;
  const float* w = fcW + ((size_t)l*NC + c)*FD;
  float s = 0.f;
  #pragma unroll
  for (int k = 0; k < FD; k += 4) {
    float4 fv = *(const float4*)(f + k);
    float4 wv = *(const float4*)(w + k);
    s += fv.x*wv.x + fv.y*wv.y + fv.z*wv.z + fv.w*wv.w;
  }
  logits[idx] = s + fcb[l*NC + c];
}

extern "C" void kernel_launch(void* const* d_in, const int* in_sizes, int n_in,
                              void* d_out, int out_size, void* d_ws, size_t ws_size,
                              hipStream_t stream) {
  const float* x_user   = (const float*)d_in[0];
  const float* x_item   = (const float*)d_in[1];
  const int*   eu2i     = (const int*)d_in[2];
  const int*   ei2u     = (const int*)d_in[3];
  const int*   bu       = (const int*)d_in[4];
  const int*   bi       = (const int*)d_in[5];
  const float* Wrel_u2i = (const float*)d_in[6];
  const float* Wroot_u2i= (const float*)d_in[7];
  const float* b_u2i    = (const float*)d_in[8];
  const float* Wrel_i2u = (const float*)d_in[9];
  const float* Wroot_i2u= (const float*)d_in[10];
  const float* b_i2u    = (const float*)d_in[11];
  const float* bn_g_user= (const float*)d_in[12];
  const float* bn_b_user= (const float*)d_in[13];
  const float* bn_g_item= (const float*)d_in[14];
  const float* bn_b_item= (const float*)d_in[15];
  const float* fcW      = (const float*)d_in[16];
  const float* fcb      = (const float*)d_in[17];

  char* ws = (char*)d_ws;
  int*   gcnt   = (int*)(ws + OFF_GCNT);
  int*   bcursor= (int*)(ws + OFF_BCUR);
  float* accSQ  = (float*)(ws + OFF_ACC);     // 2 banks x 512 f32
  int*   ustart = (int*)(ws + OFF_USTART);
  int*   istart = (int*)(ws + OFF_ISTART);
  float* invcnt = (float*)(ws + OFF_INVCNT);
  int2*  rowrange = (int2*)(ws + OFF_ROWRANGE);
  u16*   WB     = (u16*)(ws + OFF_WB);
  int*   csrbin = (int*)(ws + OFF_CSR);
  u16*   p0I    = (u16*)(ws + OFF_N0I);       // pair0 item
  u16*   p0U    = (u16*)(ws + OFF_N0U);       // pair0 user
  float* P      = (float*)(ws + OFF_P);
  u16*   WBs    = (u16*)(ws + OFF_WBS);
  float* bvec   = (float*)(ws + OFF_BVEC);
  u16*   p1U    = (u16*)(ws + OFF_XU0);       // pair1 user (= initial cast)
  u16*   p1I    = (u16*)(ws + OFF_XI0);       // pair1 item (= initial cast)
  float* fout   = (float*)d_out;
  float* featsAll = fout + LOGITS_N;

  float* bank0 = accSQ;
  float* bank1 = accSQ + 512;

  hipMemsetAsync(ws, 0, MEMSET_BYTES, stream);
  hipMemsetAsync(ws + OFF_P, 0, 2ul*NG*FD*4ul, stream);
  // small kernels first: absorb the post-reset cold window (R6: first-slot
  // streaming kernel ran at 833 GB/s). Cast moved to warm position.
  k_hist<<<NBLK, 256, 0, stream>>>(bu, bi, gcnt);
  k_bin<<<NBINBLK, 256, 0, stream>>>(eu2i, ei2u, bcursor, csrbin);
  k_scan_g<<<1, 512, 0, stream>>>(gcnt, ustart, istart, invcnt);
  k_csrbuild<<<NBUCK, 256, 0, stream>>>(bcursor, csrbin, rowrange);
  k_cast<<<3381, 256, 0, stream>>>(x_user, x_item, p1U, p1I,
                                   Wrel_u2i, Wroot_u2i, Wrel_i2u, Wroot_i2u, WB);

  // ---- layer 0: sources are raw inputs (no relu, no BN fold), pair1 = x0 ----
  k_gather<0><<<25000, 256, 0, stream>>>(p1U, p1I, rowrange, csrbin, p0I, p0U);
  k_gemm<<<dim3(NBLK,2), 256, 0, stream>>>(p0U, p0I, p1U, p1I, WB,
                                           b_i2u, b_u2i, bank0,
                                           bvec, rowrange, bu, bi,
                                           ustart, istart, P, 0);
  k_bnfold2<<<322, 256, 0, stream>>>(Wrel_u2i, Wroot_u2i, Wrel_i2u, Wroot_i2u,
                                     1, bank0, bank1,
                                     bn_g_user, bn_b_user, bn_g_item, bn_b_item,
                                     WBs, bvec, P, ustart, istart, invcnt,
                                     featsAll, 0);

  // ---- layer 1: relu in gather/staging, BN folded; writes pair1 (x0 dead) ----
  k_gather<1><<<25000, 256, 0, stream>>>(p0U, p0I, rowrange, csrbin, p1I, p1U);
  k_gemm<<<dim3(NBLK,2), 256, 0, stream>>>(p1U, p1I, p0U, p0I, WBs,
                                           b_i2u + FD, b_u2i + FD, bank1,
                                           bvec, rowrange, bu, bi,
                                           ustart, istart, P, 1);
  k_bnfold2<<<322, 256, 0, stream>>>(Wrel_u2i, Wroot_u2i, Wrel_i2u, Wroot_i2u,
                                     2, bank1, bank0,
                                     bn_g_user, bn_b_user, bn_g_item, bn_b_item,
                                     WBs, bvec, P, ustart, istart, invcnt,
                                     featsAll + NG*FD, 0);

  // ---- layer 2 ----
  k_gather<1><<<25000, 256, 0, stream>>>(p1U, p1I, rowrange, csrbin, p0I, p0U);
  k_gemm<<<dim3(NBLK,2), 256, 0, stream>>>(p0U, p0I, p1U, p1I, WBs,
                                           b_i2u + 2*FD, b_u2i + 2*FD, bank0,
                                           bvec, rowrange, bu, bi,
                                           ustart, istart, P, 1);
  k_bnfold2<<<256, 256, 0, stream>>>(Wrel_u2i, Wroot_u2i, Wrel_i2u, Wroot_i2u,
                                     2, bank0, bank1,
                                     bn_g_user, bn_b_user, bn_g_item, bn_b_item,
                                     WBs, bvec, P, ustart, istart, invcnt,
                                     featsAll + 2*NG*FD, 1);

  k_heads<<<96, 256, 0, stream>>>(featsAll, fcW, fcb, fout);
}

// Round 9
// 476.204 us; speedup vs baseline: 1.5326x; 1.0116x over previous
//
#include <hip/hip_runtime.h>

#define NN 50000
#define FD 128
#define NE 800000
#define NG 512
#define NC 16
#define NL 3
#define NTOT 100000
#define NBLK 391            // ceil(100000/256) and ceil(50000/128)
#define NBUCK 196           // ceil(100000/512) slot-buckets
#define CAP 10240           // per-bucket capacity (avg 8163, sigma ~90)
#define BINTILE 2048
#define NBINBLK 782         // ceil(1600000/2048)
#define NGBLK 6250          // gather blocks: 2 x 50000/16
#define BNEPS 1e-5f
#define LOGITS_N (NL*NG*NC)
#define Q4 800000           // 50000*128/4 float4s per half-array

typedef unsigned short u16;
typedef unsigned char u8;
typedef __attribute__((ext_vector_type(8))) short short8;
typedef __attribute__((ext_vector_type(4))) float f32x4;

// ---- workspace layout (bytes) ----
#define OFF_GCNT     0ul          // 2*512 int
#define OFF_BCUR     4096ul       // 196 int
#define OFF_ACC      5120ul       // 2 banks x 512 f32 (S[256],Q[256] each)
#define MEMSET_BYTES 9216ul       // covers GCNT + BCUR + ACC banks
#define OFF_USTART   9728ul       // 513 int
#define OFF_ISTART   12288ul      // 513 int
#define OFF_INVCNT   14848ul      // 512 f32
#define OFF_ROWRANGE 16896ul      // 100000 int2
#define OFF_WB       817152ul     // layer-0 2*128*256 bf16
#define OFF_CSR      1210368ul    // 196*10240 int (binned, then CSR in place)
#define OFF_N0I      9238528ul    // pair0 item (50000*128 bf16)
#define OFF_N0U      22038528ul   // pair0 user
#define OFF_P        34838528ul   // [2][512][128] f32 = 524288 B
#define OFF_WBS      35362816ul   // 2*128*256 bf16 scaled weights
#define OFF_BVEC     35493888ul   // b1[2][128] | b2[2][128] f32
#define OFF_XU0      60438528ul   // pair1 user / initial cast
#define OFF_XI0      73238528ul   // pair1 item / initial cast

static __device__ __forceinline__ float bf2f(u16 v) {
  return __uint_as_float(((unsigned)v) << 16);
}
static __device__ __forceinline__ u16 f2bf(float f) {
  unsigned u = __float_as_uint(f);
  return (u16)((u + 0x7FFFu + ((u >> 16) & 1u)) >> 16);
}
template<int RELU>
static __device__ __forceinline__ void accT8(float* a, int4 v) {
  unsigned w[4] = {(unsigned)v.x, (unsigned)v.y, (unsigned)v.z, (unsigned)v.w};
  #pragma unroll
  for (int i = 0; i < 4; i++) {
    float lo = __uint_as_float(w[i] << 16);
    float hi = __uint_as_float(w[i] & 0xffff0000u);
    if (RELU) { lo = lo > 0.f ? lo : 0.f; hi = hi > 0.f ? hi : 0.f; }
    a[2*i]   += lo;
    a[2*i+1] += hi;
  }
}
static __device__ __forceinline__ int relu2(int w) {
  int lo = (w & 0x00008000) ? 0 : (w & 0x0000FFFF);
  int hi = (w < 0)          ? 0 : (int)(w & 0xFFFF0000u);
  return lo | hi;
}
static __device__ __forceinline__ ushort4 cvt4(float4 v) {
  ushort4 o = { f2bf(v.x), f2bf(v.y), f2bf(v.z), f2bf(v.w) };
  return o;
}

// bucket edges by dst-slot>>9 into fixed-capacity regions; entry (lslot:9|src:17).
// Blocks [NBINBLK, NBINBLK+391): batch histogram (ballot run-length, sorted ids).
__global__ __launch_bounds__(256) void k_bin(const int* __restrict__ eu2i,
                                             const int* __restrict__ ei2u,
                                             int* __restrict__ bcursor,
                                             int* __restrict__ binned,
                                             const int* __restrict__ bu,
                                             const int* __restrict__ bi,
                                             int* __restrict__ gcnt) {
  if (blockIdx.x >= NBINBLK) {
    int i = (blockIdx.x - NBINBLK)*256 + threadIdx.x;
    int lane = threadIdx.x & 63;
    bool valid = i < NTOT;
    int slot = -1;
    if (valid) {
      int type = i >= NN;
      int g = type ? bi[i-NN] : bu[i];
      slot = type*NG + g;
    }
    int prevslot = __shfl_up(slot, 1);
    bool head = valid && (lane == 0 || prevslot != slot);
    unsigned long long hb = __ballot(head);
    int nvalid = __popcll(__ballot(valid));   // valid lanes form a prefix
    if (head) {
      unsigned long long higher = (lane < 63) ? (hb >> (lane+1)) : 0ull;
      int next = higher ? (lane + __ffsll(higher)) : 64;
      int end = next < nvalid ? next : nvalid;
      atomicAdd(&gcnt[slot], end - lane);
    }
    return;
  }
  __shared__ int hist[256];
  __shared__ int scan[256];
  __shared__ int gbase[256];
  __shared__ int rbuf[BINTILE];
  __shared__ u8 rbk[BINTILE];
  int tid = threadIdx.x;
  int base = blockIdx.x * BINTILE;
  hist[tid] = 0;
  __syncthreads();
  int packr[8], bkr[8], rankr[8];
  #pragma unroll
  for (int c = 0; c < 8; c++) {
    int idx = base + c*256 + tid;
    if (idx < 2*NE) {
      int rel = idx >= NE;
      int e = rel ? idx - NE : idx;
      const int* edge = rel ? ei2u : eu2i;
      int s = edge[e];
      int d = edge[NE + e];
      int slot = d + (rel ? NN : 0);
      int bk = slot >> 9;
      bkr[c] = bk;
      packr[c] = ((slot & 511) << 17) | s;
      rankr[c] = atomicAdd(&hist[bk], 1);
    } else bkr[c] = -1;
  }
  __syncthreads();
  scan[tid] = hist[tid];
  __syncthreads();
  for (int o = 1; o < 256; o <<= 1) {
    int v = (tid >= o) ? scan[tid - o] : 0;
    __syncthreads();
    scan[tid] += v;
    __syncthreads();
  }
  if (tid < NBUCK && hist[tid] > 0)
    gbase[tid] = atomicAdd(&bcursor[tid], hist[tid]);
  __syncthreads();
  #pragma unroll
  for (int c = 0; c < 8; c++) {
    if (bkr[c] >= 0) {
      int bk = bkr[c];
      int lpos = scan[bk] - hist[bk] + rankr[c];
      rbuf[lpos] = packr[c];
      rbk[lpos] = (u8)bk;
    }
  }
  __syncthreads();
  int nv = min(BINTILE, 2*NE - base);
  for (int j = tid; j < nv; j += 256) {
    int bk = rbk[j];
    int outpos = bk*CAP + gbase[bk] + (j - (scan[bk] - hist[bk]));
    binned[outpos] = rbuf[j];
  }
}

// blocks [0,196): per-bucket CSR build (local hist+scan -> rowrange, LDS scatter,
// CSR in place). Block 196: graph-count scan -> ustart/istart/invcnt (256 thr,
// 2 elems each; same arithmetic as the old 512-thread k_scan_g).
__global__ __launch_bounds__(256) void k_csrbuild(const int* __restrict__ bcursor,
                                                  int* __restrict__ csrbin,
                                                  int2* __restrict__ rowrange,
                                                  const int* __restrict__ gcnt,
                                                  int* __restrict__ ustart,
                                                  int* __restrict__ istart,
                                                  float* __restrict__ invcnt) {
  __shared__ int lcnt[512];
  __shared__ int scan2[256];
  __shared__ int lcsr[CAP];
  int b = blockIdx.x;
  int tid = threadIdx.x;
  if (b == NBUCK) {
    int cu0 = gcnt[2*tid],     cu1 = gcnt[2*tid + 1];
    int ci0 = gcnt[NG + 2*tid], ci1 = gcnt[NG + 2*tid + 1];
    int su = cu0 + cu1, si = ci0 + ci1;
    lcnt[tid] = su; lcsr[tid] = si;
    __syncthreads();
    for (int o = 1; o < 256; o <<= 1) {
      int vu = (tid >= o) ? lcnt[tid - o] : 0;
      int vi = (tid >= o) ? lcsr[tid - o] : 0;
      __syncthreads();
      lcnt[tid] += vu; lcsr[tid] += vi;
      __syncthreads();
    }
    int eu = lcnt[tid] - su;   // exclusive pair prefix
    int ei = lcsr[tid] - si;
    ustart[2*tid]     = eu;        ustart[2*tid + 1] = eu + cu0;
    istart[2*tid]     = ei;        istart[2*tid + 1] = ei + ci0;
    if (tid == 255) { ustart[NG] = lcnt[255]; istart[NG] = lcsr[255]; }
    int c0 = cu0 + ci0, c1 = cu1 + ci1;
    invcnt[2*tid]     = 1.0f / (float)(c0 > 0 ? c0 : 1);
    invcnt[2*tid + 1] = 1.0f / (float)(c1 > 0 ? c1 : 1);
    return;
  }
  int slot0 = b << 9;
  int nslots = min(512, NTOT - slot0);
  int n = bcursor[b];
  int gb = b * CAP;
  lcnt[tid] = 0; lcnt[tid + 256] = 0;
  __syncthreads();
  for (int i = tid; i < n; i += 256) {
    int e = csrbin[gb + i];
    atomicAdd(&lcnt[e >> 17], 1);
  }
  __syncthreads();
  int v0 = lcnt[2*tid], v1 = lcnt[2*tid + 1];
  int ps = v0 + v1;
  scan2[tid] = ps;
  __syncthreads();
  for (int o = 1; o < 256; o <<= 1) {
    int v = (tid >= o) ? scan2[tid - o] : 0;
    __syncthreads();
    scan2[tid] += v;
    __syncthreads();
  }
  int e0 = scan2[tid] - ps;       // exclusive prefix for slot 2*tid
  int e1 = e0 + v0;
  if (2*tid < nslots)     rowrange[slot0 + 2*tid]     = make_int2(gb + e0, gb + e0 + v0);
  if (2*tid + 1 < nslots) rowrange[slot0 + 2*tid + 1] = make_int2(gb + e1, gb + e1 + v1);
  __syncthreads();
  lcnt[2*tid] = e0; lcnt[2*tid + 1] = e1;   // cursors
  __syncthreads();
  for (int i = tid; i < n; i += 256) {
    int e = csrbin[gb + i];
    int pos = atomicAdd(&lcnt[e >> 17], 1);
    lcsr[pos] = e & 0x1FFFF;
  }
  __syncthreads();
  for (int i = tid; i < n; i += 256) csrbin[gb + i] = lcsr[i];
}

// cast (warm-clock position, R6/R8 lesson: first-slot streaming ran at 833 GB/s).
// blocks [0,3125): castX 4x float4 MLP; [3125,3381): layer-0 castW;
// [3381,3893): zero P (replaces a memset dispatch).
__global__ __launch_bounds__(256) void k_cast(const float* __restrict__ xu,
                                              const float* __restrict__ xi,
                                              u16* __restrict__ xbu,
                                              u16* __restrict__ xbi,
                                              const float* __restrict__ WrelA,
                                              const float* __restrict__ WrootA,
                                              const float* __restrict__ WrelB,
                                              const float* __restrict__ WrootB,
                                              u16* __restrict__ WB,
                                              float* __restrict__ P) {
  int b = blockIdx.x;
  if (b < 3125) {
    int t = b*256 + threadIdx.x;           // < 800000
    const float4* su = (const float4*)xu;
    const float4* si = (const float4*)xi;
    float4 v0 = su[t];
    float4 v1 = su[t + Q4];
    float4 v2 = si[t];
    float4 v3 = si[t + Q4];
    ushort4* du = (ushort4*)xbu;
    ushort4* di = (ushort4*)xbi;
    du[t]      = cvt4(v0);
    du[t + Q4] = cvt4(v1);
    di[t]      = cvt4(v2);
    di[t + Q4] = cvt4(v3);
  } else if (b < 3381) {
    int idx = (b - 3125)*256 + threadIdx.x;   // 65536 layer-0 weight entries
    int lr = idx >> 15;
    int rem = idx & 32767;
    int h = rem >> 8;
    int k = rem & 255;
    int rel = lr & 1;
    const float* Wr = rel ? WrelB : WrelA;
    const float* Wo = rel ? WrootB : WrootA;
    float v = (k < FD) ? Wr[h*FD + k] : Wo[h*FD + (k-FD)];
    WB[idx] = f2bf(v);
  } else {
    int idx = (b - 3381)*256 + threadIdx.x;   // 131072 P floats
    P[idx] = 0.f;
  }
}

// merged BN finalize + fold + feats:
// every block recomputes sc/sh from accSQ bank (cheap, bit-identical).
// mode 0: blocks [0,64) WBs scale, [64,66) bvec, [66,322) feats
// mode 1 (last layer): all 256 blocks feats.
// feats block fb==0 also zeroes the OTHER accSQ bank for the next gemm.
// feats blocks zero their P entries after reading (ready for next layer).
__global__ __launch_bounds__(256) void k_bnfold2(const float* __restrict__ WrelA,
                                                 const float* __restrict__ WrootA,
                                                 const float* __restrict__ WrelB,
                                                 const float* __restrict__ WrootB,
                                                 int l,
                                                 const float* __restrict__ accSQ,
                                                 float* __restrict__ accSQz,
                                                 const float* __restrict__ gu,
                                                 const float* __restrict__ bu_,
                                                 const float* __restrict__ gi_,
                                                 const float* __restrict__ bi_,
                                                 u16* __restrict__ WBs,
                                                 float* __restrict__ bvec,
                                                 float* __restrict__ P,
                                                 const int* __restrict__ ustart,
                                                 const int* __restrict__ istart,
                                                 const float* __restrict__ invcnt,
                                                 float* __restrict__ feats,
                                                 int mode) {
  __shared__ float sc_l[256], sh_l[256];
  int tid = threadIdx.x;
  {
    int type = tid >> 7;
    int c = tid & 127;
    float s = accSQ[tid];
    float q = accSQ[256 + tid];
    float inv = 1.0f / (float)NN;
    float mean = s * inv;
    float var = q * inv - mean*mean;
    float rstd = rsqrtf(var + BNEPS);
    float g = type ? gi_[c] : gu[c];
    float bb = type ? bi_[c] : bu_[c];
    float sc = rstd * g;
    sc_l[tid] = sc;
    sh_l[tid] = bb - mean * sc;
  }
  __syncthreads();
  int b = blockIdx.x;
  int nfold = mode ? 0 : 66;
  if (b < nfold) {
    if (b < 64) {
      int e = b*256 + tid;          // 16384 entries x 4 consecutive k
      int rel = e >> 13;
      int rem = e & 8191;
      int h = rem >> 6;
      int k0 = (rem & 63) * 4;
      const float* Wr = rel ? WrelB : WrelA;
      const float* Wo = rel ? WrootB : WrootA;
      const float* scs = sc_l + (rel ? 128 : 0);
      const float* scd = sc_l + (rel ? 0 : 128);
      u16 t[4];
      #pragma unroll
      for (int j = 0; j < 4; j++) {
        int k = k0 + j;
        float v = (k < FD) ? Wr[((size_t)l*FD + h)*FD + k] * scs[k]
                           : Wo[((size_t)l*FD + h)*FD + (k - FD)] * scd[k - FD];
        t[j] = f2bf(v);
      }
      ushort4 o = { t[0], t[1], t[2], t[3] };
      *(ushort4*)(WBs + rel*32768 + h*256 + k0) = o;
    } else {
      int vid = (b - 64)*256 + tid; // 0..511
      int kind = vid >> 8;          // 0 = b1 (Wrel, sh_src), 1 = b2 (Wroot, sh_dst)
      int rel = (vid >> 7) & 1;
      int h = vid & 127;
      const float* W = kind ? (rel ? WrootB : WrootA) : (rel ? WrelB : WrelA);
      const float* sh = sh_l + ((kind ^ rel) ? 128 : 0);
      const float* wrow = W + ((size_t)l*FD + h)*FD;
      float s = 0.f;
      #pragma unroll
      for (int k = 0; k < FD; k += 4) {
        float4 wv = *(const float4*)(wrow + k);
        float4 sv = { sh[k], sh[k+1], sh[k+2], sh[k+3] };
        s += wv.x*sv.x + wv.y*sv.y + wv.z*sv.z + wv.w*sv.w;
      }
      bvec[kind*256 + rel*128 + h] = s;
    }
  } else {
    int fb = b - nfold;             // 0..255
    if (fb == 0) { accSQz[tid] = 0.f; accSQz[256 + tid] = 0.f; }
    int g = fb*2 + (tid >> 7);
    int ch = tid & 127;
    size_t iu = (size_t)g*FD + ch;
    size_t ii = (size_t)NG*FD + iu;
    float pu = P[iu];
    float pi = P[ii];
    float cu = (float)(ustart[g+1] - ustart[g]);
    float ci = (float)(istart[g+1] - istart[g]);
    feats[iu] = invcnt[g] * (sc_l[ch]*pu + cu*sh_l[ch]
                           + sc_l[128+ch]*pi + ci*sh_l[128+ch]);
    P[iu] = 0.f; P[ii] = 0.f;
  }
}

// 4 rows per wave (grid 6250): same per-row body as before, 4x fewer block
// launches (R8: occupancy 66-71% with 4-row blocks -> block churn suspected).
// 16B/lane loads, quarter-waves take different edges, 2 chains w/ prefetch.
template<int RELU>
__global__ __launch_bounds__(256) void k_gather(const u16* __restrict__ curU,
                                                const u16* __restrict__ curI,
                                                const int2* __restrict__ rowrange,
                                                const int* __restrict__ csr,
                                                u16* __restrict__ aggI,
                                                u16* __restrict__ aggU) {
  int b = blockIdx.x;
  int half = b >= 3125;
  int blk = half ? b - 3125 : b;
  const u16* src = half ? curI : curU;
  u16* out = half ? aggU : aggI;
  int slotbase = half ? NN : 0;
  int wid = __builtin_amdgcn_readfirstlane(threadIdx.x >> 6);
  int lane = threadIdx.x & 63;
  int q = lane >> 4;
  int c16 = (lane & 15) * 8;      // 8 bf16 = 16B per lane
  const u16* sp = src + c16;
  int rowbase = blk*16 + wid*4;
  for (int rr = 0; rr < 4; rr++) {
    int row = rowbase + rr;
    int2 pr = rowrange[slotbase + row];
    int p = pr.x, pe = pr.y;
    float a0[8], a1[8];
    #pragma unroll
    for (int j = 0; j < 8; j++) { a0[j] = 0.f; a1[j] = 0.f; }
    if (p + 8 <= pe) {
      int i0 = csr[p + q], i1 = csr[p + 4 + q];
      while (p + 16 <= pe) {
        int n0 = csr[p + 8 + q], n1 = csr[p + 12 + q];
        int4 v0 = *(const int4*)(sp + (size_t)i0*FD);
        int4 v1 = *(const int4*)(sp + (size_t)i1*FD);
        accT8<RELU>(a0, v0); accT8<RELU>(a1, v1);
        i0 = n0; i1 = n1; p += 8;
      }
      int4 v0 = *(const int4*)(sp + (size_t)i0*FD);
      int4 v1 = *(const int4*)(sp + (size_t)i1*FD);
      accT8<RELU>(a0, v0); accT8<RELU>(a1, v1);
      p += 8;
    }
    int rem = pe - p;               // 0..7
    if (q < rem) {
      int s = csr[p + q];
      accT8<RELU>(a0, *(const int4*)(sp + (size_t)s*FD));
    }
    if (q + 4 < rem) {
      int s = csr[p + 4 + q];
      accT8<RELU>(a1, *(const int4*)(sp + (size_t)s*FD));
    }
    #pragma unroll
    for (int j = 0; j < 8; j++) a0[j] += a1[j];
    #pragma unroll
    for (int j = 0; j < 8; j++) {
      a0[j] += __shfl_xor(a0[j], 16);
      a0[j] += __shfl_xor(a0[j], 32);
    }
    if (q == 0) {
      int4 o;
      o.x = (unsigned)f2bf(a0[0]) | ((unsigned)f2bf(a0[1]) << 16);
      o.y = (unsigned)f2bf(a0[2]) | ((unsigned)f2bf(a0[3]) << 16);
      o.z = (unsigned)f2bf(a0[4]) | ((unsigned)f2bf(a0[5]) << 16);
      o.w = (unsigned)f2bf(a0[6]) | ((unsigned)f2bf(a0[7]) << 16);
      *(int4*)(out + (size_t)row*FD + c16) = o;
    }
  }
}

// MFMA bf16 GEMM + fused BN-stat + per-graph pool.
// new[n,h] = [agg|cur][n,0:256] @ WB[h,0:256]^T + bias'[n,h]
// Epilogue: relu-stats from registers (shuffle+atomics), coalesced C
// writeback via LDS tile Cs[128][132], per-graph pooling read back from Cs
// with REGISTER accumulation per graph-segment -> ONE global atomic per
// (graph,col,half). No per-element atomics (R4 lesson: 12.8M LDS atomics
// serialized the kernel to 120us).
__global__ __launch_bounds__(256) void k_gemm(u16* __restrict__ newU,
                                              u16* __restrict__ newI,
                                              const u16* __restrict__ curU,
                                              const u16* __restrict__ curI,
                                              const u16* __restrict__ WBl,
                                              const float* __restrict__ bI2U,
                                              const float* __restrict__ bU2I,
                                              float* __restrict__ accSQ,
                                              const float* __restrict__ bvec,
                                              const int2* __restrict__ rowrange,
                                              const int* __restrict__ bu,
                                              const int* __restrict__ bi,
                                              const int* __restrict__ ustart,
                                              const int* __restrict__ istart,
                                              float* __restrict__ P,
                                              int fold) {
  __shared__ u16 smem[128*72*2];            // As | Bs; reused as Cs[128][132]
  __shared__ float Sred[2][4][128];
  u16* As = smem;
  u16* Bs = smem + 128*72;
  u16* Cs = smem;                           // 128*132 = 16896 u16 <= 18432
  int ty = blockIdx.y;
  u16* A1 = ty ? newI : newU;
  const u16* A2 = ty ? curI : curU;
  const u16* WBp = ty ? WBl : (WBl + 32768);
  const float* bias = ty ? bU2I : bI2U;
  const float* b1p = bvec + (ty ? 0 : 128);
  const float* b2p = bvec + 256 + (ty ? 0 : 128);
  const int* batch = ty ? bi : bu;
  const int* st = ty ? istart : ustart;
  float* Pg = P + (size_t)ty*NG*FD;
  int slot0 = ty ? 0 : NN;        // dst slots: items [0,NN), users [NN,2NN)
  int tid = threadIdx.x;
  int n0 = blockIdx.x * 128;
  int w = __builtin_amdgcn_readfirstlane(tid >> 6);
  int lane = tid & 63;
  int l15 = lane & 15;
  int quad = lane >> 4;
  f32x4 acc[2][8];
  #pragma unroll
  for (int tr = 0; tr < 2; tr++)
    #pragma unroll
    for (int tc = 0; tc < 8; tc++)
      acc[tr][tc] = (f32x4){0.f,0.f,0.f,0.f};

  for (int ch = 0; ch < 4; ch++) {
    const u16* Ap = (ch < 2) ? ((const u16*)A1 + ch*64) : (A2 + (ch-2)*64);
    int dorelu = fold && (ch >= 2);
    #pragma unroll
    for (int i = 0; i < 4; i++) {
      int e = i*256 + tid;
      int r = e >> 3, seg = e & 7;
      int4 v = {0,0,0,0};
      int gr = n0 + r;
      if (gr < NN) v = *(const int4*)(Ap + (size_t)gr*FD + seg*8);
      if (dorelu) { v.x = relu2(v.x); v.y = relu2(v.y); v.z = relu2(v.z); v.w = relu2(v.w); }
      *(int4*)&As[r*72 + seg*8] = v;
    }
    #pragma unroll
    for (int i = 0; i < 4; i++) {
      int e = i*256 + tid;
      int r = e >> 3, seg = e & 7;
      int4 v = *(const int4*)(WBp + r*256 + ch*64 + seg*8);
      *(int4*)&Bs[r*72 + seg*8] = v;
    }
    __syncthreads();
    #pragma unroll
    for (int ks = 0; ks < 2; ks++) {
      int kb = ks*32 + quad*8;
      short8 af0 = *(const short8*)&As[(w*32 + l15)*72 + kb];
      short8 af1 = *(const short8*)&As[(w*32 + 16 + l15)*72 + kb];
      short8 bf[8];
      #pragma unroll
      for (int tc = 0; tc < 8; tc++)
        bf[tc] = *(const short8*)&Bs[(tc*16 + l15)*72 + kb];
      #pragma unroll
      for (int tc = 0; tc < 8; tc++) {
        acc[0][tc] = __builtin_amdgcn_mfma_f32_16x16x32_bf16(af0, bf[tc], acc[0][tc], 0, 0, 0);
        acc[1][tc] = __builtin_amdgcn_mfma_f32_16x16x32_bf16(af1, bf[tc], acc[1][tc], 0, 0, 0);
      }
    }
    __syncthreads();
  }
  float sv[8], qv[8], bj[8], b1j[8];
  #pragma unroll
  for (int tc = 0; tc < 8; tc++) {
    int col = tc*16 + l15;
    float base = bias[col];
    if (fold) { base += b2p[col]; b1j[tc] = b1p[col]; } else b1j[tc] = 0.f;
    bj[tc] = base;
    sv[tc] = 0.f; qv[tc] = 0.f;
  }
  float dg[2][4] = {{0.f,0.f,0.f,0.f},{0.f,0.f,0.f,0.f}};
  if (fold) {
    #pragma unroll
    for (int tr = 0; tr < 2; tr++)
      #pragma unroll
      for (int gq = 0; gq < 4; gq++) {
        int r = n0 + w*32 + tr*16 + quad*4 + gq;
        if (r < NN) {
          int2 rr = rowrange[slot0 + r];
          dg[tr][gq] = (float)(rr.y - rr.x);
        }
      }
  }
  #pragma unroll
  for (int tr = 0; tr < 2; tr++) {
    int rl0 = w*32 + tr*16 + quad*4;
    int rbase = n0 + rl0;
    #pragma unroll
    for (int tc = 0; tc < 8; tc++) {
      int col = tc*16 + l15;
      #pragma unroll
      for (int g = 0; g < 4; g++) {
        int r = rbase + g;
        float v = acc[tr][tc][g] + bj[tc] + dg[tr][g]*b1j[tc];
        Cs[(rl0 + g)*132 + col] = f2bf(v);
        if (r < NN) {
          float y = v > 0.f ? v : 0.f;
          sv[tc] += y; qv[tc] += y*y;
        }
      }
    }
  }
  #pragma unroll
  for (int tc = 0; tc < 8; tc++) {
    sv[tc] += __shfl_xor(sv[tc], 16); qv[tc] += __shfl_xor(qv[tc], 16);
    sv[tc] += __shfl_xor(sv[tc], 32); qv[tc] += __shfl_xor(qv[tc], 32);
  }
  if (quad == 0) {
    #pragma unroll
    for (int tc = 0; tc < 8; tc++) {
      Sred[0][w][tc*16 + l15] = sv[tc];
      Sred[1][w][tc*16 + l15] = qv[tc];
    }
  }
  __syncthreads();          // covers Cs writes + Sred writes
  if (tid < 128) {
    float s = Sred[0][0][tid] + Sred[0][1][tid] + Sred[0][2][tid] + Sred[0][3][tid];
    float q = Sred[1][0][tid] + Sred[1][1][tid] + Sred[1][2][tid] + Sred[1][3][tid];
    atomicAdd(&accSQ[ty*128 + tid], s);
    atomicAdd(&accSQ[256 + ty*128 + tid], q);
  }
  // per-graph pooling from Cs: thread = (col, half-of-rows). Graph segments
  // are contiguous (rows graph-sorted); boundaries straight from st[].
  {
    int col = tid & 127;
    int half = tid >> 7;
    int rlo = half * 64, rhi = rlo + 64;     // local row range
    int gg0 = batch[n0];
    int lastr = n0 + 127; if (lastr > NN - 1) lastr = NN - 1;
    int gg1 = batch[lastr];
    for (int g = gg0; g <= gg1; ++g) {
      int lo = st[g]   - n0; lo = lo < rlo ? rlo : lo;
      int hi = st[g+1] - n0; hi = hi > rhi ? rhi : hi;
      float s = 0.f;
      for (int r = lo; r < hi; ++r) {
        float v = bf2f(Cs[r*132 + col]);
        s += v > 0.f ? v : 0.f;
      }
      if (hi > lo) atomicAdd(&Pg[(size_t)g*FD + col], s);
    }
  }
  // coalesced write-back: per pass j, block covers rows j*16..j*16+15 (4 KB)
  int prow = tid >> 4;            // 0..15
  int pc = (tid & 15) * 8;        // u16 col base (16B per lane)
  #pragma unroll
  for (int j = 0; j < 8; j++) {
    int row = j*16 + prow;
    int gr = n0 + row;
    int4 vv = *(const int4*)&Cs[row*132 + pc];
    if (gr < NN) *(int4*)(A1 + (size_t)gr*FD + pc) = vv;
  }
}

__global__ __launch_bounds__(256) void k_heads(const float* __restrict__ feats,
                                               const float* __restrict__ fcW,
                                               const float* __restrict__ fcb,
                                               float* __restrict__ logits) {
  int idx = blockIdx.x*256 + threadIdx.x;
  if (idx >= LOGITS_N) return;
  int l = idx >> 13;
  int rem = idx & 8191;
  int g = rem >> 4;
  int c = rem & 15;
  const float* f = feats + ((size_t)l*NG + g)*FD;
  const float* w = fcW + ((size_t)l*NC + c)*FD;
  float s = 0.f;
  #pragma unroll
  for (int k = 0; k < FD; k += 4) {
    float4 fv = *(const float4*)(f + k);
    float4 wv = *(const float4*)(w + k);
    s += fv.x*wv.x + fv.y*wv.y + fv.z*wv.z + fv.w*wv.w;
  }
  logits[idx] = s + fcb[l*NC + c];
}

extern "C" void kernel_launch(void* const* d_in, const int* in_sizes, int n_in,
                              void* d_out, int out_size, void* d_ws, size_t ws_size,
                              hipStream_t stream) {
  const float* x_user   = (const float*)d_in[0];
  const float* x_item   = (const float*)d_in[1];
  const int*   eu2i     = (const int*)d_in[2];
  const int*   ei2u     = (const int*)d_in[3];
  const int*   bu       = (const int*)d_in[4];
  const int*   bi       = (const int*)d_in[5];
  const float* Wrel_u2i = (const float*)d_in[6];
  const float* Wroot_u2i= (const float*)d_in[7];
  const float* b_u2i    = (const float*)d_in[8];
  const float* Wrel_i2u = (const float*)d_in[9];
  const float* Wroot_i2u= (const float*)d_in[10];
  const float* b_i2u    = (const float*)d_in[11];
  const float* bn_g_user= (const float*)d_in[12];
  const float* bn_b_user= (const float*)d_in[13];
  const float* bn_g_item= (const float*)d_in[14];
  const float* bn_b_item= (const float*)d_in[15];
  const float* fcW      = (const float*)d_in[16];
  const float* fcb      = (const float*)d_in[17];

  char* ws = (char*)d_ws;
  int*   gcnt   = (int*)(ws + OFF_GCNT);
  int*   bcursor= (int*)(ws + OFF_BCUR);
  float* accSQ  = (float*)(ws + OFF_ACC);     // 2 banks x 512 f32
  int*   ustart = (int*)(ws + OFF_USTART);
  int*   istart = (int*)(ws + OFF_ISTART);
  float* invcnt = (float*)(ws + OFF_INVCNT);
  int2*  rowrange = (int2*)(ws + OFF_ROWRANGE);
  u16*   WB     = (u16*)(ws + OFF_WB);
  int*   csrbin = (int*)(ws + OFF_CSR);
  u16*   p0I    = (u16*)(ws + OFF_N0I);       // pair0 item
  u16*   p0U    = (u16*)(ws + OFF_N0U);       // pair0 user
  float* P      = (float*)(ws + OFF_P);
  u16*   WBs    = (u16*)(ws + OFF_WBS);
  float* bvec   = (float*)(ws + OFF_BVEC);
  u16*   p1U    = (u16*)(ws + OFF_XU0);       // pair1 user (= initial cast)
  u16*   p1I    = (u16*)(ws + OFF_XI0);       // pair1 item (= initial cast)
  float* fout   = (float*)d_out;
  float* featsAll = fout + LOGITS_N;

  float* bank0 = accSQ;
  float* bank1 = accSQ + 512;

  hipMemsetAsync(ws, 0, MEMSET_BYTES, stream);
  // small kernels first: absorb the post-reset cold window (R6/R8-verified).
  k_bin<<<NBINBLK + 391, 256, 0, stream>>>(eu2i, ei2u, bcursor, csrbin,
                                           bu, bi, gcnt);
  k_csrbuild<<<NBUCK + 1, 256, 0, stream>>>(bcursor, csrbin, rowrange,
                                            gcnt, ustart, istart, invcnt);
  k_cast<<<3893, 256, 0, stream>>>(x_user, x_item, p1U, p1I,
                                   Wrel_u2i, Wroot_u2i, Wrel_i2u, Wroot_i2u,
                                   WB, P);

  // ---- layer 0: sources are raw inputs (no relu, no BN fold), pair1 = x0 ----
  k_gather<0><<<NGBLK, 256, 0, stream>>>(p1U, p1I, rowrange, csrbin, p0I, p0U);
  k_gemm<<<dim3(NBLK,2), 256, 0, stream>>>(p0U, p0I, p1U, p1I, WB,
                                           b_i2u, b_u2i, bank0,
                                           bvec, rowrange, bu, bi,
                                           ustart, istart, P, 0);
  k_bnfold2<<<322, 256, 0, stream>>>(Wrel_u2i, Wroot_u2i, Wrel_i2u, Wroot_i2u,
                                     1, bank0, bank1,
                                     bn_g_user, bn_b_user, bn_g_item, bn_b_item,
                                     WBs, bvec, P, ustart, istart, invcnt,
                                     featsAll, 0);

  // ---- layer 1: relu in gather/staging, BN folded; writes pair1 (x0 dead) ----
  k_gather<1><<<NGBLK, 256, 0, stream>>>(p0U, p0I, rowrange, csrbin, p1I, p1U);
  k_gemm<<<dim3(NBLK,2), 256, 0, stream>>>(p1U, p1I, p0U, p0I, WBs,
                                           b_i2u + FD, b_u2i + FD, bank1,
                                           bvec, rowrange, bu, bi,
                                           ustart, istart, P, 1);
  k_bnfold2<<<322, 256, 0, stream>>>(Wrel_u2i, Wroot_u2i, Wrel_i2u, Wroot_i2u,
                                     2, bank1, bank0,
                                     bn_g_user, bn_b_user, bn_g_item, bn_b_item,
                                     WBs, bvec, P, ustart, istart, invcnt,
                                     featsAll + NG*FD, 0);

  // ---- layer 2 ----
  k_gather<1><<<NGBLK, 256, 0, stream>>>(p1U, p1I, rowrange, csrbin, p0I, p0U);
  k_gemm<<<dim3(NBLK,2), 256, 0, stream>>>(p0U, p0I, p1U, p1I, WBs,
                                           b_i2u + 2*FD, b_u2i + 2*FD, bank0,
                                           bvec, rowrange, bu, bi,
                                           ustart, istart, P, 1);
  k_bnfold2<<<256, 256, 0, stream>>>(Wrel_u2i, Wroot_u2i, Wrel_i2u, Wroot_i2u,
                                     2, bank0, bank1,
                                     bn_g_user, bn_b_user, bn_g_item, bn_b_item,
                                     WBs, bvec, P, ustart, istart, invcnt,
                                     featsAll + 2*NG*FD, 1);

  k_heads<<<96, 256, 0, stream>>>(featsAll, fcW, fcb, fout);
}

// Round 10
// 468.172 us; speedup vs baseline: 1.5589x; 1.0172x over previous
//
#include <hip/hip_runtime.h>

#define NN 50000
#define FD 128
#define NE 800000
#define NG 512
#define NC 16
#define NL 3
#define NTOT 100000
#define NBLK 391            // ceil(100000/256) and ceil(50000/128)
#define NBUCK 196           // ceil(100000/512) slot-buckets
#define CAP 10240           // per-bucket capacity (avg 8163, sigma ~90)
#define BINTILE 2048
#define NBINBLK 782         // ceil(1600000/2048)
#define BNEPS 1e-5f
#define LOGITS_N (NL*NG*NC)
#define Q4 800000           // 50000*128/4 float4s per half-array

typedef unsigned short u16;
typedef unsigned char u8;
typedef __attribute__((ext_vector_type(8))) short short8;
typedef __attribute__((ext_vector_type(4))) float f32x4;

// ---- workspace layout (bytes) ----
#define OFF_GCNT     0ul          // 2*512 int
#define OFF_BCUR     4096ul       // 196 int
#define OFF_ACC      5120ul       // 2 banks x 512 f32 (S[256],Q[256] each)
#define MEMSET_BYTES 9216ul       // covers GCNT + BCUR + ACC banks
#define OFF_USTART   9728ul       // 513 int
#define OFF_ISTART   12288ul      // 513 int
#define OFF_INVCNT   14848ul      // 512 f32
#define OFF_ROWRANGE 16896ul      // 100000 int2
#define OFF_WB       817152ul     // layer-0 2*128*256 bf16
#define OFF_CSR      1210368ul    // 196*10240 int (binned, then CSR in place)
#define OFF_N0I      9238528ul    // pair0 item (50000*128 bf16)
#define OFF_N0U      22038528ul   // pair0 user
#define OFF_P        34838528ul   // [2][512][128] f32 = 524288 B
#define OFF_WBS      35362816ul   // 2*128*256 bf16 scaled weights
#define OFF_BVEC     35493888ul   // b1[2][128] | b2[2][128] f32
#define OFF_XU0      60438528ul   // pair1 user / initial cast
#define OFF_XI0      73238528ul   // pair1 item / initial cast

static __device__ __forceinline__ float bf2f(u16 v) {
  return __uint_as_float(((unsigned)v) << 16);
}
static __device__ __forceinline__ u16 f2bf(float f) {
  unsigned u = __float_as_uint(f);
  return (u16)((u + 0x7FFFu + ((u >> 16) & 1u)) >> 16);
}
template<int RELU>
static __device__ __forceinline__ void accT8(float* a, int4 v) {
  unsigned w[4] = {(unsigned)v.x, (unsigned)v.y, (unsigned)v.z, (unsigned)v.w};
  #pragma unroll
  for (int i = 0; i < 4; i++) {
    float lo = __uint_as_float(w[i] << 16);
    float hi = __uint_as_float(w[i] & 0xffff0000u);
    if (RELU) { lo = lo > 0.f ? lo : 0.f; hi = hi > 0.f ? hi : 0.f; }
    a[2*i]   += lo;
    a[2*i+1] += hi;
  }
}
static __device__ __forceinline__ int relu2(int w) {
  int lo = (w & 0x00008000) ? 0 : (w & 0x0000FFFF);
  int hi = (w < 0)          ? 0 : (int)(w & 0xFFFF0000u);
  return lo | hi;
}
static __device__ __forceinline__ ushort4 cvt4(float4 v) {
  ushort4 o = { f2bf(v.x), f2bf(v.y), f2bf(v.z), f2bf(v.w) };
  return o;
}

// bucket edges by dst-slot>>9 into fixed-capacity regions; entry (lslot:9|src:17).
// Blocks [NBINBLK, NBINBLK+391): batch histogram (ballot run-length, sorted ids).
__global__ __launch_bounds__(256) void k_bin(const int* __restrict__ eu2i,
                                             const int* __restrict__ ei2u,
                                             int* __restrict__ bcursor,
                                             int* __restrict__ binned,
                                             const int* __restrict__ bu,
                                             const int* __restrict__ bi,
                                             int* __restrict__ gcnt) {
  if (blockIdx.x >= NBINBLK) {
    int i = (blockIdx.x - NBINBLK)*256 + threadIdx.x;
    int lane = threadIdx.x & 63;
    bool valid = i < NTOT;
    int slot = -1;
    if (valid) {
      int type = i >= NN;
      int g = type ? bi[i-NN] : bu[i];
      slot = type*NG + g;
    }
    int prevslot = __shfl_up(slot, 1);
    bool head = valid && (lane == 0 || prevslot != slot);
    unsigned long long hb = __ballot(head);
    int nvalid = __popcll(__ballot(valid));   // valid lanes form a prefix
    if (head) {
      unsigned long long higher = (lane < 63) ? (hb >> (lane+1)) : 0ull;
      int next = higher ? (lane + __ffsll(higher)) : 64;
      int end = next < nvalid ? next : nvalid;
      atomicAdd(&gcnt[slot], end - lane);
    }
    return;
  }
  __shared__ int hist[256];
  __shared__ int scan[256];
  __shared__ int gbase[256];
  __shared__ int rbuf[BINTILE];
  __shared__ u8 rbk[BINTILE];
  int tid = threadIdx.x;
  int base = blockIdx.x * BINTILE;
  hist[tid] = 0;
  __syncthreads();
  int packr[8], bkr[8], rankr[8];
  #pragma unroll
  for (int c = 0; c < 8; c++) {
    int idx = base + c*256 + tid;
    if (idx < 2*NE) {
      int rel = idx >= NE;
      int e = rel ? idx - NE : idx;
      const int* edge = rel ? ei2u : eu2i;
      int s = edge[e];
      int d = edge[NE + e];
      int slot = d + (rel ? NN : 0);
      int bk = slot >> 9;
      bkr[c] = bk;
      packr[c] = ((slot & 511) << 17) | s;
      rankr[c] = atomicAdd(&hist[bk], 1);
    } else bkr[c] = -1;
  }
  __syncthreads();
  scan[tid] = hist[tid];
  __syncthreads();
  for (int o = 1; o < 256; o <<= 1) {
    int v = (tid >= o) ? scan[tid - o] : 0;
    __syncthreads();
    scan[tid] += v;
    __syncthreads();
  }
  if (tid < NBUCK && hist[tid] > 0)
    gbase[tid] = atomicAdd(&bcursor[tid], hist[tid]);
  __syncthreads();
  #pragma unroll
  for (int c = 0; c < 8; c++) {
    if (bkr[c] >= 0) {
      int bk = bkr[c];
      int lpos = scan[bk] - hist[bk] + rankr[c];
      rbuf[lpos] = packr[c];
      rbk[lpos] = (u8)bk;
    }
  }
  __syncthreads();
  int nv = min(BINTILE, 2*NE - base);
  for (int j = tid; j < nv; j += 256) {
    int bk = rbk[j];
    int outpos = bk*CAP + gbase[bk] + (j - (scan[bk] - hist[bk]));
    binned[outpos] = rbuf[j];
  }
}

// blocks [0,196): per-bucket CSR build (local hist+scan -> rowrange, LDS scatter,
// CSR in place). Block 196: graph-count scan -> ustart/istart/invcnt (256 thr,
// 2 elems each; same arithmetic as the old 512-thread k_scan_g).
__global__ __launch_bounds__(256) void k_csrbuild(const int* __restrict__ bcursor,
                                                  int* __restrict__ csrbin,
                                                  int2* __restrict__ rowrange,
                                                  const int* __restrict__ gcnt,
                                                  int* __restrict__ ustart,
                                                  int* __restrict__ istart,
                                                  float* __restrict__ invcnt) {
  __shared__ int lcnt[512];
  __shared__ int scan2[256];
  __shared__ int lcsr[CAP];
  int b = blockIdx.x;
  int tid = threadIdx.x;
  if (b == NBUCK) {
    int cu0 = gcnt[2*tid],     cu1 = gcnt[2*tid + 1];
    int ci0 = gcnt[NG + 2*tid], ci1 = gcnt[NG + 2*tid + 1];
    int su = cu0 + cu1, si = ci0 + ci1;
    lcnt[tid] = su; lcsr[tid] = si;
    __syncthreads();
    for (int o = 1; o < 256; o <<= 1) {
      int vu = (tid >= o) ? lcnt[tid - o] : 0;
      int vi = (tid >= o) ? lcsr[tid - o] : 0;
      __syncthreads();
      lcnt[tid] += vu; lcsr[tid] += vi;
      __syncthreads();
    }
    int eu = lcnt[tid] - su;   // exclusive pair prefix
    int ei = lcsr[tid] - si;
    ustart[2*tid]     = eu;        ustart[2*tid + 1] = eu + cu0;
    istart[2*tid]     = ei;        istart[2*tid + 1] = ei + ci0;
    if (tid == 255) { ustart[NG] = lcnt[255]; istart[NG] = lcsr[255]; }
    int c0 = cu0 + ci0, c1 = cu1 + ci1;
    invcnt[2*tid]     = 1.0f / (float)(c0 > 0 ? c0 : 1);
    invcnt[2*tid + 1] = 1.0f / (float)(c1 > 0 ? c1 : 1);
    return;
  }
  int slot0 = b << 9;
  int nslots = min(512, NTOT - slot0);
  int n = bcursor[b];
  int gb = b * CAP;
  lcnt[tid] = 0; lcnt[tid + 256] = 0;
  __syncthreads();
  for (int i = tid; i < n; i += 256) {
    int e = csrbin[gb + i];
    atomicAdd(&lcnt[e >> 17], 1);
  }
  __syncthreads();
  int v0 = lcnt[2*tid], v1 = lcnt[2*tid + 1];
  int ps = v0 + v1;
  scan2[tid] = ps;
  __syncthreads();
  for (int o = 1; o < 256; o <<= 1) {
    int v = (tid >= o) ? scan2[tid - o] : 0;
    __syncthreads();
    scan2[tid] += v;
    __syncthreads();
  }
  int e0 = scan2[tid] - ps;       // exclusive prefix for slot 2*tid
  int e1 = e0 + v0;
  if (2*tid < nslots)     rowrange[slot0 + 2*tid]     = make_int2(gb + e0, gb + e0 + v0);
  if (2*tid + 1 < nslots) rowrange[slot0 + 2*tid + 1] = make_int2(gb + e1, gb + e1 + v1);
  __syncthreads();
  lcnt[2*tid] = e0; lcnt[2*tid + 1] = e1;   // cursors
  __syncthreads();
  for (int i = tid; i < n; i += 256) {
    int e = csrbin[gb + i];
    int pos = atomicAdd(&lcnt[e >> 17], 1);
    lcsr[pos] = e & 0x1FFFF;
  }
  __syncthreads();
  for (int i = tid; i < n; i += 256) csrbin[gb + i] = lcsr[i];
}

// cast (warm-clock position, R6/R8 lesson: first-slot streaming ran at 833 GB/s).
// blocks [0,3125): castX 4x float4 MLP; [3125,3381): layer-0 castW;
// [3381,3893): zero P (replaces a memset dispatch).
__global__ __launch_bounds__(256) void k_cast(const float* __restrict__ xu,
                                              const float* __restrict__ xi,
                                              u16* __restrict__ xbu,
                                              u16* __restrict__ xbi,
                                              const float* __restrict__ WrelA,
                                              const float* __restrict__ WrootA,
                                              const float* __restrict__ WrelB,
                                              const float* __restrict__ WrootB,
                                              u16* __restrict__ WB,
                                              float* __restrict__ P) {
  int b = blockIdx.x;
  if (b < 3125) {
    int t = b*256 + threadIdx.x;           // < 800000
    const float4* su = (const float4*)xu;
    const float4* si = (const float4*)xi;
    float4 v0 = su[t];
    float4 v1 = su[t + Q4];
    float4 v2 = si[t];
    float4 v3 = si[t + Q4];
    ushort4* du = (ushort4*)xbu;
    ushort4* di = (ushort4*)xbi;
    du[t]      = cvt4(v0);
    du[t + Q4] = cvt4(v1);
    di[t]      = cvt4(v2);
    di[t + Q4] = cvt4(v3);
  } else if (b < 3381) {
    int idx = (b - 3125)*256 + threadIdx.x;   // 65536 layer-0 weight entries
    int lr = idx >> 15;
    int rem = idx & 32767;
    int h = rem >> 8;
    int k = rem & 255;
    int rel = lr & 1;
    const float* Wr = rel ? WrelB : WrelA;
    const float* Wo = rel ? WrootB : WrootA;
    float v = (k < FD) ? Wr[h*FD + k] : Wo[h*FD + (k-FD)];
    WB[idx] = f2bf(v);
  } else {
    int idx = (b - 3381)*256 + threadIdx.x;   // 131072 P floats
    P[idx] = 0.f;
  }
}

// merged BN finalize + fold + feats:
// every block recomputes sc/sh from accSQ bank (cheap, bit-identical).
// mode 0: blocks [0,64) WBs scale, [64,66) bvec, [66,322) feats
// mode 1 (last layer): all 256 blocks feats.
// feats block fb==0 also zeroes the OTHER accSQ bank for the next gemm.
// feats blocks zero their P entries after reading (ready for next layer).
__global__ __launch_bounds__(256) void k_bnfold2(const float* __restrict__ WrelA,
                                                 const float* __restrict__ WrootA,
                                                 const float* __restrict__ WrelB,
                                                 const float* __restrict__ WrootB,
                                                 int l,
                                                 const float* __restrict__ accSQ,
                                                 float* __restrict__ accSQz,
                                                 const float* __restrict__ gu,
                                                 const float* __restrict__ bu_,
                                                 const float* __restrict__ gi_,
                                                 const float* __restrict__ bi_,
                                                 u16* __restrict__ WBs,
                                                 float* __restrict__ bvec,
                                                 float* __restrict__ P,
                                                 const int* __restrict__ ustart,
                                                 const int* __restrict__ istart,
                                                 const float* __restrict__ invcnt,
                                                 float* __restrict__ feats,
                                                 int mode) {
  __shared__ float sc_l[256], sh_l[256];
  int tid = threadIdx.x;
  {
    int type = tid >> 7;
    int c = tid & 127;
    float s = accSQ[tid];
    float q = accSQ[256 + tid];
    float inv = 1.0f / (float)NN;
    float mean = s * inv;
    float var = q * inv - mean*mean;
    float rstd = rsqrtf(var + BNEPS);
    float g = type ? gi_[c] : gu[c];
    float bb = type ? bi_[c] : bu_[c];
    float sc = rstd * g;
    sc_l[tid] = sc;
    sh_l[tid] = bb - mean * sc;
  }
  __syncthreads();
  int b = blockIdx.x;
  int nfold = mode ? 0 : 66;
  if (b < nfold) {
    if (b < 64) {
      int e = b*256 + tid;          // 16384 entries x 4 consecutive k
      int rel = e >> 13;
      int rem = e & 8191;
      int h = rem >> 6;
      int k0 = (rem & 63) * 4;
      const float* Wr = rel ? WrelB : WrelA;
      const float* Wo = rel ? WrootB : WrootA;
      const float* scs = sc_l + (rel ? 128 : 0);
      const float* scd = sc_l + (rel ? 0 : 128);
      u16 t[4];
      #pragma unroll
      for (int j = 0; j < 4; j++) {
        int k = k0 + j;
        float v = (k < FD) ? Wr[((size_t)l*FD + h)*FD + k] * scs[k]
                           : Wo[((size_t)l*FD + h)*FD + (k - FD)] * scd[k - FD];
        t[j] = f2bf(v);
      }
      ushort4 o = { t[0], t[1], t[2], t[3] };
      *(ushort4*)(WBs + rel*32768 + h*256 + k0) = o;
    } else {
      int vid = (b - 64)*256 + tid; // 0..511
      int kind = vid >> 8;          // 0 = b1 (Wrel, sh_src), 1 = b2 (Wroot, sh_dst)
      int rel = (vid >> 7) & 1;
      int h = vid & 127;
      const float* W = kind ? (rel ? WrootB : WrootA) : (rel ? WrelB : WrelA);
      const float* sh = sh_l + ((kind ^ rel) ? 128 : 0);
      const float* wrow = W + ((size_t)l*FD + h)*FD;
      float s = 0.f;
      #pragma unroll
      for (int k = 0; k < FD; k += 4) {
        float4 wv = *(const float4*)(wrow + k);
        float4 sv = { sh[k], sh[k+1], sh[k+2], sh[k+3] };
        s += wv.x*sv.x + wv.y*sv.y + wv.z*sv.z + wv.w*sv.w;
      }
      bvec[kind*256 + rel*128 + h] = s;
    }
  } else {
    int fb = b - nfold;             // 0..255
    if (fb == 0) { accSQz[tid] = 0.f; accSQz[256 + tid] = 0.f; }
    int g = fb*2 + (tid >> 7);
    int ch = tid & 127;
    size_t iu = (size_t)g*FD + ch;
    size_t ii = (size_t)NG*FD + iu;
    float pu = P[iu];
    float pi = P[ii];
    float cu = (float)(ustart[g+1] - ustart[g]);
    float ci = (float)(istart[g+1] - istart[g]);
    feats[iu] = invcnt[g] * (sc_l[ch]*pu + cu*sh_l[ch]
                           + sc_l[128+ch]*pi + ci*sh_l[128+ch]);
    P[iu] = 0.f; P[ii] = 0.f;
  }
}

// one wave per dst row (grid 25000 -- R8-measured best: R9's 4-row serial
// wave regressed FETCH 152.7->157 MB and dur +1us; concurrent row spread
// maximizes cross-block L2 source sharing). 16B/lane loads, quarter-waves
// take different edges; 2 chains x 8-edge iters with index prefetch.
template<int RELU>
__global__ __launch_bounds__(256) void k_gather(const u16* __restrict__ curU,
                                                const u16* __restrict__ curI,
                                                const int2* __restrict__ rowrange,
                                                const int* __restrict__ csr,
                                                u16* __restrict__ aggI,
                                                u16* __restrict__ aggU) {
  int b = blockIdx.x;
  int half = b >= 12500;
  int blk = half ? b - 12500 : b;
  const u16* src = half ? curI : curU;
  u16* out = half ? aggU : aggI;
  int slotbase = half ? NN : 0;
  int wid = __builtin_amdgcn_readfirstlane(threadIdx.x >> 6);
  int row = blk*4 + wid;
  int lane = threadIdx.x & 63;
  int q = lane >> 4;
  int c16 = (lane & 15) * 8;      // 8 bf16 = 16B per lane
  const u16* sp = src + c16;
  int2 pr = rowrange[slotbase + row];
  int p = pr.x, pe = pr.y;
  float a0[8], a1[8];
  #pragma unroll
  for (int j = 0; j < 8; j++) { a0[j] = 0.f; a1[j] = 0.f; }
  if (p + 8 <= pe) {
    int i0 = csr[p + q], i1 = csr[p + 4 + q];
    while (p + 16 <= pe) {
      int n0 = csr[p + 8 + q], n1 = csr[p + 12 + q];
      int4 v0 = *(const int4*)(sp + (size_t)i0*FD);
      int4 v1 = *(const int4*)(sp + (size_t)i1*FD);
      accT8<RELU>(a0, v0); accT8<RELU>(a1, v1);
      i0 = n0; i1 = n1; p += 8;
    }
    int4 v0 = *(const int4*)(sp + (size_t)i0*FD);
    int4 v1 = *(const int4*)(sp + (size_t)i1*FD);
    accT8<RELU>(a0, v0); accT8<RELU>(a1, v1);
    p += 8;
  }
  int rem = pe - p;               // 0..7
  if (q < rem) {
    int s = csr[p + q];
    accT8<RELU>(a0, *(const int4*)(sp + (size_t)s*FD));
  }
  if (q + 4 < rem) {
    int s = csr[p + 4 + q];
    accT8<RELU>(a1, *(const int4*)(sp + (size_t)s*FD));
  }
  #pragma unroll
  for (int j = 0; j < 8; j++) a0[j] += a1[j];
  #pragma unroll
  for (int j = 0; j < 8; j++) {
    a0[j] += __shfl_xor(a0[j], 16);
    a0[j] += __shfl_xor(a0[j], 32);
  }
  if (q == 0) {
    int4 o;
    o.x = (unsigned)f2bf(a0[0]) | ((unsigned)f2bf(a0[1]) << 16);
    o.y = (unsigned)f2bf(a0[2]) | ((unsigned)f2bf(a0[3]) << 16);
    o.z = (unsigned)f2bf(a0[4]) | ((unsigned)f2bf(a0[5]) << 16);
    o.w = (unsigned)f2bf(a0[6]) | ((unsigned)f2bf(a0[7]) << 16);
    *(int4*)(out + (size_t)row*FD + c16) = o;
  }
}

// MFMA bf16 GEMM + fused BN-stat + per-graph pool.
// new[n,h] = [agg|cur][n,0:256] @ WB[h,0:256]^T + bias'[n,h]
// Epilogue: relu-stats from registers (shuffle+atomics), coalesced C
// writeback via LDS tile Cs[128][132], per-graph pooling read back from Cs
// with REGISTER accumulation per graph-segment -> ONE global atomic per
// (graph,col,half). No per-element atomics (R4 lesson: 12.8M LDS atomics
// serialized the kernel to 120us).
__global__ __launch_bounds__(256) void k_gemm(u16* __restrict__ newU,
                                              u16* __restrict__ newI,
                                              const u16* __restrict__ curU,
                                              const u16* __restrict__ curI,
                                              const u16* __restrict__ WBl,
                                              const float* __restrict__ bI2U,
                                              const float* __restrict__ bU2I,
                                              float* __restrict__ accSQ,
                                              const float* __restrict__ bvec,
                                              const int2* __restrict__ rowrange,
                                              const int* __restrict__ bu,
                                              const int* __restrict__ bi,
                                              const int* __restrict__ ustart,
                                              const int* __restrict__ istart,
                                              float* __restrict__ P,
                                              int fold) {
  __shared__ u16 smem[128*72*2];            // As | Bs; reused as Cs[128][132]
  __shared__ float Sred[2][4][128];
  u16* As = smem;
  u16* Bs = smem + 128*72;
  u16* Cs = smem;                           // 128*132 = 16896 u16 <= 18432
  int ty = blockIdx.y;
  u16* A1 = ty ? newI : newU;
  const u16* A2 = ty ? curI : curU;
  const u16* WBp = ty ? WBl : (WBl + 32768);
  const float* bias = ty ? bU2I : bI2U;
  const float* b1p = bvec + (ty ? 0 : 128);
  const float* b2p = bvec + 256 + (ty ? 0 : 128);
  const int* batch = ty ? bi : bu;
  const int* st = ty ? istart : ustart;
  float* Pg = P + (size_t)ty*NG*FD;
  int slot0 = ty ? 0 : NN;        // dst slots: items [0,NN), users [NN,2NN)
  int tid = threadIdx.x;
  int n0 = blockIdx.x * 128;
  int w = __builtin_amdgcn_readfirstlane(tid >> 6);
  int lane = tid & 63;
  int l15 = lane & 15;
  int quad = lane >> 4;
  f32x4 acc[2][8];
  #pragma unroll
  for (int tr = 0; tr < 2; tr++)
    #pragma unroll
    for (int tc = 0; tc < 8; tc++)
      acc[tr][tc] = (f32x4){0.f,0.f,0.f,0.f};

  for (int ch = 0; ch < 4; ch++) {
    const u16* Ap = (ch < 2) ? ((const u16*)A1 + ch*64) : (A2 + (ch-2)*64);
    int dorelu = fold && (ch >= 2);
    #pragma unroll
    for (int i = 0; i < 4; i++) {
      int e = i*256 + tid;
      int r = e >> 3, seg = e & 7;
      int4 v = {0,0,0,0};
      int gr = n0 + r;
      if (gr < NN) v = *(const int4*)(Ap + (size_t)gr*FD + seg*8);
      if (dorelu) { v.x = relu2(v.x); v.y = relu2(v.y); v.z = relu2(v.z); v.w = relu2(v.w); }
      *(int4*)&As[r*72 + seg*8] = v;
    }
    #pragma unroll
    for (int i = 0; i < 4; i++) {
      int e = i*256 + tid;
      int r = e >> 3, seg = e & 7;
      int4 v = *(const int4*)(WBp + r*256 + ch*64 + seg*8);
      *(int4*)&Bs[r*72 + seg*8] = v;
    }
    __syncthreads();
    #pragma unroll
    for (int ks = 0; ks < 2; ks++) {
      int kb = ks*32 + quad*8;
      short8 af0 = *(const short8*)&As[(w*32 + l15)*72 + kb];
      short8 af1 = *(const short8*)&As[(w*32 + 16 + l15)*72 + kb];
      short8 bf[8];
      #pragma unroll
      for (int tc = 0; tc < 8; tc++)
        bf[tc] = *(const short8*)&Bs[(tc*16 + l15)*72 + kb];
      #pragma unroll
      for (int tc = 0; tc < 8; tc++) {
        acc[0][tc] = __builtin_amdgcn_mfma_f32_16x16x32_bf16(af0, bf[tc], acc[0][tc], 0, 0, 0);
        acc[1][tc] = __builtin_amdgcn_mfma_f32_16x16x32_bf16(af1, bf[tc], acc[1][tc], 0, 0, 0);
      }
    }
    __syncthreads();
  }
  float sv[8], qv[8], bj[8], b1j[8];
  #pragma unroll
  for (int tc = 0; tc < 8; tc++) {
    int col = tc*16 + l15;
    float base = bias[col];
    if (fold) { base += b2p[col]; b1j[tc] = b1p[col]; } else b1j[tc] = 0.f;
    bj[tc] = base;
    sv[tc] = 0.f; qv[tc] = 0.f;
  }
  float dg[2][4] = {{0.f,0.f,0.f,0.f},{0.f,0.f,0.f,0.f}};
  if (fold) {
    #pragma unroll
    for (int tr = 0; tr < 2; tr++)
      #pragma unroll
      for (int gq = 0; gq < 4; gq++) {
        int r = n0 + w*32 + tr*16 + quad*4 + gq;
        if (r < NN) {
          int2 rr = rowrange[slot0 + r];
          dg[tr][gq] = (float)(rr.y - rr.x);
        }
      }
  }
  #pragma unroll
  for (int tr = 0; tr < 2; tr++) {
    int rl0 = w*32 + tr*16 + quad*4;
    int rbase = n0 + rl0;
    #pragma unroll
    for (int tc = 0; tc < 8; tc++) {
      int col = tc*16 + l15;
      #pragma unroll
      for (int g = 0; g < 4; g++) {
        int r = rbase + g;
        float v = acc[tr][tc][g] + bj[tc] + dg[tr][g]*b1j[tc];
        Cs[(rl0 + g)*132 + col] = f2bf(v);
        if (r < NN) {
          float y = v > 0.f ? v : 0.f;
          sv[tc] += y; qv[tc] += y*y;
        }
      }
    }
  }
  #pragma unroll
  for (int tc = 0; tc < 8; tc++) {
    sv[tc] += __shfl_xor(sv[tc], 16); qv[tc] += __shfl_xor(qv[tc], 16);
    sv[tc] += __shfl_xor(sv[tc], 32); qv[tc] += __shfl_xor(qv[tc], 32);
  }
  if (quad == 0) {
    #pragma unroll
    for (int tc = 0; tc < 8; tc++) {
      Sred[0][w][tc*16 + l15] = sv[tc];
      Sred[1][w][tc*16 + l15] = qv[tc];
    }
  }
  __syncthreads();          // covers Cs writes + Sred writes
  if (tid < 128) {
    float s = Sred[0][0][tid] + Sred[0][1][tid] + Sred[0][2][tid] + Sred[0][3][tid];
    float q = Sred[1][0][tid] + Sred[1][1][tid] + Sred[1][2][tid] + Sred[1][3][tid];
    atomicAdd(&accSQ[ty*128 + tid], s);
    atomicAdd(&accSQ[256 + ty*128 + tid], q);
  }
  // per-graph pooling from Cs: thread = (col, half-of-rows). Graph segments
  // are contiguous (rows graph-sorted); boundaries straight from st[].
  {
    int col = tid & 127;
    int half = tid >> 7;
    int rlo = half * 64, rhi = rlo + 64;     // local row range
    int gg0 = batch[n0];
    int lastr = n0 + 127; if (lastr > NN - 1) lastr = NN - 1;
    int gg1 = batch[lastr];
    for (int g = gg0; g <= gg1; ++g) {
      int lo = st[g]   - n0; lo = lo < rlo ? rlo : lo;
      int hi = st[g+1] - n0; hi = hi > rhi ? rhi : hi;
      float s = 0.f;
      for (int r = lo; r < hi; ++r) {
        float v = bf2f(Cs[r*132 + col]);
        s += v > 0.f ? v : 0.f;
      }
      if (hi > lo) atomicAdd(&Pg[(size_t)g*FD + col], s);
    }
  }
  // coalesced write-back: per pass j, block covers rows j*16..j*16+15 (4 KB)
  int prow = tid >> 4;            // 0..15
  int pc = (tid & 15) * 8;        // u16 col base (16B per lane)
  #pragma unroll
  for (int j = 0; j < 8; j++) {
    int row = j*16 + prow;
    int gr = n0 + row;
    int4 vv = *(const int4*)&Cs[row*132 + pc];
    if (gr < NN) *(int4*)(A1 + (size_t)gr*FD + pc) = vv;
  }
}

__global__ __launch_bounds__(256) void k_heads(const float* __restrict__ feats,
                                               const float* __restrict__ fcW,
                                               const float* __restrict__ fcb,
                                               float* __restrict__ logits) {
  int idx = blockIdx.x*256 + threadIdx.x;
  if (idx >= LOGITS_N) return;
  int l = idx >> 13;
  int rem = idx & 8191;
  int g = rem >> 4;
  int c = rem & 15;
  const float* f = feats + ((size_t)l*NG + g)*FD;
  const float* w = fcW + ((size_t)l*NC + c)*FD;
  float s = 0.f;
  #pragma unroll
  for (int k = 0; k < FD; k += 4) {
    float4 fv = *(const float4*)(f + k);
    float4 wv = *(const float4*)(w + k);
    s += fv.x*wv.x + fv.y*wv.y + fv.z*wv.z + fv.w*wv.w;
  }
  logits[idx] = s + fcb[l*NC + c];
}

extern "C" void kernel_launch(void* const* d_in, const int* in_sizes, int n_in,
                              void* d_out, int out_size, void* d_ws, size_t ws_size,
                              hipStream_t stream) {
  const float* x_user   = (const float*)d_in[0];
  const float* x_item   = (const float*)d_in[1];
  const int*   eu2i     = (const int*)d_in[2];
  const int*   ei2u     = (const int*)d_in[3];
  const int*   bu       = (const int*)d_in[4];
  const int*   bi       = (const int*)d_in[5];
  const float* Wrel_u2i = (const float*)d_in[6];
  const float* Wroot_u2i= (const float*)d_in[7];
  const float* b_u2i    = (const float*)d_in[8];
  const float* Wrel_i2u = (const float*)d_in[9];
  const float* Wroot_i2u= (const float*)d_in[10];
  const float* b_i2u    = (const float*)d_in[11];
  const float* bn_g_user= (const float*)d_in[12];
  const float* bn_b_user= (const float*)d_in[13];
  const float* bn_g_item= (const float*)d_in[14];
  const float* bn_b_item= (const float*)d_in[15];
  const float* fcW      = (const float*)d_in[16];
  const float* fcb      = (const float*)d_in[17];

  char* ws = (char*)d_ws;
  int*   gcnt   = (int*)(ws + OFF_GCNT);
  int*   bcursor= (int*)(ws + OFF_BCUR);
  float* accSQ  = (float*)(ws + OFF_ACC);     // 2 banks x 512 f32
  int*   ustart = (int*)(ws + OFF_USTART);
  int*   istart = (int*)(ws + OFF_ISTART);
  float* invcnt = (float*)(ws + OFF_INVCNT);
  int2*  rowrange = (int2*)(ws + OFF_ROWRANGE);
  u16*   WB     = (u16*)(ws + OFF_WB);
  int*   csrbin = (int*)(ws + OFF_CSR);
  u16*   p0I    = (u16*)(ws + OFF_N0I);       // pair0 item
  u16*   p0U    = (u16*)(ws + OFF_N0U);       // pair0 user
  float* P      = (float*)(ws + OFF_P);
  u16*   WBs    = (u16*)(ws + OFF_WBS);
  float* bvec   = (float*)(ws + OFF_BVEC);
  u16*   p1U    = (u16*)(ws + OFF_XU0);       // pair1 user (= initial cast)
  u16*   p1I    = (u16*)(ws + OFF_XI0);       // pair1 item (= initial cast)
  float* fout   = (float*)d_out;
  float* featsAll = fout + LOGITS_N;

  float* bank0 = accSQ;
  float* bank1 = accSQ + 512;

  hipMemsetAsync(ws, 0, MEMSET_BYTES, stream);
  // small kernels first: absorb the post-reset cold window (R6/R8-verified).
  k_bin<<<NBINBLK + 391, 256, 0, stream>>>(eu2i, ei2u, bcursor, csrbin,
                                           bu, bi, gcnt);
  k_csrbuild<<<NBUCK + 1, 256, 0, stream>>>(bcursor, csrbin, rowrange,
                                            gcnt, ustart, istart, invcnt);
  k_cast<<<3893, 256, 0, stream>>>(x_user, x_item, p1U, p1I,
                                   Wrel_u2i, Wroot_u2i, Wrel_i2u, Wroot_i2u,
                                   WB, P);

  // ---- layer 0: sources are raw inputs (no relu, no BN fold), pair1 = x0 ----
  k_gather<0><<<25000, 256, 0, stream>>>(p1U, p1I, rowrange, csrbin, p0I, p0U);
  k_gemm<<<dim3(NBLK,2), 256, 0, stream>>>(p0U, p0I, p1U, p1I, WB,
                                           b_i2u, b_u2i, bank0,
                                           bvec, rowrange, bu, bi,
                                           ustart, istart, P, 0);
  k_bnfold2<<<322, 256, 0, stream>>>(Wrel_u2i, Wroot_u2i, Wrel_i2u, Wroot_i2u,
                                     1, bank0, bank1,
                                     bn_g_user, bn_b_user, bn_g_item, bn_b_item,
                                     WBs, bvec, P, ustart, istart, invcnt,
                                     featsAll, 0);

  // ---- layer 1: relu in gather/staging, BN folded; writes pair1 (x0 dead) ----
  k_gather<1><<<25000, 256, 0, stream>>>(p0U, p0I, rowrange, csrbin, p1I, p1U);
  k_gemm<<<dim3(NBLK,2), 256, 0, stream>>>(p1U, p1I, p0U, p0I, WBs,
                                           b_i2u + FD, b_u2i + FD, bank1,
                                           bvec, rowrange, bu, bi,
                                           ustart, istart, P, 1);
  k_bnfold2<<<322, 256, 0, stream>>>(Wrel_u2i, Wroot_u2i, Wrel_i2u, Wroot_i2u,
                                     2, bank1, bank0,
                                     bn_g_user, bn_b_user, bn_g_item, bn_b_item,
                                     WBs, bvec, P, ustart, istart, invcnt,
                                     featsAll + NG*FD, 0);

  // ---- layer 2 ----
  k_gather<1><<<25000, 256, 0, stream>>>(p1U, p1I, rowrange, csrbin, p0I, p0U);
  k_gemm<<<dim3(NBLK,2), 256, 0, stream>>>(p0U, p0I, p1U, p1I, WBs,
                                           b_i2u + 2*FD, b_u2i + 2*FD, bank0,
                                           bvec, rowrange, bu, bi,
                                           ustart, istart, P, 1);
  k_bnfold2<<<256, 256, 0, stream>>>(Wrel_u2i, Wroot_u2i, Wrel_i2u, Wroot_i2u,
                                     2, bank0, bank1,
                                     bn_g_user, bn_b_user, bn_g_item, bn_b_item,
                                     WBs, bvec, P, ustart, istart, invcnt,
                                     featsAll + 2*NG*FD, 1);

  k_heads<<<96, 256, 0, stream>>>(featsAll, fcW, fcb, fout);
}

// Round 11
// 446.409 us; speedup vs baseline: 1.6349x; 1.0488x over previous
//
#include <hip/hip_runtime.h>

#define NN 50000
#define FD 128
#define NE 800000
#define NG 512
#define NC 16
#define NL 3
#define NTOT 100000
#define NBLK 391            // ceil(100000/256) and ceil(50000/128)
#define NBUCK 196           // ceil(100000/512) slot-buckets
#define CAP 10240           // per-bucket capacity (avg 8163, sigma ~90)
#define BINTILE 2048
#define NBINBLK 782         // ceil(1600000/2048)
#define BNEPS 1e-5f
#define LOGITS_N (NL*NG*NC)
#define Q4 800000           // 50000*128/4 float4s per half-array

typedef unsigned short u16;
typedef unsigned char u8;
typedef __attribute__((ext_vector_type(8))) short short8;
typedef __attribute__((ext_vector_type(4))) float f32x4;

// ---- workspace layout (bytes) ----
#define OFF_GCNT     0ul          // 2*512 int
#define OFF_BCUR     4096ul       // 196 int
#define OFF_ACC      5120ul       // 2 banks x 512 f32 (S[256],Q[256] each)
#define MEMSET_BYTES 9216ul       // covers GCNT + BCUR + ACC banks
#define OFF_USTART   9728ul       // 513 int
#define OFF_ISTART   12288ul      // 513 int
#define OFF_INVCNT   14848ul      // 512 f32
#define OFF_ROWRANGE 16896ul      // 100000 int2
#define OFF_WB       817152ul     // layer-0 2*128*256 bf16
#define OFF_CSR      1210368ul    // 196*10240 int (binned, then CSR in place)
#define OFF_N0I      9238528ul    // pair0 item (50000*128 bf16)
#define OFF_N0U      22038528ul   // pair0 user
#define OFF_P        34838528ul   // [2][512][128] f32 = 524288 B
#define OFF_WBS      35362816ul   // 2*128*256 bf16 scaled weights
#define OFF_BVEC     35493888ul   // b1[2][128] | b2[2][128] f32
#define OFF_XU0      60438528ul   // pair1 user / initial cast
#define OFF_XI0      73238528ul   // pair1 item / initial cast

static __device__ __forceinline__ float bf2f(u16 v) {
  return __uint_as_float(((unsigned)v) << 16);
}
static __device__ __forceinline__ u16 f2bf(float f) {
  unsigned u = __float_as_uint(f);
  return (u16)((u + 0x7FFFu + ((u >> 16) & 1u)) >> 16);
}
template<int RELU>
static __device__ __forceinline__ void accT8(float* a, int4 v) {
  unsigned w[4] = {(unsigned)v.x, (unsigned)v.y, (unsigned)v.z, (unsigned)v.w};
  #pragma unroll
  for (int i = 0; i < 4; i++) {
    float lo = __uint_as_float(w[i] << 16);
    float hi = __uint_as_float(w[i] & 0xffff0000u);
    if (RELU) { lo = lo > 0.f ? lo : 0.f; hi = hi > 0.f ? hi : 0.f; }
    a[2*i]   += lo;
    a[2*i+1] += hi;
  }
}
static __device__ __forceinline__ int relu2(int w) {
  int lo = (w & 0x00008000) ? 0 : (w & 0x0000FFFF);
  int hi = (w < 0)          ? 0 : (int)(w & 0xFFFF0000u);
  return lo | hi;
}
static __device__ __forceinline__ ushort4 cvt4(float4 v) {
  ushort4 o = { f2bf(v.x), f2bf(v.y), f2bf(v.z), f2bf(v.w) };
  return o;
}

// bucket edges by dst-slot>>9 into fixed-capacity regions; entry (lslot:9|src:17).
// Blocks [NBINBLK, NBINBLK+391): batch histogram (ballot run-length, sorted ids).
__global__ __launch_bounds__(256) void k_bin(const int* __restrict__ eu2i,
                                             const int* __restrict__ ei2u,
                                             int* __restrict__ bcursor,
                                             int* __restrict__ binned,
                                             const int* __restrict__ bu,
                                             const int* __restrict__ bi,
                                             int* __restrict__ gcnt) {
  if (blockIdx.x >= NBINBLK) {
    int i = (blockIdx.x - NBINBLK)*256 + threadIdx.x;
    int lane = threadIdx.x & 63;
    bool valid = i < NTOT;
    int slot = -1;
    if (valid) {
      int type = i >= NN;
      int g = type ? bi[i-NN] : bu[i];
      slot = type*NG + g;
    }
    int prevslot = __shfl_up(slot, 1);
    bool head = valid && (lane == 0 || prevslot != slot);
    unsigned long long hb = __ballot(head);
    int nvalid = __popcll(__ballot(valid));   // valid lanes form a prefix
    if (head) {
      unsigned long long higher = (lane < 63) ? (hb >> (lane+1)) : 0ull;
      int next = higher ? (lane + __ffsll(higher)) : 64;
      int end = next < nvalid ? next : nvalid;
      atomicAdd(&gcnt[slot], end - lane);
    }
    return;
  }
  __shared__ int hist[256];
  __shared__ int scan[256];
  __shared__ int gbase[256];
  __shared__ int rbuf[BINTILE];
  __shared__ u8 rbk[BINTILE];
  int tid = threadIdx.x;
  int base = blockIdx.x * BINTILE;
  hist[tid] = 0;
  __syncthreads();
  int packr[8], bkr[8], rankr[8];
  #pragma unroll
  for (int c = 0; c < 8; c++) {
    int idx = base + c*256 + tid;
    if (idx < 2*NE) {
      int rel = idx >= NE;
      int e = rel ? idx - NE : idx;
      const int* edge = rel ? ei2u : eu2i;
      int s = edge[e];
      int d = edge[NE + e];
      int slot = d + (rel ? NN : 0);
      int bk = slot >> 9;
      bkr[c] = bk;
      packr[c] = ((slot & 511) << 17) | s;
      rankr[c] = atomicAdd(&hist[bk], 1);
    } else bkr[c] = -1;
  }
  __syncthreads();
  scan[tid] = hist[tid];
  __syncthreads();
  for (int o = 1; o < 256; o <<= 1) {
    int v = (tid >= o) ? scan[tid - o] : 0;
    __syncthreads();
    scan[tid] += v;
    __syncthreads();
  }
  if (tid < NBUCK && hist[tid] > 0)
    gbase[tid] = atomicAdd(&bcursor[tid], hist[tid]);
  __syncthreads();
  #pragma unroll
  for (int c = 0; c < 8; c++) {
    if (bkr[c] >= 0) {
      int bk = bkr[c];
      int lpos = scan[bk] - hist[bk] + rankr[c];
      rbuf[lpos] = packr[c];
      rbk[lpos] = (u8)bk;
    }
  }
  __syncthreads();
  int nv = min(BINTILE, 2*NE - base);
  for (int j = tid; j < nv; j += 256) {
    int bk = rbk[j];
    int outpos = bk*CAP + gbase[bk] + (j - (scan[bk] - hist[bk]));
    binned[outpos] = rbuf[j];
  }
}

// blocks [0,196): per-bucket CSR build (local hist+scan -> rowrange, LDS scatter,
// CSR in place). Block 196: graph-count scan -> ustart/istart/invcnt.
__global__ __launch_bounds__(256) void k_csrbuild(const int* __restrict__ bcursor,
                                                  int* __restrict__ csrbin,
                                                  int2* __restrict__ rowrange,
                                                  const int* __restrict__ gcnt,
                                                  int* __restrict__ ustart,
                                                  int* __restrict__ istart,
                                                  float* __restrict__ invcnt) {
  __shared__ int lcnt[512];
  __shared__ int scan2[256];
  __shared__ int lcsr[CAP];
  int b = blockIdx.x;
  int tid = threadIdx.x;
  if (b == NBUCK) {
    int cu0 = gcnt[2*tid],     cu1 = gcnt[2*tid + 1];
    int ci0 = gcnt[NG + 2*tid], ci1 = gcnt[NG + 2*tid + 1];
    int su = cu0 + cu1, si = ci0 + ci1;
    lcnt[tid] = su; lcsr[tid] = si;
    __syncthreads();
    for (int o = 1; o < 256; o <<= 1) {
      int vu = (tid >= o) ? lcnt[tid - o] : 0;
      int vi = (tid >= o) ? lcsr[tid - o] : 0;
      __syncthreads();
      lcnt[tid] += vu; lcsr[tid] += vi;
      __syncthreads();
    }
    int eu = lcnt[tid] - su;   // exclusive pair prefix
    int ei = lcsr[tid] - si;
    ustart[2*tid]     = eu;        ustart[2*tid + 1] = eu + cu0;
    istart[2*tid]     = ei;        istart[2*tid + 1] = ei + ci0;
    if (tid == 255) { ustart[NG] = lcnt[255]; istart[NG] = lcsr[255]; }
    int c0 = cu0 + ci0, c1 = cu1 + ci1;
    invcnt[2*tid]     = 1.0f / (float)(c0 > 0 ? c0 : 1);
    invcnt[2*tid + 1] = 1.0f / (float)(c1 > 0 ? c1 : 1);
    return;
  }
  int slot0 = b << 9;
  int nslots = min(512, NTOT - slot0);
  int n = bcursor[b];
  int gb = b * CAP;
  lcnt[tid] = 0; lcnt[tid + 256] = 0;
  __syncthreads();
  for (int i = tid; i < n; i += 256) {
    int e = csrbin[gb + i];
    atomicAdd(&lcnt[e >> 17], 1);
  }
  __syncthreads();
  int v0 = lcnt[2*tid], v1 = lcnt[2*tid + 1];
  int ps = v0 + v1;
  scan2[tid] = ps;
  __syncthreads();
  for (int o = 1; o < 256; o <<= 1) {
    int v = (tid >= o) ? scan2[tid - o] : 0;
    __syncthreads();
    scan2[tid] += v;
    __syncthreads();
  }
  int e0 = scan2[tid] - ps;       // exclusive prefix for slot 2*tid
  int e1 = e0 + v0;
  if (2*tid < nslots)     rowrange[slot0 + 2*tid]     = make_int2(gb + e0, gb + e0 + v0);
  if (2*tid + 1 < nslots) rowrange[slot0 + 2*tid + 1] = make_int2(gb + e1, gb + e1 + v1);
  __syncthreads();
  lcnt[2*tid] = e0; lcnt[2*tid + 1] = e1;   // cursors
  __syncthreads();
  for (int i = tid; i < n; i += 256) {
    int e = csrbin[gb + i];
    int pos = atomicAdd(&lcnt[e >> 17], 1);
    lcsr[pos] = e & 0x1FFFF;
  }
  __syncthreads();
  for (int i = tid; i < n; i += 256) csrbin[gb + i] = lcsr[i];
}

// cast (warm-clock position, R6/R8 lesson: first-slot streaming ran at 833 GB/s).
// blocks [0,3125): castX 4x float4 MLP; [3125,3381): layer-0 castW;
// [3381,3893): zero P (replaces a memset dispatch).
__global__ __launch_bounds__(256) void k_cast(const float* __restrict__ xu,
                                              const float* __restrict__ xi,
                                              u16* __restrict__ xbu,
                                              u16* __restrict__ xbi,
                                              const float* __restrict__ WrelA,
                                              const float* __restrict__ WrootA,
                                              const float* __restrict__ WrelB,
                                              const float* __restrict__ WrootB,
                                              u16* __restrict__ WB,
                                              float* __restrict__ P) {
  int b = blockIdx.x;
  if (b < 3125) {
    int t = b*256 + threadIdx.x;           // < 800000
    const float4* su = (const float4*)xu;
    const float4* si = (const float4*)xi;
    float4 v0 = su[t];
    float4 v1 = su[t + Q4];
    float4 v2 = si[t];
    float4 v3 = si[t + Q4];
    ushort4* du = (ushort4*)xbu;
    ushort4* di = (ushort4*)xbi;
    du[t]      = cvt4(v0);
    du[t + Q4] = cvt4(v1);
    di[t]      = cvt4(v2);
    di[t + Q4] = cvt4(v3);
  } else if (b < 3381) {
    int idx = (b - 3125)*256 + threadIdx.x;   // 65536 layer-0 weight entries
    int lr = idx >> 15;
    int rem = idx & 32767;
    int h = rem >> 8;
    int k = rem & 255;
    int rel = lr & 1;
    const float* Wr = rel ? WrelB : WrelA;
    const float* Wo = rel ? WrootB : WrootA;
    float v = (k < FD) ? Wr[h*FD + k] : Wo[h*FD + (k-FD)];
    WB[idx] = f2bf(v);
  } else {
    int idx = (b - 3381)*256 + threadIdx.x;   // 131072 P floats
    P[idx] = 0.f;
  }
}

// merged BN finalize + fold + feats + per-layer classifier head:
// every block recomputes sc/sh from accSQ bank (cheap, bit-identical).
// mode 0: blocks [0,64) WBs scale, [64,66) bvec, [66,322) feats+heads
// mode 1 (last layer): all 256 blocks feats+heads.
// feats block fb==0 also zeroes the OTHER accSQ bank for the next gemm.
// feats blocks zero their P entries, then 32 threads compute the 2 graphs'
// 16-class logits from the LDS-staged feats row (replaces k_heads launch).
__global__ __launch_bounds__(256) void k_bnfold2(const float* __restrict__ WrelA,
                                                 const float* __restrict__ WrootA,
                                                 const float* __restrict__ WrelB,
                                                 const float* __restrict__ WrootB,
                                                 int l,
                                                 const float* __restrict__ accSQ,
                                                 float* __restrict__ accSQz,
                                                 const float* __restrict__ gu,
                                                 const float* __restrict__ bu_,
                                                 const float* __restrict__ gi_,
                                                 const float* __restrict__ bi_,
                                                 u16* __restrict__ WBs,
                                                 float* __restrict__ bvec,
                                                 float* __restrict__ P,
                                                 const int* __restrict__ ustart,
                                                 const int* __restrict__ istart,
                                                 const float* __restrict__ invcnt,
                                                 float* __restrict__ feats,
                                                 const float* __restrict__ fcWl,
                                                 const float* __restrict__ fcbl,
                                                 float* __restrict__ logitsl,
                                                 int mode) {
  __shared__ float sc_l[256], sh_l[256];
  __shared__ float ft[2][128];
  int tid = threadIdx.x;
  {
    int type = tid >> 7;
    int c = tid & 127;
    float s = accSQ[tid];
    float q = accSQ[256 + tid];
    float inv = 1.0f / (float)NN;
    float mean = s * inv;
    float var = q * inv - mean*mean;
    float rstd = rsqrtf(var + BNEPS);
    float g = type ? gi_[c] : gu[c];
    float bb = type ? bi_[c] : bu_[c];
    float sc = rstd * g;
    sc_l[tid] = sc;
    sh_l[tid] = bb - mean * sc;
  }
  __syncthreads();
  int b = blockIdx.x;
  int nfold = mode ? 0 : 66;
  if (b < nfold) {
    if (b < 64) {
      int e = b*256 + tid;          // 16384 entries x 4 consecutive k
      int rel = e >> 13;
      int rem = e & 8191;
      int h = rem >> 6;
      int k0 = (rem & 63) * 4;
      const float* Wr = rel ? WrelB : WrelA;
      const float* Wo = rel ? WrootB : WrootA;
      const float* scs = sc_l + (rel ? 128 : 0);
      const float* scd = sc_l + (rel ? 0 : 128);
      u16 t[4];
      #pragma unroll
      for (int j = 0; j < 4; j++) {
        int k = k0 + j;
        float v = (k < FD) ? Wr[((size_t)l*FD + h)*FD + k] * scs[k]
                           : Wo[((size_t)l*FD + h)*FD + (k - FD)] * scd[k - FD];
        t[j] = f2bf(v);
      }
      ushort4 o = { t[0], t[1], t[2], t[3] };
      *(ushort4*)(WBs + rel*32768 + h*256 + k0) = o;
    } else {
      int vid = (b - 64)*256 + tid; // 0..511
      int kind = vid >> 8;          // 0 = b1 (Wrel, sh_src), 1 = b2 (Wroot, sh_dst)
      int rel = (vid >> 7) & 1;
      int h = vid & 127;
      const float* W = kind ? (rel ? WrootB : WrootA) : (rel ? WrelB : WrelA);
      const float* sh = sh_l + ((kind ^ rel) ? 128 : 0);
      const float* wrow = W + ((size_t)l*FD + h)*FD;
      float s = 0.f;
      #pragma unroll
      for (int k = 0; k < FD; k += 4) {
        float4 wv = *(const float4*)(wrow + k);
        float4 sv = { sh[k], sh[k+1], sh[k+2], sh[k+3] };
        s += wv.x*sv.x + wv.y*sv.y + wv.z*sv.z + wv.w*sv.w;
      }
      bvec[kind*256 + rel*128 + h] = s;
    }
  } else {
    int fb = b - nfold;             // 0..255
    if (fb == 0) { accSQz[tid] = 0.f; accSQz[256 + tid] = 0.f; }
    int g2 = tid >> 7;
    int g = fb*2 + g2;
    int ch = tid & 127;
    size_t iu = (size_t)g*FD + ch;
    size_t ii = (size_t)NG*FD + iu;
    float pu = P[iu];
    float pi = P[ii];
    float cu = (float)(ustart[g+1] - ustart[g]);
    float ci = (float)(istart[g+1] - istart[g]);
    float fv = invcnt[g] * (sc_l[ch]*pu + cu*sh_l[ch]
                          + sc_l[128+ch]*pi + ci*sh_l[128+ch]);
    feats[iu] = fv;
    ft[g2][ch] = fv;
    P[iu] = 0.f; P[ii] = 0.f;
    __syncthreads();
    if (tid < 32) {
      int gg = tid >> 4;            // 0..1
      int c = tid & 15;
      const float* wrow = fcWl + (size_t)c*FD;
      float s = 0.f;
      #pragma unroll
      for (int k = 0; k < FD; k += 4) {
        float4 wv = *(const float4*)(wrow + k);
        s += ft[gg][k]*wv.x + ft[gg][k+1]*wv.y
           + ft[gg][k+2]*wv.z + ft[gg][k+3]*wv.w;
      }
      logitsl[(size_t)(fb*2 + gg)*NC + c] = s + fcbl[c];
    }
  }
}

// one wave per dst row (grid 25000 -- R8/R10-measured best: R9's 4-row serial
// wave regressed FETCH +3% and dur +1us; concurrent row spread maximizes
// cross-block L2 source sharing). 16B/lane loads, quarter-waves take
// different edges; 2 chains x 8-edge iters with index prefetch.
template<int RELU>
__global__ __launch_bounds__(256) void k_gather(const u16* __restrict__ curU,
                                                const u16* __restrict__ curI,
                                                const int2* __restrict__ rowrange,
                                                const int* __restrict__ csr,
                                                u16* __restrict__ aggI,
                                                u16* __restrict__ aggU) {
  int b = blockIdx.x;
  int half = b >= 12500;
  int blk = half ? b - 12500 : b;
  const u16* src = half ? curI : curU;
  u16* out = half ? aggU : aggI;
  int slotbase = half ? NN : 0;
  int wid = __builtin_amdgcn_readfirstlane(threadIdx.x >> 6);
  int row = blk*4 + wid;
  int lane = threadIdx.x & 63;
  int q = lane >> 4;
  int c16 = (lane & 15) * 8;      // 8 bf16 = 16B per lane
  const u16* sp = src + c16;
  int2 pr = rowrange[slotbase + row];
  int p = pr.x, pe = pr.y;
  float a0[8], a1[8];
  #pragma unroll
  for (int j = 0; j < 8; j++) { a0[j] = 0.f; a1[j] = 0.f; }
  if (p + 8 <= pe) {
    int i0 = csr[p + q], i1 = csr[p + 4 + q];
    while (p + 16 <= pe) {
      int n0 = csr[p + 8 + q], n1 = csr[p + 12 + q];
      int4 v0 = *(const int4*)(sp + (size_t)i0*FD);
      int4 v1 = *(const int4*)(sp + (size_t)i1*FD);
      accT8<RELU>(a0, v0); accT8<RELU>(a1, v1);
      i0 = n0; i1 = n1; p += 8;
    }
    int4 v0 = *(const int4*)(sp + (size_t)i0*FD);
    int4 v1 = *(const int4*)(sp + (size_t)i1*FD);
    accT8<RELU>(a0, v0); accT8<RELU>(a1, v1);
    p += 8;
  }
  int rem = pe - p;               // 0..7
  if (q < rem) {
    int s = csr[p + q];
    accT8<RELU>(a0, *(const int4*)(sp + (size_t)s*FD));
  }
  if (q + 4 < rem) {
    int s = csr[p + 4 + q];
    accT8<RELU>(a1, *(const int4*)(sp + (size_t)s*FD));
  }
  #pragma unroll
  for (int j = 0; j < 8; j++) a0[j] += a1[j];
  #pragma unroll
  for (int j = 0; j < 8; j++) {
    a0[j] += __shfl_xor(a0[j], 16);
    a0[j] += __shfl_xor(a0[j], 32);
  }
  if (q == 0) {
    int4 o;
    o.x = (unsigned)f2bf(a0[0]) | ((unsigned)f2bf(a0[1]) << 16);
    o.y = (unsigned)f2bf(a0[2]) | ((unsigned)f2bf(a0[3]) << 16);
    o.z = (unsigned)f2bf(a0[4]) | ((unsigned)f2bf(a0[5]) << 16);
    o.w = (unsigned)f2bf(a0[6]) | ((unsigned)f2bf(a0[7]) << 16);
    *(int4*)(out + (size_t)row*FD + c16) = o;
  }
}

// MFMA bf16 GEMM + fused BN-stat + per-graph pool.
// new[n,h] = [agg|cur][n,0:256] @ WB[h,0:256]^T + bias'[n,h]
// A-operand register prefetch (T14 issue-early/write-late): chunk ch+1's A
// loads issue right after the stage barrier, hiding HBM/L3 latency under the
// MFMA loop. __launch_bounds__(256,4) pins VGPR<=128 so the +16 prefetch regs
// can't break 4 blocks/CU (LDS = exactly 40KB).
// Epilogue: relu-stats from registers (shuffle+atomics), coalesced C
// writeback via LDS tile Cs[128][132], per-graph pooling read back from Cs
// with register accumulation per graph-segment -> ONE global atomic per
// (graph,col,half). No per-element atomics (R4 lesson: 12.8M LDS atomics
// serialized the kernel to 120us).
__global__ __launch_bounds__(256, 4) void k_gemm(u16* __restrict__ newU,
                                              u16* __restrict__ newI,
                                              const u16* __restrict__ curU,
                                              const u16* __restrict__ curI,
                                              const u16* __restrict__ WBl,
                                              const float* __restrict__ bI2U,
                                              const float* __restrict__ bU2I,
                                              float* __restrict__ accSQ,
                                              const float* __restrict__ bvec,
                                              const int2* __restrict__ rowrange,
                                              const int* __restrict__ bu,
                                              const int* __restrict__ bi,
                                              const int* __restrict__ ustart,
                                              const int* __restrict__ istart,
                                              float* __restrict__ P,
                                              int fold) {
  __shared__ u16 smem[128*72*2];            // As | Bs; reused as Cs[128][132]
  __shared__ float Sred[2][4][128];
  u16* As = smem;
  u16* Bs = smem + 128*72;
  u16* Cs = smem;                           // 128*132 = 16896 u16 <= 18432
  int ty = blockIdx.y;
  u16* A1 = ty ? newI : newU;
  const u16* A2 = ty ? curI : curU;
  const u16* WBp = ty ? WBl : (WBl + 32768);
  const float* bias = ty ? bU2I : bI2U;
  const float* b1p = bvec + (ty ? 0 : 128);
  const float* b2p = bvec + 256 + (ty ? 0 : 128);
  const int* batch = ty ? bi : bu;
  const int* st = ty ? istart : ustart;
  float* Pg = P + (size_t)ty*NG*FD;
  int slot0 = ty ? 0 : NN;        // dst slots: items [0,NN), users [NN,2NN)
  int tid = threadIdx.x;
  int n0 = blockIdx.x * 128;
  int w = __builtin_amdgcn_readfirstlane(tid >> 6);
  int lane = tid & 63;
  int l15 = lane & 15;
  int quad = lane >> 4;
  f32x4 acc[2][8];
  #pragma unroll
  for (int tr = 0; tr < 2; tr++)
    #pragma unroll
    for (int tc = 0; tc < 8; tc++)
      acc[tr][tc] = (f32x4){0.f,0.f,0.f,0.f};

  // prologue: prefetch chunk 0's A tile into registers
  int4 aR[4];
  {
    const u16* Ap = (const u16*)A1;
    #pragma unroll
    for (int i = 0; i < 4; i++) {
      int e = i*256 + tid;
      int r = e >> 3, seg = e & 7;
      int gr = n0 + r;
      int4 v = {0,0,0,0};
      if (gr < NN) v = *(const int4*)(Ap + (size_t)gr*FD + seg*8);
      aR[i] = v;
    }
  }
  for (int ch = 0; ch < 4; ch++) {
    int dorelu = fold && (ch >= 2);
    #pragma unroll
    for (int i = 0; i < 4; i++) {
      int e = i*256 + tid;
      int r = e >> 3, seg = e & 7;
      int4 v = aR[i];
      if (dorelu) { v.x = relu2(v.x); v.y = relu2(v.y); v.z = relu2(v.z); v.w = relu2(v.w); }
      *(int4*)&As[r*72 + seg*8] = v;
    }
    #pragma unroll
    for (int i = 0; i < 4; i++) {
      int e = i*256 + tid;
      int r = e >> 3, seg = e & 7;
      int4 v = *(const int4*)(WBp + r*256 + ch*64 + seg*8);
      *(int4*)&Bs[r*72 + seg*8] = v;
    }
    __syncthreads();
    if (ch < 3) {                   // issue next chunk's A loads under the MFMAs
      const u16* Apn = (ch + 1 < 2) ? ((const u16*)A1 + (ch+1)*64)
                                    : (A2 + (ch-1)*64);
      #pragma unroll
      for (int i = 0; i < 4; i++) {
        int e = i*256 + tid;
        int r = e >> 3, seg = e & 7;
        int gr = n0 + r;
        int4 v = {0,0,0,0};
        if (gr < NN) v = *(const int4*)(Apn + (size_t)gr*FD + seg*8);
        aR[i] = v;
      }
    }
    #pragma unroll
    for (int ks = 0; ks < 2; ks++) {
      int kb = ks*32 + quad*8;
      short8 af0 = *(const short8*)&As[(w*32 + l15)*72 + kb];
      short8 af1 = *(const short8*)&As[(w*32 + 16 + l15)*72 + kb];
      short8 bf[8];
      #pragma unroll
      for (int tc = 0; tc < 8; tc++)
        bf[tc] = *(const short8*)&Bs[(tc*16 + l15)*72 + kb];
      #pragma unroll
      for (int tc = 0; tc < 8; tc++) {
        acc[0][tc] = __builtin_amdgcn_mfma_f32_16x16x32_bf16(af0, bf[tc], acc[0][tc], 0, 0, 0);
        acc[1][tc] = __builtin_amdgcn_mfma_f32_16x16x32_bf16(af1, bf[tc], acc[1][tc], 0, 0, 0);
      }
    }
    __syncthreads();
  }
  float sv[8], qv[8], bj[8], b1j[8];
  #pragma unroll
  for (int tc = 0; tc < 8; tc++) {
    int col = tc*16 + l15;
    float base = bias[col];
    if (fold) { base += b2p[col]; b1j[tc] = b1p[col]; } else b1j[tc] = 0.f;
    bj[tc] = base;
    sv[tc] = 0.f; qv[tc] = 0.f;
  }
  float dg[2][4] = {{0.f,0.f,0.f,0.f},{0.f,0.f,0.f,0.f}};
  if (fold) {
    #pragma unroll
    for (int tr = 0; tr < 2; tr++)
      #pragma unroll
      for (int gq = 0; gq < 4; gq++) {
        int r = n0 + w*32 + tr*16 + quad*4 + gq;
        if (r < NN) {
          int2 rr = rowrange[slot0 + r];
          dg[tr][gq] = (float)(rr.y - rr.x);
        }
      }
  }
  #pragma unroll
  for (int tr = 0; tr < 2; tr++) {
    int rl0 = w*32 + tr*16 + quad*4;
    int rbase = n0 + rl0;
    #pragma unroll
    for (int tc = 0; tc < 8; tc++) {
      int col = tc*16 + l15;
      #pragma unroll
      for (int g = 0; g < 4; g++) {
        int r = rbase + g;
        float v = acc[tr][tc][g] + bj[tc] + dg[tr][g]*b1j[tc];
        Cs[(rl0 + g)*132 + col] = f2bf(v);
        if (r < NN) {
          float y = v > 0.f ? v : 0.f;
          sv[tc] += y; qv[tc] += y*y;
        }
      }
    }
  }
  #pragma unroll
  for (int tc = 0; tc < 8; tc++) {
    sv[tc] += __shfl_xor(sv[tc], 16); qv[tc] += __shfl_xor(qv[tc], 16);
    sv[tc] += __shfl_xor(sv[tc], 32); qv[tc] += __shfl_xor(qv[tc], 32);
  }
  if (quad == 0) {
    #pragma unroll
    for (int tc = 0; tc < 8; tc++) {
      Sred[0][w][tc*16 + l15] = sv[tc];
      Sred[1][w][tc*16 + l15] = qv[tc];
    }
  }
  __syncthreads();          // covers Cs writes + Sred writes
  if (tid < 128) {
    float s = Sred[0][0][tid] + Sred[0][1][tid] + Sred[0][2][tid] + Sred[0][3][tid];
    float q = Sred[1][0][tid] + Sred[1][1][tid] + Sred[1][2][tid] + Sred[1][3][tid];
    atomicAdd(&accSQ[ty*128 + tid], s);
    atomicAdd(&accSQ[256 + ty*128 + tid], q);
  }
  // per-graph pooling from Cs: thread = (col, half-of-rows). Graph segments
  // are contiguous (rows graph-sorted); boundaries straight from st[].
  {
    int col = tid & 127;
    int half = tid >> 7;
    int rlo = half * 64, rhi = rlo + 64;     // local row range
    int gg0 = batch[n0];
    int lastr = n0 + 127; if (lastr > NN - 1) lastr = NN - 1;
    int gg1 = batch[lastr];
    for (int g = gg0; g <= gg1; ++g) {
      int lo = st[g]   - n0; lo = lo < rlo ? rlo : lo;
      int hi = st[g+1] - n0; hi = hi > rhi ? rhi : hi;
      float s = 0.f;
      for (int r = lo; r < hi; ++r) {
        float v = bf2f(Cs[r*132 + col]);
        s += v > 0.f ? v : 0.f;
      }
      if (hi > lo) atomicAdd(&Pg[(size_t)g*FD + col], s);
    }
  }
  // coalesced write-back: per pass j, block covers rows j*16..j*16+15 (4 KB)
  int prow = tid >> 4;            // 0..15
  int pc = (tid & 15) * 8;        // u16 col base (16B per lane)
  #pragma unroll
  for (int j = 0; j < 8; j++) {
    int row = j*16 + prow;
    int gr = n0 + row;
    int4 vv = *(const int4*)&Cs[row*132 + pc];
    if (gr < NN) *(int4*)(A1 + (size_t)gr*FD + pc) = vv;
  }
}

extern "C" void kernel_launch(void* const* d_in, const int* in_sizes, int n_in,
                              void* d_out, int out_size, void* d_ws, size_t ws_size,
                              hipStream_t stream) {
  const float* x_user   = (const float*)d_in[0];
  const float* x_item   = (const float*)d_in[1];
  const int*   eu2i     = (const int*)d_in[2];
  const int*   ei2u     = (const int*)d_in[3];
  const int*   bu       = (const int*)d_in[4];
  const int*   bi       = (const int*)d_in[5];
  const float* Wrel_u2i = (const float*)d_in[6];
  const float* Wroot_u2i= (const float*)d_in[7];
  const float* b_u2i    = (const float*)d_in[8];
  const float* Wrel_i2u = (const float*)d_in[9];
  const float* Wroot_i2u= (const float*)d_in[10];
  const float* b_i2u    = (const float*)d_in[11];
  const float* bn_g_user= (const float*)d_in[12];
  const float* bn_b_user= (const float*)d_in[13];
  const float* bn_g_item= (const float*)d_in[14];
  const float* bn_b_item= (const float*)d_in[15];
  const float* fcW      = (const float*)d_in[16];
  const float* fcb      = (const float*)d_in[17];

  char* ws = (char*)d_ws;
  int*   gcnt   = (int*)(ws + OFF_GCNT);
  int*   bcursor= (int*)(ws + OFF_BCUR);
  float* accSQ  = (float*)(ws + OFF_ACC);     // 2 banks x 512 f32
  int*   ustart = (int*)(ws + OFF_USTART);
  int*   istart = (int*)(ws + OFF_ISTART);
  float* invcnt = (float*)(ws + OFF_INVCNT);
  int2*  rowrange = (int2*)(ws + OFF_ROWRANGE);
  u16*   WB     = (u16*)(ws + OFF_WB);
  int*   csrbin = (int*)(ws + OFF_CSR);
  u16*   p0I    = (u16*)(ws + OFF_N0I);       // pair0 item
  u16*   p0U    = (u16*)(ws + OFF_N0U);       // pair0 user
  float* P      = (float*)(ws + OFF_P);
  u16*   WBs    = (u16*)(ws + OFF_WBS);
  float* bvec   = (float*)(ws + OFF_BVEC);
  u16*   p1U    = (u16*)(ws + OFF_XU0);       // pair1 user (= initial cast)
  u16*   p1I    = (u16*)(ws + OFF_XI0);       // pair1 item (= initial cast)
  float* fout   = (float*)d_out;
  float* featsAll = fout + LOGITS_N;

  float* bank0 = accSQ;
  float* bank1 = accSQ + 512;

  hipMemsetAsync(ws, 0, MEMSET_BYTES, stream);
  // small kernels first: absorb the post-reset cold window (R6/R8-verified).
  k_bin<<<NBINBLK + 391, 256, 0, stream>>>(eu2i, ei2u, bcursor, csrbin,
                                           bu, bi, gcnt);
  k_csrbuild<<<NBUCK + 1, 256, 0, stream>>>(bcursor, csrbin, rowrange,
                                            gcnt, ustart, istart, invcnt);
  k_cast<<<3893, 256, 0, stream>>>(x_user, x_item, p1U, p1I,
                                   Wrel_u2i, Wroot_u2i, Wrel_i2u, Wroot_i2u,
                                   WB, P);

  // ---- layer 0: sources are raw inputs (no relu, no BN fold), pair1 = x0 ----
  k_gather<0><<<25000, 256, 0, stream>>>(p1U, p1I, rowrange, csrbin, p0I, p0U);
  k_gemm<<<dim3(NBLK,2), 256, 0, stream>>>(p0U, p0I, p1U, p1I, WB,
                                           b_i2u, b_u2i, bank0,
                                           bvec, rowrange, bu, bi,
                                           ustart, istart, P, 0);
  k_bnfold2<<<322, 256, 0, stream>>>(Wrel_u2i, Wroot_u2i, Wrel_i2u, Wroot_i2u,
                                     1, bank0, bank1,
                                     bn_g_user, bn_b_user, bn_g_item, bn_b_item,
                                     WBs, bvec, P, ustart, istart, invcnt,
                                     featsAll, fcW, fcb, fout, 0);

  // ---- layer 1: relu in gather/staging, BN folded; writes pair1 (x0 dead) ----
  k_gather<1><<<25000, 256, 0, stream>>>(p0U, p0I, rowrange, csrbin, p1I, p1U);
  k_gemm<<<dim3(NBLK,2), 256, 0, stream>>>(p1U, p1I, p0U, p0I, WBs,
                                           b_i2u + FD, b_u2i + FD, bank1,
                                           bvec, rowrange, bu, bi,
                                           ustart, istart, P, 1);
  k_bnfold2<<<322, 256, 0, stream>>>(Wrel_u2i, Wroot_u2i, Wrel_i2u, Wroot_i2u,
                                     2, bank1, bank0,
                                     bn_g_user, bn_b_user, bn_g_item, bn_b_item,
                                     WBs, bvec, P, ustart, istart, invcnt,
                                     featsAll + NG*FD,
                                     fcW + NC*FD, fcb + NC, fout + NG*NC, 0);

  // ---- layer 2 ----
  k_gather<1><<<25000, 256, 0, stream>>>(p1U, p1I, rowrange, csrbin, p0I, p0U);
  k_gemm<<<dim3(NBLK,2), 256, 0, stream>>>(p0U, p0I, p1U, p1I, WBs,
                                           b_i2u + 2*FD, b_u2i + 2*FD, bank0,
                                           bvec, rowrange, bu, bi,
                                           ustart, istart, P, 1);
  k_bnfold2<<<256, 256, 0, stream>>>(Wrel_u2i, Wroot_u2i, Wrel_i2u, Wroot_i2u,
                                     2, bank0, bank1,
                                     bn_g_user, bn_b_user, bn_g_item, bn_b_item,
                                     WBs, bvec, P, ustart, istart, invcnt,
                                     featsAll + 2*NG*FD,
                                     fcW + 2*NC*FD, fcb + 2*NC, fout + 2*NG*NC, 1);
}